// Round 1
// baseline (2500.583 us; speedup 1.0000x reference)
//
#include <hip/hip_runtime.h>
#include <stdint.h>

// Fixed problem config
#define NN   2
#define ANU  5
#define CH   64
#define HH   96
#define WW   96
#define KK   6
#define PSHh 8
#define PNHh 12
#define BB   (NN*PNHh)        // 24
#define PP   (ANU*WW)         // 480
#define CCD  (CH*ANU*PSHh)    // 2560
#define IMG_HW (HH*WW)            // 9216
#define IMG_STRIDE (CH*HH*WW)     // 589824 floats per input image
#define LFV_IMG (CH*ANU*HH)       // 30720 floats per (n,v,w) image in lfV / a1

// ---------------------------------------------------------------------------
// K0: transpose lf_fea[(n,u,v)][c][h][w] -> lfV[(n,v,w)][c][u][h]
// ---------------------------------------------------------------------------
__global__ __launch_bounds__(256) void k0_lfv(const float* __restrict__ lf_fea,
                                              float* __restrict__ lfV) {
    int bc  = blockIdx.x;          // img*64 + c
    int img = bc >> 6;
    int c   = bc & 63;
    int n = img / 25, r = img % 25, u = r / 5, v = r % 5;
    const float* src = lf_fea + (size_t)bc * IMG_HW;
    __shared__ float tile[96][97];
    for (int e = threadIdx.x; e < 96*96; e += 256) {
        int h = e / 96, w = e % 96;
        tile[h][w] = src[e];
    }
    __syncthreads();
    size_t base = (size_t)((n*5 + v)*96) * LFV_IMG + (size_t)c*480 + u*96;
    for (int e = threadIdx.x; e < 96*96; e += 256) {
        int w = e / 96, h = e % 96;
        lfV[base + (size_t)w * LFV_IMG + h] = tile[h][w];
    }
}

// ---------------------------------------------------------------------------
// K1: sq[b][p] = sum_cc lf[b][cc][p]^2  (fp64 accumulate for accuracy)
// ---------------------------------------------------------------------------
__global__ __launch_bounds__(256) void k1_sq(const float* __restrict__ lf_fea,
                                             float* __restrict__ sq) {
    int rr = blockIdx.x * 256 + threadIdx.x;     // 0..11519
    int b = rr / PP, p = rr % PP;
    int n = b / PNHh, pnh = b % PNHh;
    int v = p / WW,  w = p % WW;
    double acc = 0.0;
    for (int c = 0; c < 64; ++c) {
        for (int u = 0; u < 5; ++u) {
            const float* s = lf_fea + ((size_t)((n*25 + u*5 + v)*64 + c)) * IMG_HW
                             + pnh*8*96 + w;
#pragma unroll
            for (int psh = 0; psh < 8; ++psh) {
                float x = s[psh*96];
                acc += (double)x * (double)x;
            }
        }
    }
    sq[rr] = (float)acc;
}

// ---------------------------------------------------------------------------
// K2: dist[b][p][q] = sq[p] + sq[q] - 2 * <lf[:,p], lf[:,q]>
//     tiled 96x96 per block; per-chunk sub-accumulators keep fp32 error ~2e-5
// ---------------------------------------------------------------------------
__global__ __launch_bounds__(256) void k2_dist(const float* __restrict__ lf_fea,
                                               const float* __restrict__ sq,
                                               float* __restrict__ dist) {
    int blk = blockIdx.x;            // b*25 + vr*5 + vc
    int b  = blk / 25;
    int t2 = blk % 25;
    int vr = t2 / 5, vc = t2 % 5;
    int n = b / PNHh, pnh = b % PNHh;

    __shared__ float As[32][96];
    __shared__ float Bs[32][96];

    int tx = threadIdx.x & 15, ty = threadIdx.x >> 4;
    float acc[6][6] = {};

    for (int kc0 = 0; kc0 < CCD; kc0 += 32) {
        for (int e = threadIdx.x; e < 32*96; e += 256) {
            int kci = e / 96, w = e % 96;
            int cc = kc0 + kci;
            int c = cc / 40, r2 = cc % 40, u = r2 >> 3, psh = r2 & 7;
            size_t off = ((size_t)((n*25 + u*5)*64 + c)) * IMG_HW + (pnh*8 + psh)*96 + w;
            As[kci][w] = lf_fea[off + (size_t)vr * IMG_STRIDE];
            Bs[kci][w] = lf_fea[off + (size_t)vc * IMG_STRIDE];
        }
        __syncthreads();
        float accC[6][6] = {};
#pragma unroll
        for (int kc = 0; kc < 32; ++kc) {
            float a[6], bq[6];
#pragma unroll
            for (int i = 0; i < 6; ++i) a[i]  = As[kc][ty*6 + i];
#pragma unroll
            for (int j = 0; j < 6; ++j) bq[j] = Bs[kc][tx*6 + j];
#pragma unroll
            for (int i = 0; i < 6; ++i)
#pragma unroll
                for (int j = 0; j < 6; ++j)
                    accC[i][j] = fmaf(a[i], bq[j], accC[i][j]);
        }
#pragma unroll
        for (int i = 0; i < 6; ++i)
#pragma unroll
            for (int j = 0; j < 6; ++j)
                acc[i][j] += accC[i][j];
        __syncthreads();
    }

    const float* sqb = sq + b*PP;
    size_t dbase = (size_t)b * PP * PP;
#pragma unroll
    for (int i = 0; i < 6; ++i) {
        int p = vr*96 + ty*6 + i;
#pragma unroll
        for (int j = 0; j < 6; ++j) {
            int q = vc*96 + tx*6 + j;
            dist[dbase + (size_t)p*PP + q] = sqb[p] + sqb[q] - 2.0f*acc[i][j];
        }
    }
}

// ---------------------------------------------------------------------------
// K3: per-row top-6 smallest (ascending dist, ties -> lower index), one wave/row
// ---------------------------------------------------------------------------
__global__ __launch_bounds__(256) void k3_topk(const float* __restrict__ dist,
                                               int* __restrict__ idx) {
    int wid  = (blockIdx.x * 256 + threadIdx.x) >> 6;  // global wave id, 0..11519
    int lane = threadIdx.x & 63;
    int b = wid / PP, p = wid % PP;
    const float* row = dist + (size_t)b * PP * PP + (size_t)p * PP;

    unsigned long long key[8];
#pragma unroll
    for (int j = 0; j < 8; ++j) {
        int q = j*64 + lane;
        if (q < PP) {
            unsigned int f = __float_as_uint(row[q]);
            unsigned int mono = f ^ ((f & 0x80000000u) ? 0xFFFFFFFFu : 0x80000000u);
            key[j] = ((unsigned long long)mono << 32) | (unsigned int)q;
        } else {
            key[j] = ~0ull;
        }
    }
    int* outp = idx + ((size_t)b*PP + p) * KK;
    for (int k = 0; k < KK; ++k) {
        unsigned long long m = key[0];
#pragma unroll
        for (int j = 1; j < 8; ++j) m = (key[j] < m) ? key[j] : m;
        for (int s = 1; s < 64; s <<= 1) {
            unsigned long long o = __shfl_xor(m, s, 64);
            m = (o < m) ? o : m;
        }
        if (lane == 0) outp[k] = (int)(m & 0xFFFFFFFFu);
#pragma unroll
        for (int j = 0; j < 8; ++j) if (key[j] == m) key[j] = ~0ull;
    }
}

// ---------------------------------------------------------------------------
// K4: gather + 1x1 conv (384->64) + leaky  => a1[(n,v,w)][co][u][h]
//     block = (b, 4 consecutive p);  GEMM [64co x 160cols] over kc=384
// ---------------------------------------------------------------------------
#define BSW 164
__global__ __launch_bounds__(256) void k4_conv1(const float* __restrict__ lfV,
                                                const float* __restrict__ w1,
                                                const int* __restrict__ idxg,
                                                float* __restrict__ a1) {
    int blk = blockIdx.x;           // b*120 + ptile
    int b = blk / 120, ptile = blk % 120;
    int n = b / PNHh, pnh = b % PNHh;
    int p0 = ptile * 4;

    __shared__ float Bs[64][BSW];
    __shared__ float W1s[64][68];
    __shared__ int   idxs[4][6];

    int t = threadIdx.x;
    if (t < 24) {
        int pi = t / 6, k = t % 6;
        idxs[pi][k] = idxg[((size_t)b*PP + p0 + pi)*KK + k];
    }

    int co4  = (t & 15) * 4;
    int colg = t >> 4;              // 0..15, 10 cols each
    float acc[4][10] = {};

    for (int k = 0; k < KK; ++k) {
        __syncthreads();   // idxs visible (k=0) / protect LDS reuse (k>0)
        // stage W1s[c][co] = w1[co*384 + k*64 + c]
        {
            int co = t >> 2, cq = t & 3;
            const float4* src = (const float4*)(w1 + (size_t)co*384 + k*64);
#pragma unroll
            for (int q = 0; q < 4; ++q) {
                float4 vv = src[cq*4 + q];
                int cb = (cq*4 + q)*4;
                W1s[cb+0][co] = vv.x; W1s[cb+1][co] = vv.y;
                W1s[cb+2][co] = vv.z; W1s[cb+3][co] = vv.w;
            }
        }
        // stage Bs[c][col], col = pi*40 + u*8 + psh
#pragma unroll
        for (int ii = 0; ii < 10; ++ii) {
            int e = t + 256*ii;                  // < 2560 float4s
            int pi = e / 640, r = e % 640;
            int c = r / 10, f = r % 10;
            int u = f >> 1, half = f & 1;
            int q = idxs[pi][k];
            int vq = q / 96, wq = q % 96;
            const float4* src = (const float4*)(lfV
                + (size_t)((n*5 + vq)*96 + wq) * LFV_IMG
                + (size_t)c*480 + u*96 + pnh*8 + half*4);
            float4 vv = *src;
            *(float4*)&Bs[c][pi*40 + u*8 + half*4] = vv;
        }
        __syncthreads();
        // compute
#pragma unroll 4
        for (int c = 0; c < 64; ++c) {
            float4 wv = *(const float4*)&W1s[c][co4];
#pragma unroll
            for (int j2 = 0; j2 < 10; ++j2) {
                float bv = Bs[c][colg*10 + j2];
                acc[0][j2] = fmaf(wv.x, bv, acc[0][j2]);
                acc[1][j2] = fmaf(wv.y, bv, acc[1][j2]);
                acc[2][j2] = fmaf(wv.z, bv, acc[2][j2]);
                acc[3][j2] = fmaf(wv.w, bv, acc[3][j2]);
            }
        }
    }
    // epilogue: leaky + store a1
#pragma unroll
    for (int j2 = 0; j2 < 10; ++j2) {
        int col = colg*10 + j2;
        int pi = col / 40, rr = col % 40;
        int u = rr >> 3, psh = rr & 7;
        int pg = p0 + pi;
        int v = pg / 96, w = pg % 96;
        size_t base = (size_t)((n*5 + v)*96 + w) * LFV_IMG + (size_t)u*96 + pnh*8 + psh;
#pragma unroll
        for (int jj = 0; jj < 4; ++jj) {
            float x = acc[jj][j2];
            a1[base + (size_t)(co4 + jj)*480] = (x > 0.f) ? x : 0.1f*x;
        }
    }
}

// ---------------------------------------------------------------------------
// K5: 3x3 conv over (u,h), epi = concat(lfV, a1) [128ch] -> 64ch, leaky,
//     fused with the output permutation  out[(n,u,v)][co][h][w]
//     block = (imgv, u); thread = (co, h-strip of 24)
// ---------------------------------------------------------------------------
__global__ __launch_bounds__(256) void k5_conv3(const float* __restrict__ lfV,
                                                const float* __restrict__ a1,
                                                const float* __restrict__ w2,
                                                float* __restrict__ outp) {
    int blk = blockIdx.x;           // imgv*5 + u
    int imgv = blk / 5, u = blk % 5;
    int n = imgv / 480, r2 = imgv % 480, v = r2 / 96, w = r2 % 96;

    __shared__ float ins[16][3][100];   // [ci_local][du][1+h], zero-padded edges
    __shared__ float w2s[16*9*64];      // [(i*9 + du*3+dh)*64 + co]

    int t = threadIdx.x;
    int co = t & 63, s = t >> 6;
    int h0 = s * 24;
    float acc[24] = {};

    for (int cc8 = 0; cc8 < 8; ++cc8) {
        __syncthreads();
        // stage input rows (16 channels x 3 u-offsets x 96 h)
        for (int e = t; e < 1152; e += 256) {
            int i = e / 72, rr = e % 72, du = rr / 24, q = rr % 24;
            int ci = cc8*16 + i;
            int uu = u + du - 1;
            float4 vv = {0.f, 0.f, 0.f, 0.f};
            if (uu >= 0 && uu < 5) {
                const float* srcp = (ci < 64)
                    ? (lfV + (size_t)imgv*LFV_IMG + (size_t)ci*480 + uu*96)
                    : (a1  + (size_t)imgv*LFV_IMG + (size_t)(ci - 64)*480 + uu*96);
                vv = *(const float4*)(srcp + q*4);
            }
            float* d = &ins[i][du][1 + q*4];
            d[0] = vv.x; d[1] = vv.y; d[2] = vv.z; d[3] = vv.w;
        }
        if (t < 48) { int i = t/3, du = t%3; ins[i][du][0] = 0.f; ins[i][du][97] = 0.f; }
        // stage weights (transposed: co contiguous)
        {
            int co2 = t >> 2, lane4 = t & 3;
            const float* srcw = w2 + (size_t)co2*1152 + cc8*144 + lane4*36;
#pragma unroll
            for (int q = 0; q < 9; ++q) {
                float4 vv = *(const float4*)(srcw + q*4);
                int i0 = lane4*36 + q*4;
                w2s[(i0+0)*64 + co2] = vv.x;
                w2s[(i0+1)*64 + co2] = vv.y;
                w2s[(i0+2)*64 + co2] = vv.z;
                w2s[(i0+3)*64 + co2] = vv.w;
            }
        }
        __syncthreads();
        // compute
        for (int i = 0; i < 16; ++i) {
#pragma unroll
            for (int du = 0; du < 3; ++du) {
                float rr[26];
                const float* rowp = &ins[i][du][h0];
#pragma unroll
                for (int q = 0; q < 6; ++q) {
                    float4 vv = *(const float4*)(rowp + q*4);
                    rr[q*4+0] = vv.x; rr[q*4+1] = vv.y;
                    rr[q*4+2] = vv.z; rr[q*4+3] = vv.w;
                }
                rr[24] = rowp[24]; rr[25] = rowp[25];
#pragma unroll
                for (int dh = 0; dh < 3; ++dh) {
                    float wv = w2s[((i*3 + du)*3 + dh)*64 + co];
#pragma unroll
                    for (int j = 0; j < 24; ++j)
                        acc[j] = fmaf(wv, rr[j + dh], acc[j]);
                }
            }
        }
    }
    // leaky + permuted store: out[(n*25+u*5+v)][co][h0+j][w]
    size_t obase = ((size_t)((n*25 + u*5 + v)*64 + co)) * IMG_HW + (size_t)h0*96 + w;
#pragma unroll
    for (int j = 0; j < 24; ++j) {
        float x = acc[j];
        outp[obase + (size_t)j*96] = (x > 0.f) ? x : 0.1f*x;
    }
}

// ---------------------------------------------------------------------------
extern "C" void kernel_launch(void* const* d_in, const int* in_sizes, int n_in,
                              void* d_out, int out_size, void* d_ws, size_t ws_size,
                              hipStream_t stream) {
    const float* lf_fea = (const float*)d_in[0];
    const float* w1     = (const float*)d_in[1];
    const float* w2     = (const float*)d_in[2];
    float* outp = (float*)d_out;

    char* ws = (char*)d_ws;
    // ws layout (bytes):
    //   lfV : 960*64*5*96*4          = 117,964,800
    //   a1  : 117,964,800
    //   dist: 24*480*480*4           =  22,118,400
    //   sq  : 24*480*4               =      46,080
    //   idx : 24*480*6*4             =      69,120
    float* lfV  = (float*)(ws);
    float* a1   = (float*)(ws + 117964800ull);
    float* dist = (float*)(ws + 235929600ull);
    float* sq   = (float*)(ws + 258048000ull);
    int*   idx  = (int*)  (ws + 258094080ull);

    hipLaunchKernelGGL(k0_lfv,   dim3(3200), dim3(256), 0, stream, lf_fea, lfV);
    hipLaunchKernelGGL(k1_sq,    dim3(45),   dim3(256), 0, stream, lf_fea, sq);
    hipLaunchKernelGGL(k2_dist,  dim3(600),  dim3(256), 0, stream, lf_fea, sq, dist);
    hipLaunchKernelGGL(k3_topk,  dim3(2880), dim3(256), 0, stream, dist, idx);
    hipLaunchKernelGGL(k4_conv1, dim3(2880), dim3(256), 0, stream, lfV, w1, idx, a1);
    hipLaunchKernelGGL(k5_conv3, dim3(4800), dim3(256), 0, stream, lfV, a1, w2, outp);
}

// Round 7
// 2375.236 us; speedup vs baseline: 1.0528x; 1.0528x over previous
//
#include <hip/hip_runtime.h>
#include <stdint.h>

// Fixed problem config
#define NN   2
#define ANU  5
#define CH   64
#define HH   96
#define WW   96
#define KK   6
#define PSHh 8
#define PNHh 12
#define BB   (NN*PNHh)        // 24
#define PP   (ANU*WW)         // 480
#define CCD  (CH*ANU*PSHh)    // 2560
#define IMG_HW (HH*WW)            // 9216
#define IMG_STRIDE (CH*HH*WW)     // 589824 floats per input image
#define LFV_IMG (CH*ANU*HH)       // 30720 floats per (n,v,w) image in lfV / a1

typedef int   i32x4 __attribute__((ext_vector_type(4)));
typedef float f32x4 __attribute__((ext_vector_type(4)));

__device__ __forceinline__ unsigned short f2bf(float f) {
    unsigned int u = __float_as_uint(f);
    return (unsigned short)((u + 0x7FFFu + ((u >> 16) & 1u)) >> 16);
}

__device__ __forceinline__ void mfma_bf16_16x16x32(f32x4& d, i32x4 a, i32x4 b) {
    asm volatile("v_mfma_f32_16x16x32_bf16 %0, %1, %2, %0"
                 : "+v"(d) : "v"(a), "v"(b));
}

// pack 8 consecutive fp32 -> 8 bf16 in an i32x4 (A-fragment)
__device__ __forceinline__ i32x4 pack8(const float* p) {
    float4 lo = *(const float4*)p;
    float4 hi = *(const float4*)(p + 4);
    i32x4 r;
    r[0] = (int)((unsigned int)f2bf(lo.x) | ((unsigned int)f2bf(lo.y) << 16));
    r[1] = (int)((unsigned int)f2bf(lo.z) | ((unsigned int)f2bf(lo.w) << 16));
    r[2] = (int)((unsigned int)f2bf(hi.x) | ((unsigned int)f2bf(hi.y) << 16));
    r[3] = (int)((unsigned int)f2bf(hi.z) | ((unsigned int)f2bf(hi.w) << 16));
    return r;
}

// ---------------------------------------------------------------------------
// sentinel: fill d_out with 3.0f (diagnostic; overwritten by k5 if pipeline runs)
// ---------------------------------------------------------------------------
__global__ __launch_bounds__(256) void k_sentinel(float* outp, int n4) {
    int i = blockIdx.x * 256 + threadIdx.x;
    float4 v = {3.0f, 3.0f, 3.0f, 3.0f};
    for (; i < n4; i += 256 * 2048) ((float4*)outp)[i] = v;
}

// ---------------------------------------------------------------------------
// K0: transpose lf_fea[(n,u,v)][c][h][w] -> lfV[(n,v,w)][c][u][h]  (round-1)
// ---------------------------------------------------------------------------
__global__ __launch_bounds__(256) void k0_lfv(const float* __restrict__ lf_fea,
                                              float* __restrict__ lfV) {
    int bc  = blockIdx.x;          // img*64 + c
    int img = bc >> 6;
    int c   = bc & 63;
    int n = img / 25, r = img % 25, u = r / 5, v = r % 5;
    const float* src = lf_fea + (size_t)bc * IMG_HW;
    __shared__ float tile[96][97];
    for (int e = threadIdx.x; e < 96*96; e += 256) {
        int h = e / 96, w = e % 96;
        tile[h][w] = src[e];
    }
    __syncthreads();
    size_t base = (size_t)((n*5 + v)*96) * LFV_IMG + (size_t)c*480 + u*96;
    for (int e = threadIdx.x; e < 96*96; e += 256) {
        int w = e / 96, h = e % 96;
        lfV[base + (size_t)w * LFV_IMG + h] = tile[h][w];
    }
}

// ---------------------------------------------------------------------------
// K1: sq[b][p] (fp64 accumulate)  (round-1 verbatim)
// ---------------------------------------------------------------------------
__global__ __launch_bounds__(256) void k1_sq(const float* __restrict__ lf_fea,
                                             float* __restrict__ sq) {
    int rr = blockIdx.x * 256 + threadIdx.x;     // 0..11519
    int b = rr / PP, p = rr % PP;
    int n = b / PNHh, pnh = b % PNHh;
    int v = p / WW,  w = p % WW;
    double acc = 0.0;
    for (int c = 0; c < 64; ++c) {
        for (int u = 0; u < 5; ++u) {
            const float* s = lf_fea + ((size_t)((n*25 + u*5 + v)*64 + c)) * IMG_HW
                             + pnh*8*96 + w;
#pragma unroll
            for (int psh = 0; psh < 8; ++psh) {
                float x = s[psh*96];
                acc += (double)x * (double)x;
            }
        }
    }
    sq[rr] = (float)acc;
}

// ---------------------------------------------------------------------------
// K2: dist  (round-1 verbatim)
// ---------------------------------------------------------------------------
__global__ __launch_bounds__(256) void k2_dist(const float* __restrict__ lf_fea,
                                               const float* __restrict__ sq,
                                               float* __restrict__ dist) {
    int blk = blockIdx.x;            // b*25 + vr*5 + vc
    int b  = blk / 25;
    int t2 = blk % 25;
    int vr = t2 / 5, vc = t2 % 5;
    int n = b / PNHh, pnh = b % PNHh;

    __shared__ float As[32][96];
    __shared__ float Bs[32][96];

    int tx = threadIdx.x & 15, ty = threadIdx.x >> 4;
    float acc[6][6] = {};

    for (int kc0 = 0; kc0 < CCD; kc0 += 32) {
        for (int e = threadIdx.x; e < 32*96; e += 256) {
            int kci = e / 96, w = e % 96;
            int cc = kc0 + kci;
            int c = cc / 40, r2 = cc % 40, u = r2 >> 3, psh = r2 & 7;
            size_t off = ((size_t)((n*25 + u*5)*64 + c)) * IMG_HW + (pnh*8 + psh)*96 + w;
            As[kci][w] = lf_fea[off + (size_t)vr * IMG_STRIDE];
            Bs[kci][w] = lf_fea[off + (size_t)vc * IMG_STRIDE];
        }
        __syncthreads();
        float accC[6][6] = {};
#pragma unroll
        for (int kc = 0; kc < 32; ++kc) {
            float a[6], bq[6];
#pragma unroll
            for (int i = 0; i < 6; ++i) a[i]  = As[kc][ty*6 + i];
#pragma unroll
            for (int j = 0; j < 6; ++j) bq[j] = Bs[kc][tx*6 + j];
#pragma unroll
            for (int i = 0; i < 6; ++i)
#pragma unroll
                for (int j = 0; j < 6; ++j)
                    accC[i][j] = fmaf(a[i], bq[j], accC[i][j]);
        }
#pragma unroll
        for (int i = 0; i < 6; ++i)
#pragma unroll
            for (int j = 0; j < 6; ++j)
                acc[i][j] += accC[i][j];
        __syncthreads();
    }

    const float* sqb = sq + b*PP;
    size_t dbase = (size_t)b * PP * PP;
#pragma unroll
    for (int i = 0; i < 6; ++i) {
        int p = vr*96 + ty*6 + i;
#pragma unroll
        for (int j = 0; j < 6; ++j) {
            int q = vc*96 + tx*6 + j;
            dist[dbase + (size_t)p*PP + q] = sqb[p] + sqb[q] - 2.0f*acc[i][j];
        }
    }
}

// ---------------------------------------------------------------------------
// K3: per-row top-6  (round-1 verbatim)
// ---------------------------------------------------------------------------
__global__ __launch_bounds__(256) void k3_topk(const float* __restrict__ dist,
                                               int* __restrict__ idx) {
    int wid  = (blockIdx.x * 256 + threadIdx.x) >> 6;  // global wave id
    int lane = threadIdx.x & 63;
    int b = wid / PP, p = wid % PP;
    const float* row = dist + (size_t)b * PP * PP + (size_t)p * PP;

    unsigned long long key[8];
#pragma unroll
    for (int j = 0; j < 8; ++j) {
        int q = j*64 + lane;
        if (q < PP) {
            unsigned int f = __float_as_uint(row[q]);
            unsigned int mono = f ^ ((f & 0x80000000u) ? 0xFFFFFFFFu : 0x80000000u);
            key[j] = ((unsigned long long)mono << 32) | (unsigned int)q;
        } else {
            key[j] = ~0ull;
        }
    }
    int* outp = idx + ((size_t)b*PP + p) * KK;
    for (int k = 0; k < KK; ++k) {
        unsigned long long m = key[0];
#pragma unroll
        for (int j = 1; j < 8; ++j) m = (key[j] < m) ? key[j] : m;
        for (int s = 1; s < 64; s <<= 1) {
            unsigned long long o = __shfl_xor(m, s, 64);
            m = (o < m) ? o : m;
        }
        if (lane == 0) outp[k] = (int)(m & 0xFFFFFFFFu);
#pragma unroll
        for (int j = 0; j < 8; ++j) if (key[j] == m) key[j] = ~0ull;
    }
}

// ---------------------------------------------------------------------------
// K4: gather + 1x1 conv (K=384 -> 64co) via INLINE-ASM MFMA bf16.
//     A-fragments: fp32 w1 loaded + converted in-register (no extra buffer).
//     Hazard-safe: dependency-carrying s_nop asm (1 operand per asm only).
//     block = (b, 2 p's); C = [64co x 80cols], col = pl*40 + u*8 + psh
// ---------------------------------------------------------------------------
__global__ __launch_bounds__(256) void k4_conv1(const float* __restrict__ lfV,
                                                const float* __restrict__ w1,
                                                const int* __restrict__ idxg,
                                                float* __restrict__ a1) {
    int blk = blockIdx.x;            // b*240 + ptile
    int b = blk / 240, ptile = blk % 240;
    int n = b / PNHh, pnh = b % PNHh;
    int p0 = ptile * 2;

    __shared__ unsigned short Bs[80][384];   // [col][k*64+c] bf16
    __shared__ int idxs[12];

    int t = threadIdx.x;
    if (t < 12) idxs[t] = idxg[(b*PP + p0 + t/6)*KK + (t % 6)];
    __syncthreads();

    // stage: e = (pl,k,c,u,half) -> float4 over 4 psh values, cvt bf16, scatter
    for (int i = 0; i < 30; ++i) {
        int e = i * 256 + t;               // 7680 = 2*6*64*5*2
        int half = e & 1;
        int u    = (e >> 1) % 5;
        int c    = ((e >> 1) / 5) % 64;
        int k    = ((e >> 1) / 320) % 6;
        int pl   = e / 3840;
        int q = idxs[pl * 6 + k];
        const float* src = lfV
            + (size_t)((n*5 + q/96)*96 + (q%96)) * LFV_IMG
            + (size_t)c*480 + u*96 + pnh*8 + half*4;
        float4 vv = *(const float4*)src;
        int colbase = pl*40 + u*8 + half*4;
        int krow = k*64 + c;
        Bs[colbase+0][krow] = f2bf(vv.x);
        Bs[colbase+1][krow] = f2bf(vv.y);
        Bs[colbase+2][krow] = f2bf(vv.z);
        Bs[colbase+3][krow] = f2bf(vv.w);
    }
    __syncthreads();

    int lane = t & 63, wv = t >> 6;
    int l15 = lane & 15, hi = lane >> 4;
    int co0 = wv * 16;
    f32x4 acc[5] = {};
    // VALU(init) -> MFMA SrcC hazard guard, dependency-carried
#pragma unroll
    for (int f = 0; f < 5; ++f)
        asm volatile("s_nop 1" : "+v"(acc[f]));

    const float* ap = w1 + (size_t)(co0 + l15) * 384 + hi * 8;
    for (int ks = 0; ks < 12; ++ks) {
        i32x4 a = pack8(ap + ks * 32);
        // VALU(pack) -> MFMA SrcA hazard guard, dependency-carried
        asm volatile("s_nop 1" : "+v"(a));
#pragma unroll
        for (int f = 0; f < 5; ++f) {
            i32x4 bv = *(const i32x4*)&Bs[f*16 + l15][ks*32 + hi*8];
            mfma_bf16_16x16x32(acc[f], a, bv);
        }
    }
    // MFMA(D write) -> VALU read hazard guard, dependency-carried per acc
#pragma unroll
    for (int f = 0; f < 5; ++f)
        asm volatile("s_nop 7\ns_nop 7" : "+v"(acc[f]));

    // epilogue: leaky + fp32 store (D map m89: col = lane&15, row = hi*4 + reg)
#pragma unroll
    for (int f = 0; f < 5; ++f) {
        int col = f * 16 + l15;
        int pg = p0 + col / 40, rr = col % 40;
        int u = rr >> 3, psh = rr & 7;
        size_t base = (size_t)((n*5 + pg/96)*96 + (pg%96)) * LFV_IMG
                    + (size_t)u * 96 + pnh*8 + psh;
#pragma unroll
        for (int rg = 0; rg < 4; ++rg) {
            float x = acc[f][rg];
            x = x > 0.f ? x : 0.1f * x;
            a1[base + (size_t)(co0 + hi*4 + rg) * 480] = x;
        }
    }
}

// ---------------------------------------------------------------------------
// K5: 3x3 conv, VALU fp32 (round-1 verbatim)
// ---------------------------------------------------------------------------
__global__ __launch_bounds__(256) void k5_conv3(const float* __restrict__ lfV,
                                                const float* __restrict__ a1,
                                                const float* __restrict__ w2,
                                                float* __restrict__ outp) {
    int blk = blockIdx.x;           // imgv*5 + u
    int imgv = blk / 5, u = blk % 5;
    int n = imgv / 480, r2 = imgv % 480, v = r2 / 96, w = r2 % 96;

    __shared__ float ins[16][3][100];   // [ci_local][du][1+h], zero-padded edges
    __shared__ float w2s[16*9*64];      // [(i*9 + du*3+dh)*64 + co]

    int t = threadIdx.x;
    int co = t & 63, s = t >> 6;
    int h0 = s * 24;
    float acc[24] = {};

    for (int cc8 = 0; cc8 < 8; ++cc8) {
        __syncthreads();
        for (int e = t; e < 1152; e += 256) {
            int i = e / 72, rr = e % 72, du = rr / 24, q = rr % 24;
            int ci = cc8*16 + i;
            int uu = u + du - 1;
            float4 vv = {0.f, 0.f, 0.f, 0.f};
            if (uu >= 0 && uu < 5) {
                const float* srcp = (ci < 64)
                    ? (lfV + (size_t)imgv*LFV_IMG + (size_t)ci*480 + uu*96)
                    : (a1  + (size_t)imgv*LFV_IMG + (size_t)(ci - 64)*480 + uu*96);
                vv = *(const float4*)(srcp + q*4);
            }
            float* d = &ins[i][du][1 + q*4];
            d[0] = vv.x; d[1] = vv.y; d[2] = vv.z; d[3] = vv.w;
        }
        if (t < 48) { int i = t/3, du = t%3; ins[i][du][0] = 0.f; ins[i][du][97] = 0.f; }
        {
            int co2 = t >> 2, lane4 = t & 3;
            const float* srcw = w2 + (size_t)co2*1152 + cc8*144 + lane4*36;
#pragma unroll
            for (int q = 0; q < 9; ++q) {
                float4 vv = *(const float4*)(srcw + q*4);
                int i0 = lane4*36 + q*4;
                w2s[(i0+0)*64 + co2] = vv.x;
                w2s[(i0+1)*64 + co2] = vv.y;
                w2s[(i0+2)*64 + co2] = vv.z;
                w2s[(i0+3)*64 + co2] = vv.w;
            }
        }
        __syncthreads();
        for (int i = 0; i < 16; ++i) {
#pragma unroll
            for (int du = 0; du < 3; ++du) {
                float rr[26];
                const float* rowp = &ins[i][du][h0];
#pragma unroll
                for (int q = 0; q < 6; ++q) {
                    float4 vv = *(const float4*)(rowp + q*4);
                    rr[q*4+0] = vv.x; rr[q*4+1] = vv.y;
                    rr[q*4+2] = vv.z; rr[q*4+3] = vv.w;
                }
                rr[24] = rowp[24]; rr[25] = rowp[25];
#pragma unroll
                for (int dh = 0; dh < 3; ++dh) {
                    float wv = w2s[((i*3 + du)*3 + dh)*64 + co];
#pragma unroll
                    for (int j = 0; j < 24; ++j)
                        acc[j] = fmaf(wv, rr[j + dh], acc[j]);
                }
            }
        }
    }
    size_t obase = ((size_t)((n*25 + u*5 + v)*64 + co)) * IMG_HW + (size_t)h0*96 + w;
#pragma unroll
    for (int j = 0; j < 24; ++j) {
        float x = acc[j];
        outp[obase + (size_t)j*96] = (x > 0.f) ? x : 0.1f*x;
    }
}

// ---------------------------------------------------------------------------
extern "C" void kernel_launch(void* const* d_in, const int* in_sizes, int n_in,
                              void* d_out, int out_size, void* d_ws, size_t ws_size,
                              hipStream_t stream) {
    const float* lf_fea = (const float*)d_in[0];
    const float* w1     = (const float*)d_in[1];
    const float* w2     = (const float*)d_in[2];
    float* outp = (float*)d_out;

    char* ws = (char*)d_ws;
    // ws layout (bytes) — round-1 EXACT layout (proven in-bounds):
    //   lfV : 117,964,800  @ 0
    //   a1  : 117,964,800  @ 117,964,800
    //   dist:  22,118,400  @ 235,929,600
    //   sq  :      46,080  @ 258,048,000
    //   idx :      69,120  @ 258,094,080   (end 258,163,200)
    float* lfV  = (float*)(ws);
    float* a1   = (float*)(ws + 117964800ull);
    float* dist = (float*)(ws + 235929600ull);
    float* sq   = (float*)(ws + 258048000ull);
    int*   idx  = (int*)  (ws + 258094080ull);

    hipLaunchKernelGGL(k_sentinel, dim3(2048), dim3(256), 0, stream, outp, out_size / 4);
    hipLaunchKernelGGL(k0_lfv,     dim3(3200), dim3(256), 0, stream, lf_fea, lfV);
    hipLaunchKernelGGL(k1_sq,      dim3(45),   dim3(256), 0, stream, lf_fea, sq);
    hipLaunchKernelGGL(k2_dist,    dim3(600),  dim3(256), 0, stream, lf_fea, sq, dist);
    hipLaunchKernelGGL(k3_topk,    dim3(2880), dim3(256), 0, stream, dist, idx);
    hipLaunchKernelGGL(k4_conv1,   dim3(5760), dim3(256), 0, stream, lfV, w1, idx, a1);
    hipLaunchKernelGGL(k5_conv3,   dim3(4800), dim3(256), 0, stream, lfV, a1, w2, outp);
}

// Round 8
// 1630.161 us; speedup vs baseline: 1.5339x; 1.4571x over previous
//
#include <hip/hip_runtime.h>
#include <stdint.h>

// Fixed problem config
#define NN   2
#define ANU  5
#define CH   64
#define HH   96
#define WW   96
#define KK   6
#define PSHh 8
#define PNHh 12
#define BB   (NN*PNHh)        // 24
#define PP   (ANU*WW)         // 480
#define CCD  (CH*ANU*PSHh)    // 2560
#define IMG_HW (HH*WW)            // 9216
#define IMG_STRIDE (CH*HH*WW)     // 589824 floats per input image
#define LFV_IMG (CH*ANU*HH)       // 30720 floats per (n,v,w) image in lfV / a1

typedef int   i32x4 __attribute__((ext_vector_type(4)));
typedef float f32x4 __attribute__((ext_vector_type(4)));

__device__ __forceinline__ unsigned short f2bf(float f) {
    unsigned int u = __float_as_uint(f);
    return (unsigned short)((u + 0x7FFFu + ((u >> 16) & 1u)) >> 16);
}

__device__ __forceinline__ void mfma_bf16_16x16x32(f32x4& d, i32x4 a, i32x4 b) {
    asm volatile("v_mfma_f32_16x16x32_bf16 %0, %1, %2, %0"
                 : "+v"(d) : "v"(a), "v"(b));
}

// pack 8 consecutive fp32 -> 8 bf16 in an i32x4 (A-fragment)
__device__ __forceinline__ i32x4 pack8(const float* p) {
    float4 lo = *(const float4*)p;
    float4 hi = *(const float4*)(p + 4);
    i32x4 r;
    r[0] = (int)((unsigned int)f2bf(lo.x) | ((unsigned int)f2bf(lo.y) << 16));
    r[1] = (int)((unsigned int)f2bf(lo.z) | ((unsigned int)f2bf(lo.w) << 16));
    r[2] = (int)((unsigned int)f2bf(hi.x) | ((unsigned int)f2bf(hi.y) << 16));
    r[3] = (int)((unsigned int)f2bf(hi.z) | ((unsigned int)f2bf(hi.w) << 16));
    return r;
}

// ---------------------------------------------------------------------------
// K0: transpose lf_fea[(n,u,v)][c][h][w] -> lfV[(n,v,w)][c][u][h]  (passing)
// ---------------------------------------------------------------------------
__global__ __launch_bounds__(256) void k0_lfv(const float* __restrict__ lf_fea,
                                              float* __restrict__ lfV) {
    int bc  = blockIdx.x;          // img*64 + c
    int img = bc >> 6;
    int c   = bc & 63;
    int n = img / 25, r = img % 25, u = r / 5, v = r % 5;
    const float* src = lf_fea + (size_t)bc * IMG_HW;
    __shared__ float tile[96][97];
    for (int e = threadIdx.x; e < 96*96; e += 256) {
        int h = e / 96, w = e % 96;
        tile[h][w] = src[e];
    }
    __syncthreads();
    size_t base = (size_t)((n*5 + v)*96) * LFV_IMG + (size_t)c*480 + u*96;
    for (int e = threadIdx.x; e < 96*96; e += 256) {
        int w = e / 96, h = e % 96;
        lfV[base + (size_t)w * LFV_IMG + h] = tile[h][w];
    }
}

// ---------------------------------------------------------------------------
// K1: sq[b][p] (fp64 accumulate)  (passing, verbatim)
// ---------------------------------------------------------------------------
__global__ __launch_bounds__(256) void k1_sq(const float* __restrict__ lf_fea,
                                             float* __restrict__ sq) {
    int rr = blockIdx.x * 256 + threadIdx.x;     // 0..11519
    int b = rr / PP, p = rr % PP;
    int n = b / PNHh, pnh = b % PNHh;
    int v = p / WW,  w = p % WW;
    double acc = 0.0;
    for (int c = 0; c < 64; ++c) {
        for (int u = 0; u < 5; ++u) {
            const float* s = lf_fea + ((size_t)((n*25 + u*5 + v)*64 + c)) * IMG_HW
                             + pnh*8*96 + w;
#pragma unroll
            for (int psh = 0; psh < 8; ++psh) {
                float x = s[psh*96];
                acc += (double)x * (double)x;
            }
        }
    }
    sq[rr] = (float)acc;
}

// ---------------------------------------------------------------------------
// K2: dist  (passing, verbatim)
// ---------------------------------------------------------------------------
__global__ __launch_bounds__(256) void k2_dist(const float* __restrict__ lf_fea,
                                               const float* __restrict__ sq,
                                               float* __restrict__ dist) {
    int blk = blockIdx.x;            // b*25 + vr*5 + vc
    int b  = blk / 25;
    int t2 = blk % 25;
    int vr = t2 / 5, vc = t2 % 5;
    int n = b / PNHh, pnh = b % PNHh;

    __shared__ float As[32][96];
    __shared__ float Bs[32][96];

    int tx = threadIdx.x & 15, ty = threadIdx.x >> 4;
    float acc[6][6] = {};

    for (int kc0 = 0; kc0 < CCD; kc0 += 32) {
        for (int e = threadIdx.x; e < 32*96; e += 256) {
            int kci = e / 96, w = e % 96;
            int cc = kc0 + kci;
            int c = cc / 40, r2 = cc % 40, u = r2 >> 3, psh = r2 & 7;
            size_t off = ((size_t)((n*25 + u*5)*64 + c)) * IMG_HW + (pnh*8 + psh)*96 + w;
            As[kci][w] = lf_fea[off + (size_t)vr * IMG_STRIDE];
            Bs[kci][w] = lf_fea[off + (size_t)vc * IMG_STRIDE];
        }
        __syncthreads();
        float accC[6][6] = {};
#pragma unroll
        for (int kc = 0; kc < 32; ++kc) {
            float a[6], bq[6];
#pragma unroll
            for (int i = 0; i < 6; ++i) a[i]  = As[kc][ty*6 + i];
#pragma unroll
            for (int j = 0; j < 6; ++j) bq[j] = Bs[kc][tx*6 + j];
#pragma unroll
            for (int i = 0; i < 6; ++i)
#pragma unroll
                for (int j = 0; j < 6; ++j)
                    accC[i][j] = fmaf(a[i], bq[j], accC[i][j]);
        }
#pragma unroll
        for (int i = 0; i < 6; ++i)
#pragma unroll
            for (int j = 0; j < 6; ++j)
                acc[i][j] += accC[i][j];
        __syncthreads();
    }

    const float* sqb = sq + b*PP;
    size_t dbase = (size_t)b * PP * PP;
#pragma unroll
    for (int i = 0; i < 6; ++i) {
        int p = vr*96 + ty*6 + i;
#pragma unroll
        for (int j = 0; j < 6; ++j) {
            int q = vc*96 + tx*6 + j;
            dist[dbase + (size_t)p*PP + q] = sqb[p] + sqb[q] - 2.0f*acc[i][j];
        }
    }
}

// ---------------------------------------------------------------------------
// K3: per-row top-6  (passing, verbatim)
// ---------------------------------------------------------------------------
__global__ __launch_bounds__(256) void k3_topk(const float* __restrict__ dist,
                                               int* __restrict__ idx) {
    int wid  = (blockIdx.x * 256 + threadIdx.x) >> 6;  // global wave id
    int lane = threadIdx.x & 63;
    int b = wid / PP, p = wid % PP;
    const float* row = dist + (size_t)b * PP * PP + (size_t)p * PP;

    unsigned long long key[8];
#pragma unroll
    for (int j = 0; j < 8; ++j) {
        int q = j*64 + lane;
        if (q < PP) {
            unsigned int f = __float_as_uint(row[q]);
            unsigned int mono = f ^ ((f & 0x80000000u) ? 0xFFFFFFFFu : 0x80000000u);
            key[j] = ((unsigned long long)mono << 32) | (unsigned int)q;
        } else {
            key[j] = ~0ull;
        }
    }
    int* outp = idx + ((size_t)b*PP + p) * KK;
    for (int k = 0; k < KK; ++k) {
        unsigned long long m = key[0];
#pragma unroll
        for (int j = 1; j < 8; ++j) m = (key[j] < m) ? key[j] : m;
        for (int s = 1; s < 64; s <<= 1) {
            unsigned long long o = __shfl_xor(m, s, 64);
            m = (o < m) ? o : m;
        }
        if (lane == 0) outp[k] = (int)(m & 0xFFFFFFFFu);
#pragma unroll
        for (int j = 0; j < 8; ++j) if (key[j] == m) key[j] = ~0ull;
    }
}

// ---------------------------------------------------------------------------
// kw2: reorder w2 -> bf16 w2h[co][cc][tap][ci64] (placed in dist region, after k3)
// ---------------------------------------------------------------------------
__global__ __launch_bounds__(256) void kw2_conv(const float* __restrict__ w2,
                                                unsigned short* __restrict__ w2h) {
    int e = blockIdx.x * 256 + threadIdx.x;   // 73728 total
    if (e < 73728) {
        int co = e / 1152, r = e % 1152;
        int cc = r / 576, r2 = r % 576;
        int tap = r2 / 64, ci_l = r2 % 64;
        w2h[e] = f2bf(w2[co*1152 + (cc*64 + ci_l)*9 + tap]);
    }
}

// ---------------------------------------------------------------------------
// K4: gather + 1x1 conv via inline-asm MFMA  (passing, verbatim from r7)
// ---------------------------------------------------------------------------
__global__ __launch_bounds__(256) void k4_conv1(const float* __restrict__ lfV,
                                                const float* __restrict__ w1,
                                                const int* __restrict__ idxg,
                                                float* __restrict__ a1) {
    int blk = blockIdx.x;            // b*240 + ptile
    int b = blk / 240, ptile = blk % 240;
    int n = b / PNHh, pnh = b % PNHh;
    int p0 = ptile * 2;

    __shared__ unsigned short Bs[80][384];   // [col][k*64+c] bf16
    __shared__ int idxs[12];

    int t = threadIdx.x;
    if (t < 12) idxs[t] = idxg[(b*PP + p0 + t/6)*KK + (t % 6)];
    __syncthreads();

    for (int i = 0; i < 30; ++i) {
        int e = i * 256 + t;               // 7680 = 2*6*64*5*2
        int half = e & 1;
        int u    = (e >> 1) % 5;
        int c    = ((e >> 1) / 5) % 64;
        int k    = ((e >> 1) / 320) % 6;
        int pl   = e / 3840;
        int q = idxs[pl * 6 + k];
        const float* src = lfV
            + (size_t)((n*5 + q/96)*96 + (q%96)) * LFV_IMG
            + (size_t)c*480 + u*96 + pnh*8 + half*4;
        float4 vv = *(const float4*)src;
        int colbase = pl*40 + u*8 + half*4;
        int krow = k*64 + c;
        Bs[colbase+0][krow] = f2bf(vv.x);
        Bs[colbase+1][krow] = f2bf(vv.y);
        Bs[colbase+2][krow] = f2bf(vv.z);
        Bs[colbase+3][krow] = f2bf(vv.w);
    }
    __syncthreads();

    int lane = t & 63, wv = t >> 6;
    int l15 = lane & 15, hi = lane >> 4;
    int co0 = wv * 16;
    f32x4 acc[5] = {};
#pragma unroll
    for (int f = 0; f < 5; ++f)
        asm volatile("s_nop 1" : "+v"(acc[f]));

    const float* ap = w1 + (size_t)(co0 + l15) * 384 + hi * 8;
    for (int ks = 0; ks < 12; ++ks) {
        i32x4 a = pack8(ap + ks * 32);
        asm volatile("s_nop 1" : "+v"(a));
#pragma unroll
        for (int f = 0; f < 5; ++f) {
            i32x4 bv = *(const i32x4*)&Bs[f*16 + l15][ks*32 + hi*8];
            mfma_bf16_16x16x32(acc[f], a, bv);
        }
    }
#pragma unroll
    for (int f = 0; f < 5; ++f)
        asm volatile("s_nop 7\ns_nop 7" : "+v"(acc[f]));

#pragma unroll
    for (int f = 0; f < 5; ++f) {
        int col = f * 16 + l15;
        int pg = p0 + col / 40, rr = col % 40;
        int u = rr >> 3, psh = rr & 7;
        size_t base = (size_t)((n*5 + pg/96)*96 + (pg%96)) * LFV_IMG
                    + (size_t)u * 96 + pnh*8 + psh;
#pragma unroll
        for (int rg = 0; rg < 4; ++rg) {
            float x = acc[f][rg];
            x = x > 0.f ? x : 0.1f * x;
            a1[base + (size_t)(co0 + hi*4 + rg) * 480] = x;
        }
    }
}

// ---------------------------------------------------------------------------
// K5m: 3x3 conv over (u,h) via inline-asm MFMA.
//     in = concat(lfV, a1) fp32 -> bf16 transposed into LDS; A from w2h (bf16).
//     block = (n,v,u, h-tile 16, w-tile 8); C = [64co x 128cols], col = hl*8+w
//     ins rows: s = (w*3+du)*18 + hp, hp = hin-h0+1 in [0,18); pitch 72 shorts.
// ---------------------------------------------------------------------------
__global__ __launch_bounds__(256) void k5m_conv3(const float* __restrict__ lfV,
                                                 const float* __restrict__ a1,
                                                 const unsigned short* __restrict__ w2h,
                                                 float* __restrict__ outp) {
    int blk = blockIdx.x;
    int wt = blk % 12; int r = blk / 12;
    int ht = r % 6;  r /= 6;
    int u  = r % 5;  r /= 5;
    int v  = r % 5;  int n = r / 5;
    int w0 = wt * 8, h0 = ht * 16;
    int imgbase = (n*5 + v) * 96 + w0;

    __shared__ unsigned short ins[432][72];   // 62,208 B

    int t = threadIdx.x;
    int lane = t & 63, wv = t >> 6, l15 = lane & 15, hi = lane >> 4;
    int co0 = wv * 16;

    f32x4 acc[8] = {};
#pragma unroll
    for (int f = 0; f < 8; ++f) asm volatile("s_nop 1" : "+v"(acc[f]));

    for (int cc = 0; cc < 2; ++cc) {
        const float* basep = cc ? a1 : lfV;
        if (cc) __syncthreads();
        // stage: e = (ci, du, w, g): aligned float4 over 4 hin, cvt bf16,
        // transpose-scatter into ins; halo rows get zeros.
        for (int i = 0; i < 36; ++i) {
            int e = i * 256 + t;              // 9216 = 64ci*3du*8w*6g
            int g  = e % 6;
            int w  = (e / 6) & 7;
            int du = (e / 48) % 3;
            int ci = e / 144;
            int uin = u + du - 1;
            int hbase = h0 - 4 + g * 4;       // aligned; chunks fully in/out
            float4 vv = {0.f, 0.f, 0.f, 0.f};
            if (uin >= 0 && uin < 5 && hbase >= 0 && hbase <= 92)
                vv = *(const float4*)(basep + (size_t)(imgbase + w) * LFV_IMG
                      + (size_t)ci * 480 + uin * 96 + hbase);
            int sbase = (w*3 + du) * 18;
            int hp0 = g*4 - 3;                // hp of vv.x
            if (hp0     >= 0 && hp0     < 18) ins[sbase + hp0    ][ci] = f2bf(vv.x);
            if (hp0 + 1 >= 0 && hp0 + 1 < 18) ins[sbase + hp0 + 1][ci] = f2bf(vv.y);
            if (hp0 + 2 >= 0 && hp0 + 2 < 18) ins[sbase + hp0 + 2][ci] = f2bf(vv.z);
            if (hp0 + 3 >= 0 && hp0 + 3 < 18) ins[sbase + hp0 + 3][ci] = f2bf(vv.w);
        }
        __syncthreads();

        const unsigned short* wp = w2h + (size_t)(co0 + l15) * 1152 + cc * 576 + hi * 8;
        for (int du = 0; du < 3; ++du)
#pragma unroll
        for (int dh = 0; dh < 3; ++dh) {
#pragma unroll
            for (int kk = 0; kk < 2; ++kk) {
                i32x4 a = *(const i32x4*)(wp + (du*3 + dh) * 64 + kk * 32);
#pragma unroll
                for (int f = 0; f < 8; ++f) {
                    int col = f * 16 + l15;
                    int s = ((col & 7)*3 + du)*18 + (col >> 3) + dh;
                    i32x4 bv = *(const i32x4*)&ins[s][kk*32 + hi*8];
                    mfma_bf16_16x16x32(acc[f], a, bv);
                }
            }
        }
    }
#pragma unroll
    for (int f = 0; f < 8; ++f)
        asm volatile("s_nop 7\ns_nop 7" : "+v"(acc[f]));

    // leaky + permuted store: out[(n*25+u*5+v)][co][h0+hl][w0+w]
    size_t ob = (size_t)((n*25 + u*5 + v) * 64) * IMG_HW;
#pragma unroll
    for (int f = 0; f < 8; ++f) {
        int col = f * 16 + l15;
        int w = col & 7, hl = col >> 3;
#pragma unroll
        for (int rg = 0; rg < 4; ++rg) {
            int co = co0 + hi * 4 + rg;
            float x = acc[f][rg];
            x = x > 0.f ? x : 0.1f * x;
            outp[ob + (size_t)co * IMG_HW + (h0 + hl) * 96 + w0 + w] = x;
        }
    }
}

// ---------------------------------------------------------------------------
extern "C" void kernel_launch(void* const* d_in, const int* in_sizes, int n_in,
                              void* d_out, int out_size, void* d_ws, size_t ws_size,
                              hipStream_t stream) {
    const float* lf_fea = (const float*)d_in[0];
    const float* w1     = (const float*)d_in[1];
    const float* w2     = (const float*)d_in[2];
    float* outp = (float*)d_out;

    char* ws = (char*)d_ws;
    // ws layout (bytes) — round-1 EXACT footprint (proven in-bounds):
    //   lfV : 117,964,800  @ 0
    //   a1  : 117,964,800  @ 117,964,800
    //   dist:  22,118,400  @ 235,929,600   (w2h aliases its head AFTER k3)
    //   sq  :      46,080  @ 258,048,000
    //   idx :      69,120  @ 258,094,080   (end 258,163,200)
    float* lfV  = (float*)(ws);
    float* a1   = (float*)(ws + 117964800ull);
    float* dist = (float*)(ws + 235929600ull);
    float* sq   = (float*)(ws + 258048000ull);
    int*   idx  = (int*)  (ws + 258094080ull);
    unsigned short* w2h = (unsigned short*)(ws + 235929600ull);  // reuses dist

    hipLaunchKernelGGL(k0_lfv,   dim3(3200), dim3(256), 0, stream, lf_fea, lfV);
    hipLaunchKernelGGL(k1_sq,    dim3(45),   dim3(256), 0, stream, lf_fea, sq);
    hipLaunchKernelGGL(k2_dist,  dim3(600),  dim3(256), 0, stream, lf_fea, sq, dist);
    hipLaunchKernelGGL(k3_topk,  dim3(2880), dim3(256), 0, stream, dist, idx);
    hipLaunchKernelGGL(kw2_conv, dim3(288),  dim3(256), 0, stream, w2, w2h);
    hipLaunchKernelGGL(k4_conv1, dim3(5760), dim3(256), 0, stream, lfV, w1, idx, a1);
    hipLaunchKernelGGL(k5m_conv3,dim3(3600), dim3(256), 0, stream, lfV, a1, w2h, outp);
}

// Round 10
// 1522.537 us; speedup vs baseline: 1.6424x; 1.0707x over previous
//
#include <hip/hip_runtime.h>
#include <stdint.h>

// Fixed problem config
#define NN   2
#define ANU  5
#define CH   64
#define HH   96
#define WW   96
#define KK   6
#define PSHh 8
#define PNHh 12
#define BB   (NN*PNHh)        // 24
#define PP   (ANU*WW)         // 480
#define CCD  (CH*ANU*PSHh)    // 2560
#define IMG_HW (HH*WW)            // 9216
#define IMG_STRIDE (CH*HH*WW)     // 589824 floats per input image
#define LFV_IMG (CH*ANU*HH)       // 30720 floats per (n,v,w) image in lfV / a1

typedef int   i32x4 __attribute__((ext_vector_type(4)));
typedef float f32x4 __attribute__((ext_vector_type(4)));

__device__ __forceinline__ unsigned short f2bf(float f) {
    unsigned int u = __float_as_uint(f);
    return (unsigned short)((u + 0x7FFFu + ((u >> 16) & 1u)) >> 16);
}

__device__ __forceinline__ void mfma_bf16_16x16x32(f32x4& d, i32x4 a, i32x4 b) {
    asm volatile("v_mfma_f32_16x16x32_bf16 %0, %1, %2, %0"
                 : "+v"(d) : "v"(a), "v"(b));
}

// pack 8 consecutive fp32 -> 8 bf16 in an i32x4 (A-fragment)
__device__ __forceinline__ i32x4 pack8(const float* p) {
    float4 lo = *(const float4*)p;
    float4 hi = *(const float4*)(p + 4);
    i32x4 r;
    r[0] = (int)((unsigned int)f2bf(lo.x) | ((unsigned int)f2bf(lo.y) << 16));
    r[1] = (int)((unsigned int)f2bf(lo.z) | ((unsigned int)f2bf(lo.w) << 16));
    r[2] = (int)((unsigned int)f2bf(hi.x) | ((unsigned int)f2bf(hi.y) << 16));
    r[3] = (int)((unsigned int)f2bf(hi.z) | ((unsigned int)f2bf(hi.w) << 16));
    return r;
}

// ---------------------------------------------------------------------------
// K0: transpose lf_fea[(n,u,v)][c][h][w] -> lfV[(n,v,w)][c][u][h]  (passing)
// ---------------------------------------------------------------------------
__global__ __launch_bounds__(256) void k0_lfv(const float* __restrict__ lf_fea,
                                              float* __restrict__ lfV) {
    int bc  = blockIdx.x;          // img*64 + c
    int img = bc >> 6;
    int c   = bc & 63;
    int n = img / 25, r = img % 25, u = r / 5, v = r % 5;
    const float* src = lf_fea + (size_t)bc * IMG_HW;
    __shared__ float tile[96][97];
    for (int e = threadIdx.x; e < 96*96; e += 256) {
        int h = e / 96, w = e % 96;
        tile[h][w] = src[e];
    }
    __syncthreads();
    size_t base = (size_t)((n*5 + v)*96) * LFV_IMG + (size_t)c*480 + u*96;
    for (int e = threadIdx.x; e < 96*96; e += 256) {
        int w = e / 96, h = e % 96;
        lfV[base + (size_t)w * LFV_IMG + h] = tile[h][w];
    }
}

// ---------------------------------------------------------------------------
// K1: sq[b][p] (fp64 accumulate)  (passing, verbatim)
// ---------------------------------------------------------------------------
__global__ __launch_bounds__(256) void k1_sq(const float* __restrict__ lf_fea,
                                             float* __restrict__ sq) {
    int rr = blockIdx.x * 256 + threadIdx.x;     // 0..11519
    int b = rr / PP, p = rr % PP;
    int n = b / PNHh, pnh = b % PNHh;
    int v = p / WW,  w = p % WW;
    double acc = 0.0;
    for (int c = 0; c < 64; ++c) {
        for (int u = 0; u < 5; ++u) {
            const float* s = lf_fea + ((size_t)((n*25 + u*5 + v)*64 + c)) * IMG_HW
                             + pnh*8*96 + w;
#pragma unroll
            for (int psh = 0; psh < 8; ++psh) {
                float x = s[psh*96];
                acc += (double)x * (double)x;
            }
        }
    }
    sq[rr] = (float)acc;
}

// ---------------------------------------------------------------------------
// K2a: partial Gram. block = (b, vr, vc, ks); K-range [ks*640, ks*640+640).
//      Same chunked-fp32 math as the proven k2; writes Gpart fp32.
// ---------------------------------------------------------------------------
__global__ __launch_bounds__(256) void k2a_gram(const float* __restrict__ lf_fea,
                                                float* __restrict__ Gpart) {
    int blk = blockIdx.x;            // b*100 + t2*4 + ks, grid 2400
    int b = blk / 100;
    int r0 = blk % 100;
    int t2 = r0 / 4, ks = r0 % 4;
    int vr = t2 / 5, vc = t2 % 5;
    int n = b / PNHh, pnh = b % PNHh;

    __shared__ float As[32][96];
    __shared__ float Bs[32][96];

    int tx = threadIdx.x & 15, ty = threadIdx.x >> 4;
    float acc[6][6] = {};

    int kbase = ks * 640;
    for (int kc0 = kbase; kc0 < kbase + 640; kc0 += 32) {
        for (int e = threadIdx.x; e < 32*96; e += 256) {
            int kci = e / 96, w = e % 96;
            int cc = kc0 + kci;
            int c = cc / 40, r2 = cc % 40, u = r2 >> 3, psh = r2 & 7;
            size_t off = ((size_t)((n*25 + u*5)*64 + c)) * IMG_HW + (pnh*8 + psh)*96 + w;
            As[kci][w] = lf_fea[off + (size_t)vr * IMG_STRIDE];
            Bs[kci][w] = lf_fea[off + (size_t)vc * IMG_STRIDE];
        }
        __syncthreads();
        float accC[6][6] = {};
#pragma unroll
        for (int kc = 0; kc < 32; ++kc) {
            float a[6], bq[6];
#pragma unroll
            for (int i = 0; i < 6; ++i) a[i]  = As[kc][ty*6 + i];
#pragma unroll
            for (int j = 0; j < 6; ++j) bq[j] = Bs[kc][tx*6 + j];
#pragma unroll
            for (int i = 0; i < 6; ++i)
#pragma unroll
                for (int j = 0; j < 6; ++j)
                    accC[i][j] = fmaf(a[i], bq[j], accC[i][j]);
        }
#pragma unroll
        for (int i = 0; i < 6; ++i)
#pragma unroll
            for (int j = 0; j < 6; ++j)
                acc[i][j] += accC[i][j];
        __syncthreads();
    }

    size_t gbase = ((size_t)(ks*600 + b*25 + t2)) * 9216;
#pragma unroll
    for (int i = 0; i < 6; ++i)
#pragma unroll
        for (int j = 0; j < 6; ++j)
            Gpart[gbase + (ty*6 + i)*96 + tx*6 + j] = acc[i][j];
}

// ---------------------------------------------------------------------------
// K2b: dist[b][p][q] = sq_p + sq_q - 2 * sum_ks Gpart   (float4 over q)
// ---------------------------------------------------------------------------
__global__ __launch_bounds__(256) void k2b_dist(const float* __restrict__ Gpart,
                                                const float* __restrict__ sq,
                                                float* __restrict__ dist) {
    int tid = blockIdx.x * 256 + threadIdx.x;   // grid 5400: exactly 1,382,400
    int b = tid / 57600;
    int r = tid % 57600;
    int p = r / 120, qt = r % 120;
    int vr = p / 96, pl = p % 96;
    int vc = qt / 24;
    int ql4 = (qt % 24) * 4;

    size_t tb = ((size_t)(b*25 + vr*5 + vc)) * 9216 + pl*96 + ql4;
    float4 g0 = *(const float4*)(Gpart + tb);
    float4 g1 = *(const float4*)(Gpart + tb +  600ull*9216);
    float4 g2 = *(const float4*)(Gpart + tb + 1200ull*9216);
    float4 g3 = *(const float4*)(Gpart + tb + 1800ull*9216);
    float gx = g0.x + g1.x + g2.x + g3.x;
    float gy = g0.y + g1.y + g2.y + g3.y;
    float gz = g0.z + g1.z + g2.z + g3.z;
    float gw = g0.w + g1.w + g2.w + g3.w;

    float  sqp = sq[b*480 + p];
    float4 sqq = *(const float4*)(sq + b*480 + vc*96 + ql4);
    float4 d;
    d.x = sqp + sqq.x - 2.0f * gx;
    d.y = sqp + sqq.y - 2.0f * gy;
    d.z = sqp + sqq.z - 2.0f * gz;
    d.w = sqp + sqq.w - 2.0f * gw;
    *(float4*)(dist + (size_t)b*230400 + (size_t)p*480 + vc*96 + ql4) = d;
}

// ---------------------------------------------------------------------------
// K3: per-row top-6  (passing, verbatim)
// ---------------------------------------------------------------------------
__global__ __launch_bounds__(256) void k3_topk(const float* __restrict__ dist,
                                               int* __restrict__ idx) {
    int wid  = (blockIdx.x * 256 + threadIdx.x) >> 6;  // global wave id
    int lane = threadIdx.x & 63;
    int b = wid / PP, p = wid % PP;
    const float* row = dist + (size_t)b * PP * PP + (size_t)p * PP;

    unsigned long long key[8];
#pragma unroll
    for (int j = 0; j < 8; ++j) {
        int q = j*64 + lane;
        if (q < PP) {
            unsigned int f = __float_as_uint(row[q]);
            unsigned int mono = f ^ ((f & 0x80000000u) ? 0xFFFFFFFFu : 0x80000000u);
            key[j] = ((unsigned long long)mono << 32) | (unsigned int)q;
        } else {
            key[j] = ~0ull;
        }
    }
    int* outp = idx + ((size_t)b*PP + p) * KK;
    for (int k = 0; k < KK; ++k) {
        unsigned long long m = key[0];
#pragma unroll
        for (int j = 1; j < 8; ++j) m = (key[j] < m) ? key[j] : m;
        for (int s = 1; s < 64; s <<= 1) {
            unsigned long long o = __shfl_xor(m, s, 64);
            m = (o < m) ? o : m;
        }
        if (lane == 0) outp[k] = (int)(m & 0xFFFFFFFFu);
#pragma unroll
        for (int j = 0; j < 8; ++j) if (key[j] == m) key[j] = ~0ull;
    }
}

// ---------------------------------------------------------------------------
// kw2: reorder w2 -> bf16 w2h[co][cc][tap][ci64] (placed in dist region, after k3)
// ---------------------------------------------------------------------------
__global__ __launch_bounds__(256) void kw2_conv(const float* __restrict__ w2,
                                                unsigned short* __restrict__ w2h) {
    int e = blockIdx.x * 256 + threadIdx.x;   // 73728 total
    if (e < 73728) {
        int co = e / 1152, r = e % 1152;
        int cc = r / 576, r2 = r % 576;
        int tap = r2 / 64, ci_l = r2 % 64;
        w2h[e] = f2bf(w2[co*1152 + (cc*64 + ci_l)*9 + tap]);
    }
}

// ---------------------------------------------------------------------------
// K4: gather + 1x1 conv via inline-asm MFMA  (passing, verbatim from r8)
// ---------------------------------------------------------------------------
__global__ __launch_bounds__(256) void k4_conv1(const float* __restrict__ lfV,
                                                const float* __restrict__ w1,
                                                const int* __restrict__ idxg,
                                                float* __restrict__ a1) {
    int blk = blockIdx.x;            // b*240 + ptile
    int b = blk / 240, ptile = blk % 240;
    int n = b / PNHh, pnh = b % PNHh;
    int p0 = ptile * 2;

    __shared__ unsigned short Bs[80][384];   // [col][k*64+c] bf16
    __shared__ int idxs[12];

    int t = threadIdx.x;
    if (t < 12) idxs[t] = idxg[(b*PP + p0 + t/6)*KK + (t % 6)];
    __syncthreads();

    for (int i = 0; i < 30; ++i) {
        int e = i * 256 + t;               // 7680 = 2*6*64*5*2
        int half = e & 1;
        int u    = (e >> 1) % 5;
        int c    = ((e >> 1) / 5) % 64;
        int k    = ((e >> 1) / 320) % 6;
        int pl   = e / 3840;
        int q = idxs[pl * 6 + k];
        const float* src = lfV
            + (size_t)((n*5 + q/96)*96 + (q%96)) * LFV_IMG
            + (size_t)c*480 + u*96 + pnh*8 + half*4;
        float4 vv = *(const float4*)src;
        int colbase = pl*40 + u*8 + half*4;
        int krow = k*64 + c;
        Bs[colbase+0][krow] = f2bf(vv.x);
        Bs[colbase+1][krow] = f2bf(vv.y);
        Bs[colbase+2][krow] = f2bf(vv.z);
        Bs[colbase+3][krow] = f2bf(vv.w);
    }
    __syncthreads();

    int lane = t & 63, wv = t >> 6;
    int l15 = lane & 15, hi = lane >> 4;
    int co0 = wv * 16;
    f32x4 acc[5] = {};
#pragma unroll
    for (int f = 0; f < 5; ++f)
        asm volatile("s_nop 1" : "+v"(acc[f]));

    const float* ap = w1 + (size_t)(co0 + l15) * 384 + hi * 8;
    for (int ks = 0; ks < 12; ++ks) {
        i32x4 a = pack8(ap + ks * 32);
        asm volatile("s_nop 1" : "+v"(a));
#pragma unroll
        for (int f = 0; f < 5; ++f) {
            i32x4 bv = *(const i32x4*)&Bs[f*16 + l15][ks*32 + hi*8];
            mfma_bf16_16x16x32(acc[f], a, bv);
        }
    }
#pragma unroll
    for (int f = 0; f < 5; ++f)
        asm volatile("s_nop 7\ns_nop 7" : "+v"(acc[f]));

#pragma unroll
    for (int f = 0; f < 5; ++f) {
        int col = f * 16 + l15;
        int pg = p0 + col / 40, rr = col % 40;
        int u = rr >> 3, psh = rr & 7;
        size_t base = (size_t)((n*5 + pg/96)*96 + (pg%96)) * LFV_IMG
                    + (size_t)u * 96 + pnh*8 + psh;
#pragma unroll
        for (int rg = 0; rg < 4; ++rg) {
            float x = acc[f][rg];
            x = x > 0.f ? x : 0.1f * x;
            a1[base + (size_t)(co0 + hi*4 + rg) * 480] = x;
        }
    }
}

// ---------------------------------------------------------------------------
// K5m: 3x3 conv over (u,h) via inline-asm MFMA  (passing, verbatim from r8)
// ---------------------------------------------------------------------------
__global__ __launch_bounds__(256) void k5m_conv3(const float* __restrict__ lfV,
                                                 const float* __restrict__ a1,
                                                 const unsigned short* __restrict__ w2h,
                                                 float* __restrict__ outp) {
    int blk = blockIdx.x;
    int wt = blk % 12; int r = blk / 12;
    int ht = r % 6;  r /= 6;
    int u  = r % 5;  r /= 5;
    int v  = r % 5;  int n = r / 5;
    int w0 = wt * 8, h0 = ht * 16;
    int imgbase = (n*5 + v) * 96 + w0;

    __shared__ unsigned short ins[432][72];   // 62,208 B

    int t = threadIdx.x;
    int lane = t & 63, wv = t >> 6, l15 = lane & 15, hi = lane >> 4;
    int co0 = wv * 16;

    f32x4 acc[8] = {};
#pragma unroll
    for (int f = 0; f < 8; ++f) asm volatile("s_nop 1" : "+v"(acc[f]));

    for (int cc = 0; cc < 2; ++cc) {
        const float* basep = cc ? a1 : lfV;
        if (cc) __syncthreads();
        // stage: e = (ci, du, w, g): aligned float4 over 4 hin, cvt bf16,
        // transpose-scatter into ins; halo rows get zeros.
        for (int i = 0; i < 36; ++i) {
            int e = i * 256 + t;              // 9216 = 64ci*3du*8w*6g
            int g  = e % 6;
            int w  = (e / 6) & 7;
            int du = (e / 48) % 3;
            int ci = e / 144;
            int uin = u + du - 1;
            int hbase = h0 - 4 + g * 4;       // aligned; chunks fully in/out
            float4 vv = {0.f, 0.f, 0.f, 0.f};
            if (uin >= 0 && uin < 5 && hbase >= 0 && hbase <= 92)
                vv = *(const float4*)(basep + (size_t)(imgbase + w) * LFV_IMG
                      + (size_t)ci * 480 + uin * 96 + hbase);
            int sbase = (w*3 + du) * 18;
            int hp0 = g*4 - 3;                // hp of vv.x
            if (hp0     >= 0 && hp0     < 18) ins[sbase + hp0    ][ci] = f2bf(vv.x);
            if (hp0 + 1 >= 0 && hp0 + 1 < 18) ins[sbase + hp0 + 1][ci] = f2bf(vv.y);
            if (hp0 + 2 >= 0 && hp0 + 2 < 18) ins[sbase + hp0 + 2][ci] = f2bf(vv.z);
            if (hp0 + 3 >= 0 && hp0 + 3 < 18) ins[sbase + hp0 + 3][ci] = f2bf(vv.w);
        }
        __syncthreads();

        const unsigned short* wp = w2h + (size_t)(co0 + l15) * 1152 + cc * 576 + hi * 8;
        for (int du = 0; du < 3; ++du)
#pragma unroll
        for (int dh = 0; dh < 3; ++dh) {
#pragma unroll
            for (int kk = 0; kk < 2; ++kk) {
                i32x4 a = *(const i32x4*)(wp + (du*3 + dh) * 64 + kk * 32);
#pragma unroll
                for (int f = 0; f < 8; ++f) {
                    int col = f * 16 + l15;
                    int s = ((col & 7)*3 + du)*18 + (col >> 3) + dh;
                    i32x4 bv = *(const i32x4*)&ins[s][kk*32 + hi*8];
                    mfma_bf16_16x16x32(acc[f], a, bv);
                }
            }
        }
    }
#pragma unroll
    for (int f = 0; f < 8; ++f)
        asm volatile("s_nop 7\ns_nop 7" : "+v"(acc[f]));

    // leaky + permuted store: out[(n*25+u*5+v)][co][h0+hl][w0+w]
    size_t ob = (size_t)((n*25 + u*5 + v) * 64) * IMG_HW;
#pragma unroll
    for (int f = 0; f < 8; ++f) {
        int col = f * 16 + l15;
        int w = col & 7, hl = col >> 3;
#pragma unroll
        for (int rg = 0; rg < 4; ++rg) {
            int co = co0 + hi * 4 + rg;
            float x = acc[f][rg];
            x = x > 0.f ? x : 0.1f * x;
            outp[ob + (size_t)co * IMG_HW + (h0 + hl) * 96 + w0 + w] = x;
        }
    }
}

// ---------------------------------------------------------------------------
extern "C" void kernel_launch(void* const* d_in, const int* in_sizes, int n_in,
                              void* d_out, int out_size, void* d_ws, size_t ws_size,
                              hipStream_t stream) {
    const float* lf_fea = (const float*)d_in[0];
    const float* w1     = (const float*)d_in[1];
    const float* w2     = (const float*)d_in[2];
    float* outp = (float*)d_out;

    char* ws = (char*)d_ws;
    // ws layout (bytes) — r8 EXACT footprint (proven in-bounds):
    //   lfV : 117,964,800  @ 0
    //   a1  : 117,964,800  @ 117,964,800   (Gpart 88,473,600 aliases its head:
    //                                       k2a/k2b finish before k4 writes a1)
    //   dist:  22,118,400  @ 235,929,600   (w2h aliases its head AFTER k3)
    //   sq  :      46,080  @ 258,048,000
    //   idx :      69,120  @ 258,094,080   (end 258,163,200)
    float* lfV   = (float*)(ws);
    float* a1    = (float*)(ws + 117964800ull);
    float* Gpart = (float*)(ws + 117964800ull);   // aliases a1 (consumed first)
    float* dist  = (float*)(ws + 235929600ull);
    float* sq    = (float*)(ws + 258048000ull);
    int*   idx   = (int*)  (ws + 258094080ull);
    unsigned short* w2h = (unsigned short*)(ws + 235929600ull);  // reuses dist

    hipLaunchKernelGGL(k0_lfv,   dim3(3200), dim3(256), 0, stream, lf_fea, lfV);
    hipLaunchKernelGGL(k1_sq,    dim3(45),   dim3(256), 0, stream, lf_fea, sq);
    hipLaunchKernelGGL(k2a_gram, dim3(2400), dim3(256), 0, stream, lf_fea, Gpart);
    hipLaunchKernelGGL(k2b_dist, dim3(5400), dim3(256), 0, stream, Gpart, sq, dist);
    hipLaunchKernelGGL(k3_topk,  dim3(2880), dim3(256), 0, stream, dist, idx);
    hipLaunchKernelGGL(kw2_conv, dim3(288),  dim3(256), 0, stream, w2, w2h);
    hipLaunchKernelGGL(k4_conv1, dim3(5760), dim3(256), 0, stream, lfV, w1, idx, a1);
    hipLaunchKernelGGL(k5m_conv3,dim3(3600), dim3(256), 0, stream, lfV, a1, w2h, outp);
}

// Round 11
// 1259.323 us; speedup vs baseline: 1.9857x; 1.2090x over previous
//
#include <hip/hip_runtime.h>
#include <stdint.h>

// Fixed problem config
#define NN   2
#define ANU  5
#define CH   64
#define HH   96
#define WW   96
#define KK   6
#define PSHh 8
#define PNHh 12
#define BB   (NN*PNHh)        // 24
#define PP   (ANU*WW)         // 480
#define CCD  (CH*ANU*PSHh)    // 2560
#define IMG_HW (HH*WW)            // 9216
#define IMG_STRIDE (CH*HH*WW)     // 589824 floats per input image
#define LFV_IMG (CH*ANU*HH)       // 30720 floats per (n,v,w) image in lfV / a1

typedef int   i32x4 __attribute__((ext_vector_type(4)));
typedef float f32x4 __attribute__((ext_vector_type(4)));

__device__ __forceinline__ unsigned short f2bf(float f) {
    unsigned int u = __float_as_uint(f);
    return (unsigned short)((u + 0x7FFFu + ((u >> 16) & 1u)) >> 16);
}

__device__ __forceinline__ void mfma_bf16_16x16x32(f32x4& d, i32x4 a, i32x4 b) {
    asm volatile("v_mfma_f32_16x16x32_bf16 %0, %1, %2, %0"
                 : "+v"(d) : "v"(a), "v"(b));
}

// pack 8 consecutive fp32 -> 8 bf16 in an i32x4 (A-fragment)
__device__ __forceinline__ i32x4 pack8(const float* p) {
    float4 lo = *(const float4*)p;
    float4 hi = *(const float4*)(p + 4);
    i32x4 r;
    r[0] = (int)((unsigned int)f2bf(lo.x) | ((unsigned int)f2bf(lo.y) << 16));
    r[1] = (int)((unsigned int)f2bf(lo.z) | ((unsigned int)f2bf(lo.w) << 16));
    r[2] = (int)((unsigned int)f2bf(hi.x) | ((unsigned int)f2bf(hi.y) << 16));
    r[3] = (int)((unsigned int)f2bf(hi.z) | ((unsigned int)f2bf(hi.w) << 16));
    return r;
}

// ---------------------------------------------------------------------------
// K0: transpose lf_fea[(n,u,v)][c][h][w] -> lfV[(n,v,w)][c][u][h]  (passing)
// ---------------------------------------------------------------------------
__global__ __launch_bounds__(256) void k0_lfv(const float* __restrict__ lf_fea,
                                              float* __restrict__ lfV) {
    int bc  = blockIdx.x;          // img*64 + c
    int img = bc >> 6;
    int c   = bc & 63;
    int n = img / 25, r = img % 25, u = r / 5, v = r % 5;
    const float* src = lf_fea + (size_t)bc * IMG_HW;
    __shared__ float tile[96][97];
    for (int e = threadIdx.x; e < 96*96; e += 256) {
        int h = e / 96, w = e % 96;
        tile[h][w] = src[e];
    }
    __syncthreads();
    size_t base = (size_t)((n*5 + v)*96) * LFV_IMG + (size_t)c*480 + u*96;
    for (int e = threadIdx.x; e < 96*96; e += 256) {
        int w = e / 96, h = e % 96;
        lfV[base + (size_t)w * LFV_IMG + h] = tile[h][w];
    }
}

// ---------------------------------------------------------------------------
// K1: sq[b][p] (fp64 accumulate), 8-way column split per row; 360 blocks
// ---------------------------------------------------------------------------
__global__ __launch_bounds__(256) void k1_sq(const float* __restrict__ lf_fea,
                                             float* __restrict__ sq) {
    int t = threadIdx.x;
    int row = blockIdx.x * 32 + (t & 31);      // 0..11519
    int cp = t >> 5;                           // 0..7
    int b = row / PP, p = row % PP;
    int n = b / PNHh, pnh = b % PNHh;
    int v = p / WW, w = p % WW;
    double acc = 0.0;
    for (int ci = 0; ci < 8; ++ci) {
        int c = cp * 8 + ci;
        for (int u = 0; u < 5; ++u) {
            const float* s = lf_fea + ((size_t)((n*25 + u*5 + v)*64 + c)) * IMG_HW
                           + pnh*8*96 + w;
#pragma unroll
            for (int psh = 0; psh < 8; ++psh) {
                float x = s[psh*96];
                acc += (double)x * (double)x;
            }
        }
    }
    __shared__ double red[256];
    red[t] = acc;
    __syncthreads();
    if (t < 32) {
        double ss = 0.0;
#pragma unroll
        for (int j = 0; j < 8; ++j) ss += red[j * 32 + t];
        sq[blockIdx.x * 32 + t] = (float)ss;
    }
}

// ---------------------------------------------------------------------------
// K2a: partial Gram, SYMMETRIC: only vr<=vc pairs computed (15 of 25);
//      off-diagonal blocks write the tile AND its transpose. K-split 4.
//      grid = 24 b x 15 pairs x 4 ks = 1440
// ---------------------------------------------------------------------------
__global__ __launch_bounds__(256) void k2a_gram(const float* __restrict__ lf_fea,
                                                float* __restrict__ Gpart) {
    const int VRt[15] = {0,0,0,0,0,1,1,1,1,2,2,2,3,3,4};
    const int VCt[15] = {0,1,2,3,4,1,2,3,4,2,3,4,3,4,4};
    int blk = blockIdx.x;            // b*60 + pr*4 + ks
    int b  = blk / 60;
    int r0 = blk % 60;
    int pr = r0 / 4, ks = r0 % 4;
    int vr = VRt[pr], vc = VCt[pr];
    int n = b / PNHh, pnh = b % PNHh;

    __shared__ float As[32][96];
    __shared__ float Bs[32][96];

    int tx = threadIdx.x & 15, ty = threadIdx.x >> 4;
    float acc[6][6] = {};

    int kbase = ks * 640;
    for (int kc0 = kbase; kc0 < kbase + 640; kc0 += 32) {
        for (int e = threadIdx.x; e < 32*96; e += 256) {
            int kci = e / 96, w = e % 96;
            int cc = kc0 + kci;
            int c = cc / 40, r2 = cc % 40, u = r2 >> 3, psh = r2 & 7;
            size_t off = ((size_t)((n*25 + u*5)*64 + c)) * IMG_HW + (pnh*8 + psh)*96 + w;
            As[kci][w] = lf_fea[off + (size_t)vr * IMG_STRIDE];
            Bs[kci][w] = lf_fea[off + (size_t)vc * IMG_STRIDE];
        }
        __syncthreads();
        float accC[6][6] = {};
#pragma unroll
        for (int kc = 0; kc < 32; ++kc) {
            float a[6], bq[6];
#pragma unroll
            for (int i = 0; i < 6; ++i) a[i]  = As[kc][ty*6 + i];
#pragma unroll
            for (int j = 0; j < 6; ++j) bq[j] = Bs[kc][tx*6 + j];
#pragma unroll
            for (int i = 0; i < 6; ++i)
#pragma unroll
                for (int j = 0; j < 6; ++j)
                    accC[i][j] = fmaf(a[i], bq[j], accC[i][j]);
        }
#pragma unroll
        for (int i = 0; i < 6; ++i)
#pragma unroll
            for (int j = 0; j < 6; ++j)
                acc[i][j] += accC[i][j];
        __syncthreads();
    }

    // write tile (vr,vc)
    size_t gbase = ((size_t)(ks*600 + b*25 + vr*5 + vc)) * 9216;
#pragma unroll
    for (int i = 0; i < 6; ++i)
#pragma unroll
        for (int j = 0; j < 6; ++j)
            Gpart[gbase + (ty*6 + i)*96 + tx*6 + j] = acc[i][j];

    // off-diagonal: also write transposed tile (vc,vr)
    if (vr != vc) {
        size_t gbt = ((size_t)(ks*600 + b*25 + vc*5 + vr)) * 9216;
#pragma unroll
        for (int i = 0; i < 6; ++i)
#pragma unroll
            for (int j = 0; j < 6; ++j)
                Gpart[gbt + (tx*6 + j)*96 + ty*6 + i] = acc[i][j];
    }
}

// ---------------------------------------------------------------------------
// K2b: dist[b][p][q] = sq_p + sq_q - 2 * sum_ks Gpart   (float4 over q)
// ---------------------------------------------------------------------------
__global__ __launch_bounds__(256) void k2b_dist(const float* __restrict__ Gpart,
                                                const float* __restrict__ sq,
                                                float* __restrict__ dist) {
    int tid = blockIdx.x * 256 + threadIdx.x;   // grid 5400: exactly 1,382,400
    int b = tid / 57600;
    int r = tid % 57600;
    int p = r / 120, qt = r % 120;
    int vr = p / 96, pl = p % 96;
    int vc = qt / 24;
    int ql4 = (qt % 24) * 4;

    size_t tb = ((size_t)(b*25 + vr*5 + vc)) * 9216 + pl*96 + ql4;
    float4 g0 = *(const float4*)(Gpart + tb);
    float4 g1 = *(const float4*)(Gpart + tb +  600ull*9216);
    float4 g2 = *(const float4*)(Gpart + tb + 1200ull*9216);
    float4 g3 = *(const float4*)(Gpart + tb + 1800ull*9216);
    float gx = g0.x + g1.x + g2.x + g3.x;
    float gy = g0.y + g1.y + g2.y + g3.y;
    float gz = g0.z + g1.z + g2.z + g3.z;
    float gw = g0.w + g1.w + g2.w + g3.w;

    float  sqp = sq[b*480 + p];
    float4 sqq = *(const float4*)(sq + b*480 + vc*96 + ql4);
    float4 d;
    d.x = sqp + sqq.x - 2.0f * gx;
    d.y = sqp + sqq.y - 2.0f * gy;
    d.z = sqp + sqq.z - 2.0f * gz;
    d.w = sqp + sqq.w - 2.0f * gw;
    *(float4*)(dist + (size_t)b*230400 + (size_t)p*480 + vc*96 + ql4) = d;
}

// ---------------------------------------------------------------------------
// K3: per-row top-6  (passing, verbatim)
// ---------------------------------------------------------------------------
__global__ __launch_bounds__(256) void k3_topk(const float* __restrict__ dist,
                                               int* __restrict__ idx) {
    int wid  = (blockIdx.x * 256 + threadIdx.x) >> 6;  // global wave id
    int lane = threadIdx.x & 63;
    int b = wid / PP, p = wid % PP;
    const float* row = dist + (size_t)b * PP * PP + (size_t)p * PP;

    unsigned long long key[8];
#pragma unroll
    for (int j = 0; j < 8; ++j) {
        int q = j*64 + lane;
        if (q < PP) {
            unsigned int f = __float_as_uint(row[q]);
            unsigned int mono = f ^ ((f & 0x80000000u) ? 0xFFFFFFFFu : 0x80000000u);
            key[j] = ((unsigned long long)mono << 32) | (unsigned int)q;
        } else {
            key[j] = ~0ull;
        }
    }
    int* outp = idx + ((size_t)b*PP + p) * KK;
    for (int k = 0; k < KK; ++k) {
        unsigned long long m = key[0];
#pragma unroll
        for (int j = 1; j < 8; ++j) m = (key[j] < m) ? key[j] : m;
        for (int s = 1; s < 64; s <<= 1) {
            unsigned long long o = __shfl_xor(m, s, 64);
            m = (o < m) ? o : m;
        }
        if (lane == 0) outp[k] = (int)(m & 0xFFFFFFFFu);
#pragma unroll
        for (int j = 0; j < 8; ++j) if (key[j] == m) key[j] = ~0ull;
    }
}

// ---------------------------------------------------------------------------
// kw2: reorder w2 -> bf16 w2h[co][cc][tap][ci64] (placed in dist region, after k3)
// ---------------------------------------------------------------------------
__global__ __launch_bounds__(256) void kw2_conv(const float* __restrict__ w2,
                                                unsigned short* __restrict__ w2h) {
    int e = blockIdx.x * 256 + threadIdx.x;   // 73728 total
    if (e < 73728) {
        int co = e / 1152, r = e % 1152;
        int cc = r / 576, r2 = r % 576;
        int tap = r2 / 64, ci_l = r2 % 64;
        w2h[e] = f2bf(w2[co*1152 + (cc*64 + ci_l)*9 + tap]);
    }
}

// ---------------------------------------------------------------------------
// K4: gather + 1x1 conv via inline-asm MFMA  (passing, verbatim from r8)
// ---------------------------------------------------------------------------
__global__ __launch_bounds__(256) void k4_conv1(const float* __restrict__ lfV,
                                                const float* __restrict__ w1,
                                                const int* __restrict__ idxg,
                                                float* __restrict__ a1) {
    int blk = blockIdx.x;            // b*240 + ptile
    int b = blk / 240, ptile = blk % 240;
    int n = b / PNHh, pnh = b % PNHh;
    int p0 = ptile * 2;

    __shared__ unsigned short Bs[80][384];   // [col][k*64+c] bf16
    __shared__ int idxs[12];

    int t = threadIdx.x;
    if (t < 12) idxs[t] = idxg[(b*PP + p0 + t/6)*KK + (t % 6)];
    __syncthreads();

    for (int i = 0; i < 30; ++i) {
        int e = i * 256 + t;               // 7680 = 2*6*64*5*2
        int half = e & 1;
        int u    = (e >> 1) % 5;
        int c    = ((e >> 1) / 5) % 64;
        int k    = ((e >> 1) / 320) % 6;
        int pl   = e / 3840;
        int q = idxs[pl * 6 + k];
        const float* src = lfV
            + (size_t)((n*5 + q/96)*96 + (q%96)) * LFV_IMG
            + (size_t)c*480 + u*96 + pnh*8 + half*4;
        float4 vv = *(const float4*)src;
        int colbase = pl*40 + u*8 + half*4;
        int krow = k*64 + c;
        Bs[colbase+0][krow] = f2bf(vv.x);
        Bs[colbase+1][krow] = f2bf(vv.y);
        Bs[colbase+2][krow] = f2bf(vv.z);
        Bs[colbase+3][krow] = f2bf(vv.w);
    }
    __syncthreads();

    int lane = t & 63, wv = t >> 6;
    int l15 = lane & 15, hi = lane >> 4;
    int co0 = wv * 16;
    f32x4 acc[5] = {};
#pragma unroll
    for (int f = 0; f < 5; ++f)
        asm volatile("s_nop 1" : "+v"(acc[f]));

    const float* ap = w1 + (size_t)(co0 + l15) * 384 + hi * 8;
    for (int ks = 0; ks < 12; ++ks) {
        i32x4 a = pack8(ap + ks * 32);
        asm volatile("s_nop 1" : "+v"(a));
#pragma unroll
        for (int f = 0; f < 5; ++f) {
            i32x4 bv = *(const i32x4*)&Bs[f*16 + l15][ks*32 + hi*8];
            mfma_bf16_16x16x32(acc[f], a, bv);
        }
    }
#pragma unroll
    for (int f = 0; f < 5; ++f)
        asm volatile("s_nop 7\ns_nop 7" : "+v"(acc[f]));

#pragma unroll
    for (int f = 0; f < 5; ++f) {
        int col = f * 16 + l15;
        int pg = p0 + col / 40, rr = col % 40;
        int u = rr >> 3, psh = rr & 7;
        size_t base = (size_t)((n*5 + pg/96)*96 + (pg%96)) * LFV_IMG
                    + (size_t)u * 96 + pnh*8 + psh;
#pragma unroll
        for (int rg = 0; rg < 4; ++rg) {
            float x = acc[f][rg];
            x = x > 0.f ? x : 0.1f * x;
            a1[base + (size_t)(co0 + hi*4 + rg) * 480] = x;
        }
    }
}

// ---------------------------------------------------------------------------
// K5m: 3x3 conv over (u,h) via inline-asm MFMA  (passing, verbatim from r8)
// ---------------------------------------------------------------------------
__global__ __launch_bounds__(256) void k5m_conv3(const float* __restrict__ lfV,
                                                 const float* __restrict__ a1,
                                                 const unsigned short* __restrict__ w2h,
                                                 float* __restrict__ outp) {
    int blk = blockIdx.x;
    int wt = blk % 12; int r = blk / 12;
    int ht = r % 6;  r /= 6;
    int u  = r % 5;  r /= 5;
    int v  = r % 5;  int n = r / 5;
    int w0 = wt * 8, h0 = ht * 16;
    int imgbase = (n*5 + v) * 96 + w0;

    __shared__ unsigned short ins[432][72];   // 62,208 B

    int t = threadIdx.x;
    int lane = t & 63, wv = t >> 6, l15 = lane & 15, hi = lane >> 4;
    int co0 = wv * 16;

    f32x4 acc[8] = {};
#pragma unroll
    for (int f = 0; f < 8; ++f) asm volatile("s_nop 1" : "+v"(acc[f]));

    for (int cc = 0; cc < 2; ++cc) {
        const float* basep = cc ? a1 : lfV;
        if (cc) __syncthreads();
        // stage: e = (ci, du, w, g): aligned float4 over 4 hin, cvt bf16,
        // transpose-scatter into ins; halo rows get zeros.
        for (int i = 0; i < 36; ++i) {
            int e = i * 256 + t;              // 9216 = 64ci*3du*8w*6g
            int g  = e % 6;
            int w  = (e / 6) & 7;
            int du = (e / 48) % 3;
            int ci = e / 144;
            int uin = u + du - 1;
            int hbase = h0 - 4 + g * 4;       // aligned; chunks fully in/out
            float4 vv = {0.f, 0.f, 0.f, 0.f};
            if (uin >= 0 && uin < 5 && hbase >= 0 && hbase <= 92)
                vv = *(const float4*)(basep + (size_t)(imgbase + w) * LFV_IMG
                      + (size_t)ci * 480 + uin * 96 + hbase);
            int sbase = (w*3 + du) * 18;
            int hp0 = g*4 - 3;                // hp of vv.x
            if (hp0     >= 0 && hp0     < 18) ins[sbase + hp0    ][ci] = f2bf(vv.x);
            if (hp0 + 1 >= 0 && hp0 + 1 < 18) ins[sbase + hp0 + 1][ci] = f2bf(vv.y);
            if (hp0 + 2 >= 0 && hp0 + 2 < 18) ins[sbase + hp0 + 2][ci] = f2bf(vv.z);
            if (hp0 + 3 >= 0 && hp0 + 3 < 18) ins[sbase + hp0 + 3][ci] = f2bf(vv.w);
        }
        __syncthreads();

        const unsigned short* wp = w2h + (size_t)(co0 + l15) * 1152 + cc * 576 + hi * 8;
        for (int du = 0; du < 3; ++du)
#pragma unroll
        for (int dh = 0; dh < 3; ++dh) {
#pragma unroll
            for (int kk = 0; kk < 2; ++kk) {
                i32x4 a = *(const i32x4*)(wp + (du*3 + dh) * 64 + kk * 32);
#pragma unroll
                for (int f = 0; f < 8; ++f) {
                    int col = f * 16 + l15;
                    int s = ((col & 7)*3 + du)*18 + (col >> 3) + dh;
                    i32x4 bv = *(const i32x4*)&ins[s][kk*32 + hi*8];
                    mfma_bf16_16x16x32(acc[f], a, bv);
                }
            }
        }
    }
#pragma unroll
    for (int f = 0; f < 8; ++f)
        asm volatile("s_nop 7\ns_nop 7" : "+v"(acc[f]));

    // leaky + permuted store: out[(n*25+u*5+v)][co][h0+hl][w0+w]
    size_t ob = (size_t)((n*25 + u*5 + v) * 64) * IMG_HW;
#pragma unroll
    for (int f = 0; f < 8; ++f) {
        int col = f * 16 + l15;
        int w = col & 7, hl = col >> 3;
#pragma unroll
        for (int rg = 0; rg < 4; ++rg) {
            int co = co0 + hi * 4 + rg;
            float x = acc[f][rg];
            x = x > 0.f ? x : 0.1f * x;
            outp[ob + (size_t)co * IMG_HW + (h0 + hl) * 96 + w0 + w] = x;
        }
    }
}

// ---------------------------------------------------------------------------
extern "C" void kernel_launch(void* const* d_in, const int* in_sizes, int n_in,
                              void* d_out, int out_size, void* d_ws, size_t ws_size,
                              hipStream_t stream) {
    const float* lf_fea = (const float*)d_in[0];
    const float* w1     = (const float*)d_in[1];
    const float* w2     = (const float*)d_in[2];
    float* outp = (float*)d_out;

    char* ws = (char*)d_ws;
    // ws layout (bytes) — r8 EXACT footprint (proven in-bounds):
    //   lfV : 117,964,800  @ 0
    //   a1  : 117,964,800  @ 117,964,800   (Gpart 88,473,600 aliases its head:
    //                                       k2a/k2b finish before k4 writes a1)
    //   dist:  22,118,400  @ 235,929,600   (w2h aliases its head AFTER k3)
    //   sq  :      46,080  @ 258,048,000
    //   idx :      69,120  @ 258,094,080   (end 258,163,200)
    float* lfV   = (float*)(ws);
    float* a1    = (float*)(ws + 117964800ull);
    float* Gpart = (float*)(ws + 117964800ull);   // aliases a1 (consumed first)
    float* dist  = (float*)(ws + 235929600ull);
    float* sq    = (float*)(ws + 258048000ull);
    int*   idx   = (int*)  (ws + 258094080ull);
    unsigned short* w2h = (unsigned short*)(ws + 235929600ull);  // reuses dist

    hipLaunchKernelGGL(k0_lfv,   dim3(3200), dim3(256), 0, stream, lf_fea, lfV);
    hipLaunchKernelGGL(k1_sq,    dim3(360),  dim3(256), 0, stream, lf_fea, sq);
    hipLaunchKernelGGL(k2a_gram, dim3(1440), dim3(256), 0, stream, lf_fea, Gpart);
    hipLaunchKernelGGL(k2b_dist, dim3(5400), dim3(256), 0, stream, Gpart, sq, dist);
    hipLaunchKernelGGL(k3_topk,  dim3(2880), dim3(256), 0, stream, dist, idx);
    hipLaunchKernelGGL(kw2_conv, dim3(288),  dim3(256), 0, stream, w2, w2h);
    hipLaunchKernelGGL(k4_conv1, dim3(5760), dim3(256), 0, stream, lfV, w1, idx, a1);
    hipLaunchKernelGGL(k5m_conv3,dim3(3600), dim3(256), 0, stream, lfV, a1, w2h, outp);
}

// Round 13
// 1250.654 us; speedup vs baseline: 1.9994x; 1.0069x over previous
//
#include <hip/hip_runtime.h>
#include <stdint.h>

// Fixed problem config
#define NN   2
#define ANU  5
#define CH   64
#define HH   96
#define WW   96
#define KK   6
#define PSHh 8
#define PNHh 12
#define BB   (NN*PNHh)        // 24
#define PP   (ANU*WW)         // 480
#define CCD  (CH*ANU*PSHh)    // 2560
#define IMG_HW (HH*WW)            // 9216
#define IMG_STRIDE (CH*HH*WW)     // 589824 floats per input image
#define LFV_IMG (CH*ANU*HH)       // 30720 floats per (n,v,w) image in lfV / a1

typedef int   i32x4 __attribute__((ext_vector_type(4)));
typedef float f32x4 __attribute__((ext_vector_type(4)));

__device__ __forceinline__ unsigned short f2bf(float f) {
    unsigned int u = __float_as_uint(f);
    return (unsigned short)((u + 0x7FFFu + ((u >> 16) & 1u)) >> 16);
}

__device__ __forceinline__ void mfma_bf16_16x16x32(f32x4& d, i32x4 a, i32x4 b) {
    asm volatile("v_mfma_f32_16x16x32_bf16 %0, %1, %2, %0"
                 : "+v"(d) : "v"(a), "v"(b));
}

// pack 8 consecutive fp32 -> 8 bf16 in an i32x4 (A-fragment)
__device__ __forceinline__ i32x4 pack8(const float* p) {
    float4 lo = *(const float4*)p;
    float4 hi = *(const float4*)(p + 4);
    i32x4 r;
    r[0] = (int)((unsigned int)f2bf(lo.x) | ((unsigned int)f2bf(lo.y) << 16));
    r[1] = (int)((unsigned int)f2bf(lo.z) | ((unsigned int)f2bf(lo.w) << 16));
    r[2] = (int)((unsigned int)f2bf(hi.x) | ((unsigned int)f2bf(hi.y) << 16));
    r[3] = (int)((unsigned int)f2bf(hi.z) | ((unsigned int)f2bf(hi.w) << 16));
    return r;
}

// ---------------------------------------------------------------------------
// K0: transpose lf_fea[(n,u,v)][c][h][w] -> lfV[(n,v,w)][c][u][h]  (passing)
// ---------------------------------------------------------------------------
__global__ __launch_bounds__(256) void k0_lfv(const float* __restrict__ lf_fea,
                                              float* __restrict__ lfV) {
    int bc  = blockIdx.x;          // img*64 + c
    int img = bc >> 6;
    int c   = bc & 63;
    int n = img / 25, r = img % 25, u = r / 5, v = r % 5;
    const float* src = lf_fea + (size_t)bc * IMG_HW;
    __shared__ float tile[96][97];
    for (int e = threadIdx.x; e < 96*96; e += 256) {
        int h = e / 96, w = e % 96;
        tile[h][w] = src[e];
    }
    __syncthreads();
    size_t base = (size_t)((n*5 + v)*96) * LFV_IMG + (size_t)c*480 + u*96;
    for (int e = threadIdx.x; e < 96*96; e += 256) {
        int w = e / 96, h = e % 96;
        lfV[base + (size_t)w * LFV_IMG + h] = tile[h][w];
    }
}

// ---------------------------------------------------------------------------
// K1: sq[b][p] (fp64 accumulate), 8-way column split per row; 360 blocks
// ---------------------------------------------------------------------------
__global__ __launch_bounds__(256) void k1_sq(const float* __restrict__ lf_fea,
                                             float* __restrict__ sq) {
    int t = threadIdx.x;
    int row = blockIdx.x * 32 + (t & 31);      // 0..11519
    int cp = t >> 5;                           // 0..7
    int b = row / PP, p = row % PP;
    int n = b / PNHh, pnh = b % PNHh;
    int v = p / WW, w = p % WW;
    double acc = 0.0;
    for (int ci = 0; ci < 8; ++ci) {
        int c = cp * 8 + ci;
        for (int u = 0; u < 5; ++u) {
            const float* s = lf_fea + ((size_t)((n*25 + u*5 + v)*64 + c)) * IMG_HW
                           + pnh*8*96 + w;
#pragma unroll
            for (int psh = 0; psh < 8; ++psh) {
                float x = s[psh*96];
                acc += (double)x * (double)x;
            }
        }
    }
    __shared__ double red[256];
    red[t] = acc;
    __syncthreads();
    if (t < 32) {
        double ss = 0.0;
#pragma unroll
        for (int j = 0; j < 8; ++j) ss += red[j * 32 + t];
        sq[blockIdx.x * 32 + t] = (float)ss;
    }
}

// ---------------------------------------------------------------------------
// K2a: partial Gram, symmetric (vr<=vc), K-split 4; grid 1440  (r11 verbatim)
// ---------------------------------------------------------------------------
__global__ __launch_bounds__(256) void k2a_gram(const float* __restrict__ lf_fea,
                                                float* __restrict__ Gpart) {
    const int VRt[15] = {0,0,0,0,0,1,1,1,1,2,2,2,3,3,4};
    const int VCt[15] = {0,1,2,3,4,1,2,3,4,2,3,4,3,4,4};
    int blk = blockIdx.x;            // b*60 + pr*4 + ks
    int b  = blk / 60;
    int r0 = blk % 60;
    int pr = r0 / 4, ks = r0 % 4;
    int vr = VRt[pr], vc = VCt[pr];
    int n = b / PNHh, pnh = b % PNHh;

    __shared__ float As[32][96];
    __shared__ float Bs[32][96];

    int tx = threadIdx.x & 15, ty = threadIdx.x >> 4;
    float acc[6][6] = {};

    int kbase = ks * 640;
    for (int kc0 = kbase; kc0 < kbase + 640; kc0 += 32) {
        for (int e = threadIdx.x; e < 32*96; e += 256) {
            int kci = e / 96, w = e % 96;
            int cc = kc0 + kci;
            int c = cc / 40, r2 = cc % 40, u = r2 >> 3, psh = r2 & 7;
            size_t off = ((size_t)((n*25 + u*5)*64 + c)) * IMG_HW + (pnh*8 + psh)*96 + w;
            As[kci][w] = lf_fea[off + (size_t)vr * IMG_STRIDE];
            Bs[kci][w] = lf_fea[off + (size_t)vc * IMG_STRIDE];
        }
        __syncthreads();
        float accC[6][6] = {};
#pragma unroll
        for (int kc = 0; kc < 32; ++kc) {
            float a[6], bq[6];
#pragma unroll
            for (int i = 0; i < 6; ++i) a[i]  = As[kc][ty*6 + i];
#pragma unroll
            for (int j = 0; j < 6; ++j) bq[j] = Bs[kc][tx*6 + j];
#pragma unroll
            for (int i = 0; i < 6; ++i)
#pragma unroll
                for (int j = 0; j < 6; ++j)
                    accC[i][j] = fmaf(a[i], bq[j], accC[i][j]);
        }
#pragma unroll
        for (int i = 0; i < 6; ++i)
#pragma unroll
            for (int j = 0; j < 6; ++j)
                acc[i][j] += accC[i][j];
        __syncthreads();
    }

    size_t gbase = ((size_t)(ks*600 + b*25 + vr*5 + vc)) * 9216;
#pragma unroll
    for (int i = 0; i < 6; ++i)
#pragma unroll
        for (int j = 0; j < 6; ++j)
            Gpart[gbase + (ty*6 + i)*96 + tx*6 + j] = acc[i][j];

    if (vr != vc) {
        size_t gbt = ((size_t)(ks*600 + b*25 + vc*5 + vr)) * 9216;
#pragma unroll
        for (int i = 0; i < 6; ++i)
#pragma unroll
            for (int j = 0; j < 6; ++j)
                Gpart[gbt + (tx*6 + j)*96 + ty*6 + i] = acc[i][j];
    }
}

// ---------------------------------------------------------------------------
// K2b: dist[b][p][q] = sq_p + sq_q - 2 * sum_ks Gpart   (r11 verbatim)
// ---------------------------------------------------------------------------
__global__ __launch_bounds__(256) void k2b_dist(const float* __restrict__ Gpart,
                                                const float* __restrict__ sq,
                                                float* __restrict__ dist) {
    int tid = blockIdx.x * 256 + threadIdx.x;   // grid 5400: exactly 1,382,400
    int b = tid / 57600;
    int r = tid % 57600;
    int p = r / 120, qt = r % 120;
    int vr = p / 96, pl = p % 96;
    int vc = qt / 24;
    int ql4 = (qt % 24) * 4;

    size_t tb = ((size_t)(b*25 + vr*5 + vc)) * 9216 + pl*96 + ql4;
    float4 g0 = *(const float4*)(Gpart + tb);
    float4 g1 = *(const float4*)(Gpart + tb +  600ull*9216);
    float4 g2 = *(const float4*)(Gpart + tb + 1200ull*9216);
    float4 g3 = *(const float4*)(Gpart + tb + 1800ull*9216);
    float gx = g0.x + g1.x + g2.x + g3.x;
    float gy = g0.y + g1.y + g2.y + g3.y;
    float gz = g0.z + g1.z + g2.z + g3.z;
    float gw = g0.w + g1.w + g2.w + g3.w;

    float  sqp = sq[b*480 + p];
    float4 sqq = *(const float4*)(sq + b*480 + vc*96 + ql4);
    float4 d;
    d.x = sqp + sqq.x - 2.0f * gx;
    d.y = sqp + sqq.y - 2.0f * gy;
    d.z = sqp + sqq.z - 2.0f * gz;
    d.w = sqp + sqq.w - 2.0f * gw;
    *(float4*)(dist + (size_t)b*230400 + (size_t)p*480 + vc*96 + ql4) = d;
}

// ---------------------------------------------------------------------------
// K3: per-row top-6  (passing, verbatim)
// ---------------------------------------------------------------------------
__global__ __launch_bounds__(256) void k3_topk(const float* __restrict__ dist,
                                               int* __restrict__ idx) {
    int wid  = (blockIdx.x * 256 + threadIdx.x) >> 6;  // global wave id
    int lane = threadIdx.x & 63;
    int b = wid / PP, p = wid % PP;
    const float* row = dist + (size_t)b * PP * PP + (size_t)p * PP;

    unsigned long long key[8];
#pragma unroll
    for (int j = 0; j < 8; ++j) {
        int q = j*64 + lane;
        if (q < PP) {
            unsigned int f = __float_as_uint(row[q]);
            unsigned int mono = f ^ ((f & 0x80000000u) ? 0xFFFFFFFFu : 0x80000000u);
            key[j] = ((unsigned long long)mono << 32) | (unsigned int)q;
        } else {
            key[j] = ~0ull;
        }
    }
    int* outp = idx + ((size_t)b*PP + p) * KK;
    for (int k = 0; k < KK; ++k) {
        unsigned long long m = key[0];
#pragma unroll
        for (int j = 1; j < 8; ++j) m = (key[j] < m) ? key[j] : m;
        for (int s = 1; s < 64; s <<= 1) {
            unsigned long long o = __shfl_xor(m, s, 64);
            m = (o < m) ? o : m;
        }
        if (lane == 0) outp[k] = (int)(m & 0xFFFFFFFFu);
#pragma unroll
        for (int j = 0; j < 8; ++j) if (key[j] == m) key[j] = ~0ull;
    }
}

// ---------------------------------------------------------------------------
// kw2: reorder w2 -> bf16 w2h[co][cc][tap][ci64] (placed in dist region, after k3)
// ---------------------------------------------------------------------------
__global__ __launch_bounds__(256) void kw2_conv(const float* __restrict__ w2,
                                                unsigned short* __restrict__ w2h) {
    int e = blockIdx.x * 256 + threadIdx.x;   // 73728 total
    if (e < 73728) {
        int co = e / 1152, r = e % 1152;
        int cc = r / 576, r2 = r % 576;
        int tap = r2 / 64, ci_l = r2 % 64;
        w2h[e] = f2bf(w2[co*1152 + (cc*64 + ci_l)*9 + tap]);
    }
}

// ---------------------------------------------------------------------------
// K4: gather + 1x1 conv via inline-asm MFMA (r8/r11 core; LDS chunk indices
//     XOR-swizzled by (col&7) so b128 read banks = 4*((chunk&7)^(col&7))).
//     Scalar u16 stores only (proven construct class).
// ---------------------------------------------------------------------------
__global__ __launch_bounds__(256) void k4_conv1(const float* __restrict__ lfV,
                                                const float* __restrict__ w1,
                                                const int* __restrict__ idxg,
                                                float* __restrict__ a1) {
    int blk = blockIdx.x;            // b*240 + ptile
    int b = blk / 240, ptile = blk % 240;
    int n = b / PNHh, pnh = b % PNHh;
    int p0 = ptile * 2;

    __shared__ unsigned short Bs[80][384];   // [col][swizzled krow] bf16
    __shared__ int idxs[12];

    int t = threadIdx.x;
    if (t < 12) idxs[t] = idxg[(b*PP + p0 + t/6)*KK + (t % 6)];
    __syncthreads();

    for (int i = 0; i < 30; ++i) {
        int e = i * 256 + t;               // 7680 = 2*6*64*5*2
        int half = e & 1;
        int u    = (e >> 1) % 5;
        int c    = ((e >> 1) / 5) % 64;
        int k    = ((e >> 1) / 320) % 6;
        int pl   = e / 3840;
        int q = idxs[pl * 6 + k];
        const float* src = lfV
            + (size_t)((n*5 + q/96)*96 + (q%96)) * LFV_IMG
            + (size_t)c*480 + u*96 + pnh*8 + half*4;
        float4 vv = *(const float4*)src;
        int colbase = pl*40 + u*8 + half*4;
        int krow = k*64 + c;
        int kc = krow >> 3, kl = krow & 7;   // chunk 0..47, low 0..7
        // swizzled position per destination column: chunk low-3-bits ^ (col&7)
        int c0 = colbase + 0, c1 = colbase + 1, c2 = colbase + 2, c3 = colbase + 3;
        Bs[c0][(((kc & ~7) | ((kc & 7) ^ (c0 & 7))) << 3) | kl] = f2bf(vv.x);
        Bs[c1][(((kc & ~7) | ((kc & 7) ^ (c1 & 7))) << 3) | kl] = f2bf(vv.y);
        Bs[c2][(((kc & ~7) | ((kc & 7) ^ (c2 & 7))) << 3) | kl] = f2bf(vv.z);
        Bs[c3][(((kc & ~7) | ((kc & 7) ^ (c3 & 7))) << 3) | kl] = f2bf(vv.w);
    }
    __syncthreads();

    int lane = t & 63, wv = t >> 6;
    int l15 = lane & 15, hi = lane >> 4;
    int co0 = wv * 16;
    f32x4 acc[5] = {};
#pragma unroll
    for (int f = 0; f < 5; ++f)
        asm volatile("s_nop 1" : "+v"(acc[f]));

    const float* ap = w1 + (size_t)(co0 + l15) * 384 + hi * 8;
    for (int ks = 0; ks < 12; ++ks) {
        i32x4 a = pack8(ap + ks * 32);
        asm volatile("s_nop 1" : "+v"(a));
#pragma unroll
        for (int f = 0; f < 5; ++f) {
            int col = f * 16 + l15;
            int ch = ks * 4 + hi;            // chunk 0..47
            int chs = (ch & ~7) | ((ch & 7) ^ (col & 7));
            i32x4 bv = *(const i32x4*)&Bs[col][chs << 3];
            mfma_bf16_16x16x32(acc[f], a, bv);
        }
    }
#pragma unroll
    for (int f = 0; f < 5; ++f)
        asm volatile("s_nop 7\ns_nop 7" : "+v"(acc[f]));

#pragma unroll
    for (int f = 0; f < 5; ++f) {
        int col = f * 16 + l15;
        int pg = p0 + col / 40, rr = col % 40;
        int u = rr >> 3, psh = rr & 7;
        size_t base = (size_t)((n*5 + pg/96)*96 + (pg%96)) * LFV_IMG
                    + (size_t)u * 96 + pnh*8 + psh;
#pragma unroll
        for (int rg = 0; rg < 4; ++rg) {
            float x = acc[f][rg];
            x = x > 0.f ? x : 0.1f * x;
            a1[base + (size_t)(co0 + hi*4 + rg) * 480] = x;
        }
    }
}

// ---------------------------------------------------------------------------
// K5m: 3x3 conv via inline-asm MFMA (r8/r11 core; LDS rows now 64 shorts =
//      128B pitch, chunk XOR-swizzled by (s&7): read banks fully spread).
//      Scalar u16 stores only.
// ---------------------------------------------------------------------------
__global__ __launch_bounds__(256) void k5m_conv3(const float* __restrict__ lfV,
                                                 const float* __restrict__ a1,
                                                 const unsigned short* __restrict__ w2h,
                                                 float* __restrict__ outp) {
    int blk = blockIdx.x;
    int wt = blk % 12; int r = blk / 12;
    int ht = r % 6;  r /= 6;
    int u  = r % 5;  r /= 5;
    int v  = r % 5;  int n = r / 5;
    int w0 = wt * 8, h0 = ht * 16;
    int imgbase = (n*5 + v) * 96 + w0;

    __shared__ unsigned short ins[432][64];   // 55,296 B; 128B row pitch

    int t = threadIdx.x;
    int lane = t & 63, wv = t >> 6, l15 = lane & 15, hi = lane >> 4;
    int co0 = wv * 16;

    f32x4 acc[8] = {};
#pragma unroll
    for (int f = 0; f < 8; ++f) asm volatile("s_nop 1" : "+v"(acc[f]));

    for (int cc = 0; cc < 2; ++cc) {
        const float* basep = cc ? a1 : lfV;
        if (cc) __syncthreads();
        // stage: e = (ci, du, w, g): aligned float4 over 4 hin, cvt bf16,
        // transpose-scatter with chunk^=(s&7) swizzle; halo rows get zeros.
        for (int i = 0; i < 36; ++i) {
            int e = i * 256 + t;              // 9216 = 64ci*3du*8w*6g
            int g  = e % 6;
            int w  = (e / 6) & 7;
            int du = (e / 48) % 3;
            int ci = e / 144;
            int uin = u + du - 1;
            int hbase = h0 - 4 + g * 4;       // aligned; chunks fully in/out
            float4 vv = {0.f, 0.f, 0.f, 0.f};
            if (uin >= 0 && uin < 5 && hbase >= 0 && hbase <= 92)
                vv = *(const float4*)(basep + (size_t)(imgbase + w) * LFV_IMG
                      + (size_t)ci * 480 + uin * 96 + hbase);
            int sbase = (w*3 + du) * 18;
            int hp0 = g*4 - 3;                // hp of vv.x
            int cch = ci >> 3, clo = ci & 7;
            if (hp0 >= 0 && hp0 < 18) {
                int s = sbase + hp0;
                ins[s][((cch ^ (s & 7)) << 3) | clo] = f2bf(vv.x);
            }
            if (hp0 + 1 >= 0 && hp0 + 1 < 18) {
                int s = sbase + hp0 + 1;
                ins[s][((cch ^ (s & 7)) << 3) | clo] = f2bf(vv.y);
            }
            if (hp0 + 2 >= 0 && hp0 + 2 < 18) {
                int s = sbase + hp0 + 2;
                ins[s][((cch ^ (s & 7)) << 3) | clo] = f2bf(vv.z);
            }
            if (hp0 + 3 >= 0 && hp0 + 3 < 18) {
                int s = sbase + hp0 + 3;
                ins[s][((cch ^ (s & 7)) << 3) | clo] = f2bf(vv.w);
            }
        }
        __syncthreads();

        const unsigned short* wp = w2h + (size_t)(co0 + l15) * 1152 + cc * 576 + hi * 8;
        for (int du = 0; du < 3; ++du)
#pragma unroll
        for (int dh = 0; dh < 3; ++dh) {
#pragma unroll
            for (int kk = 0; kk < 2; ++kk) {
                i32x4 a = *(const i32x4*)(wp + (du*3 + dh) * 64 + kk * 32);
#pragma unroll
                for (int f = 0; f < 8; ++f) {
                    int col = f * 16 + l15;
                    int s = ((col & 7)*3 + du)*18 + (col >> 3) + dh;
                    i32x4 bv = *(const i32x4*)&ins[s][((kk*4 + hi) ^ (s & 7)) << 3];
                    mfma_bf16_16x16x32(acc[f], a, bv);
                }
            }
        }
        if (!cc) __syncthreads();   // protect ins reuse before second stage
    }
#pragma unroll
    for (int f = 0; f < 8; ++f)
        asm volatile("s_nop 7\ns_nop 7" : "+v"(acc[f]));

    // leaky + permuted store: out[(n*25+u*5+v)][co][h0+hl][w0+w]
    size_t ob = (size_t)((n*25 + u*5 + v) * 64) * IMG_HW;
#pragma unroll
    for (int f = 0; f < 8; ++f) {
        int col = f * 16 + l15;
        int w = col & 7, hl = col >> 3;
#pragma unroll
        for (int rg = 0; rg < 4; ++rg) {
            int co = co0 + hi * 4 + rg;
            float x = acc[f][rg];
            x = x > 0.f ? x : 0.1f * x;
            outp[ob + (size_t)co * IMG_HW + (h0 + hl) * 96 + w0 + w] = x;
        }
    }
}

// ---------------------------------------------------------------------------
extern "C" void kernel_launch(void* const* d_in, const int* in_sizes, int n_in,
                              void* d_out, int out_size, void* d_ws, size_t ws_size,
                              hipStream_t stream) {
    const float* lf_fea = (const float*)d_in[0];
    const float* w1     = (const float*)d_in[1];
    const float* w2     = (const float*)d_in[2];
    float* outp = (float*)d_out;

    char* ws = (char*)d_ws;
    // ws layout (bytes) — r8/r11 EXACT footprint (proven in-bounds):
    //   lfV : 117,964,800  @ 0
    //   a1  : 117,964,800  @ 117,964,800   (Gpart 88,473,600 aliases its head:
    //                                       k2a/k2b finish before k4 writes a1)
    //   dist:  22,118,400  @ 235,929,600   (w2h aliases its head AFTER k3)
    //   sq  :      46,080  @ 258,048,000
    //   idx :      69,120  @ 258,094,080   (end 258,163,200)
    float* lfV   = (float*)(ws);
    float* a1    = (float*)(ws + 117964800ull);
    float* Gpart = (float*)(ws + 117964800ull);   // aliases a1 (consumed first)
    float* dist  = (float*)(ws + 235929600ull);
    float* sq    = (float*)(ws + 258048000ull);
    int*   idx   = (int*)  (ws + 258094080ull);
    unsigned short* w2h = (unsigned short*)(ws + 235929600ull);  // reuses dist

    hipLaunchKernelGGL(k0_lfv,   dim3(3200), dim3(256), 0, stream, lf_fea, lfV);
    hipLaunchKernelGGL(k1_sq,    dim3(360),  dim3(256), 0, stream, lf_fea, sq);
    hipLaunchKernelGGL(k2a_gram, dim3(1440), dim3(256), 0, stream, lf_fea, Gpart);
    hipLaunchKernelGGL(k2b_dist, dim3(5400), dim3(256), 0, stream, Gpart, sq, dist);
    hipLaunchKernelGGL(k3_topk,  dim3(2880), dim3(256), 0, stream, dist, idx);
    hipLaunchKernelGGL(kw2_conv, dim3(288),  dim3(256), 0, stream, w2, w2h);
    hipLaunchKernelGGL(k4_conv1, dim3(5760), dim3(256), 0, stream, lfV, w1, idx, a1);
    hipLaunchKernelGGL(k5m_conv3,dim3(3600), dim3(256), 0, stream, lfV, a1, w2h, outp);
}

// Round 15
// 1050.071 us; speedup vs baseline: 2.3813x; 1.1910x over previous
//
#include <hip/hip_runtime.h>
#include <stdint.h>

// Fixed problem config
#define NN   2
#define ANU  5
#define CH   64
#define HH   96
#define WW   96
#define KK   6
#define PSHh 8
#define PNHh 12
#define BB   (NN*PNHh)        // 24
#define PP   (ANU*WW)         // 480
#define CCD  (CH*ANU*PSHh)    // 2560
#define IMG_HW (HH*WW)            // 9216
#define IMG_STRIDE (CH*HH*WW)     // 589824 floats per input image
#define LFV_IMG (CH*ANU*HH)       // 30720 floats per (n,v,w) image in lfV / a1

typedef int   i32x4 __attribute__((ext_vector_type(4)));
typedef float f32x4 __attribute__((ext_vector_type(4)));

__device__ __forceinline__ unsigned short f2bf(float f) {
    unsigned int u = __float_as_uint(f);
    return (unsigned short)((u + 0x7FFFu + ((u >> 16) & 1u)) >> 16);
}

__device__ __forceinline__ void mfma_bf16_16x16x32(f32x4& d, i32x4 a, i32x4 b) {
    asm volatile("v_mfma_f32_16x16x32_bf16 %0, %1, %2, %0"
                 : "+v"(d) : "v"(a), "v"(b));
}

// pack 8 consecutive fp32 -> 8 bf16 in an i32x4 (A-fragment)
__device__ __forceinline__ i32x4 pack8(const float* p) {
    float4 lo = *(const float4*)p;
    float4 hi = *(const float4*)(p + 4);
    i32x4 r;
    r[0] = (int)((unsigned int)f2bf(lo.x) | ((unsigned int)f2bf(lo.y) << 16));
    r[1] = (int)((unsigned int)f2bf(lo.z) | ((unsigned int)f2bf(lo.w) << 16));
    r[2] = (int)((unsigned int)f2bf(hi.x) | ((unsigned int)f2bf(hi.y) << 16));
    r[3] = (int)((unsigned int)f2bf(hi.z) | ((unsigned int)f2bf(hi.w) << 16));
    return r;
}

// ---------------------------------------------------------------------------
// K0: transpose lf_fea[(n,u,v)][c][h][w] -> lfV[(n,v,w)][c][u][h]  (passing)
// ---------------------------------------------------------------------------
__global__ __launch_bounds__(256) void k0_lfv(const float* __restrict__ lf_fea,
                                              float* __restrict__ lfV) {
    int bc  = blockIdx.x;          // img*64 + c
    int img = bc >> 6;
    int c   = bc & 63;
    int n = img / 25, r = img % 25, u = r / 5, v = r % 5;
    const float* src = lf_fea + (size_t)bc * IMG_HW;
    __shared__ float tile[96][97];
    for (int e = threadIdx.x; e < 96*96; e += 256) {
        int h = e / 96, w = e % 96;
        tile[h][w] = src[e];
    }
    __syncthreads();
    size_t base = (size_t)((n*5 + v)*96) * LFV_IMG + (size_t)c*480 + u*96;
    for (int e = threadIdx.x; e < 96*96; e += 256) {
        int w = e / 96, h = e % 96;
        lfV[base + (size_t)w * LFV_IMG + h] = tile[h][w];
    }
}

// ---------------------------------------------------------------------------
// K1: sq[b][p] (fp64 accumulate), 8-way column split per row; 360 blocks
// ---------------------------------------------------------------------------
__global__ __launch_bounds__(256) void k1_sq(const float* __restrict__ lf_fea,
                                             float* __restrict__ sq) {
    int t = threadIdx.x;
    int row = blockIdx.x * 32 + (t & 31);      // 0..11519
    int cp = t >> 5;                           // 0..7
    int b = row / PP, p = row % PP;
    int n = b / PNHh, pnh = b % PNHh;
    int v = p / WW, w = p % WW;
    double acc = 0.0;
    for (int ci = 0; ci < 8; ++ci) {
        int c = cp * 8 + ci;
        for (int u = 0; u < 5; ++u) {
            const float* s = lf_fea + ((size_t)((n*25 + u*5 + v)*64 + c)) * IMG_HW
                           + pnh*8*96 + w;
#pragma unroll
            for (int psh = 0; psh < 8; ++psh) {
                float x = s[psh*96];
                acc += (double)x * (double)x;
            }
        }
    }
    __shared__ double red[256];
    red[t] = acc;
    __syncthreads();
    if (t < 32) {
        double ss = 0.0;
#pragma unroll
        for (int j = 0; j < 8; ++j) ss += red[j * 32 + t];
        sq[blockIdx.x * 32 + t] = (float)ss;
    }
}

// ---------------------------------------------------------------------------
// K2a: partial Gram, symmetric (vr<=vc), K-split 4; grid 1440  (r11 verbatim)
// ---------------------------------------------------------------------------
__global__ __launch_bounds__(256) void k2a_gram(const float* __restrict__ lf_fea,
                                                float* __restrict__ Gpart) {
    const int VRt[15] = {0,0,0,0,0,1,1,1,1,2,2,2,3,3,4};
    const int VCt[15] = {0,1,2,3,4,1,2,3,4,2,3,4,3,4,4};
    int blk = blockIdx.x;            // b*60 + pr*4 + ks
    int b  = blk / 60;
    int r0 = blk % 60;
    int pr = r0 / 4, ks = r0 % 4;
    int vr = VRt[pr], vc = VCt[pr];
    int n = b / PNHh, pnh = b % PNHh;

    __shared__ float As[32][96];
    __shared__ float Bs[32][96];

    int tx = threadIdx.x & 15, ty = threadIdx.x >> 4;
    float acc[6][6] = {};

    int kbase = ks * 640;
    for (int kc0 = kbase; kc0 < kbase + 640; kc0 += 32) {
        for (int e = threadIdx.x; e < 32*96; e += 256) {
            int kci = e / 96, w = e % 96;
            int cc = kc0 + kci;
            int c = cc / 40, r2 = cc % 40, u = r2 >> 3, psh = r2 & 7;
            size_t off = ((size_t)((n*25 + u*5)*64 + c)) * IMG_HW + (pnh*8 + psh)*96 + w;
            As[kci][w] = lf_fea[off + (size_t)vr * IMG_STRIDE];
            Bs[kci][w] = lf_fea[off + (size_t)vc * IMG_STRIDE];
        }
        __syncthreads();
        float accC[6][6] = {};
#pragma unroll
        for (int kc = 0; kc < 32; ++kc) {
            float a[6], bq[6];
#pragma unroll
            for (int i = 0; i < 6; ++i) a[i]  = As[kc][ty*6 + i];
#pragma unroll
            for (int j = 0; j < 6; ++j) bq[j] = Bs[kc][tx*6 + j];
#pragma unroll
            for (int i = 0; i < 6; ++i)
#pragma unroll
                for (int j = 0; j < 6; ++j)
                    accC[i][j] = fmaf(a[i], bq[j], accC[i][j]);
        }
#pragma unroll
        for (int i = 0; i < 6; ++i)
#pragma unroll
            for (int j = 0; j < 6; ++j)
                acc[i][j] += accC[i][j];
        __syncthreads();
    }

    size_t gbase = ((size_t)(ks*600 + b*25 + vr*5 + vc)) * 9216;
#pragma unroll
    for (int i = 0; i < 6; ++i)
#pragma unroll
        for (int j = 0; j < 6; ++j)
            Gpart[gbase + (ty*6 + i)*96 + tx*6 + j] = acc[i][j];

    if (vr != vc) {
        size_t gbt = ((size_t)(ks*600 + b*25 + vc*5 + vr)) * 9216;
#pragma unroll
        for (int i = 0; i < 6; ++i)
#pragma unroll
            for (int j = 0; j < 6; ++j)
                Gpart[gbt + (tx*6 + j)*96 + ty*6 + i] = acc[i][j];
    }
}

// ---------------------------------------------------------------------------
// K2b: dist[b][p][q] = sq_p + sq_q - 2 * sum_ks Gpart   (r11 verbatim)
// ---------------------------------------------------------------------------
__global__ __launch_bounds__(256) void k2b_dist(const float* __restrict__ Gpart,
                                                const float* __restrict__ sq,
                                                float* __restrict__ dist) {
    int tid = blockIdx.x * 256 + threadIdx.x;   // grid 5400: exactly 1,382,400
    int b = tid / 57600;
    int r = tid % 57600;
    int p = r / 120, qt = r % 120;
    int vr = p / 96, pl = p % 96;
    int vc = qt / 24;
    int ql4 = (qt % 24) * 4;

    size_t tb = ((size_t)(b*25 + vr*5 + vc)) * 9216 + pl*96 + ql4;
    float4 g0 = *(const float4*)(Gpart + tb);
    float4 g1 = *(const float4*)(Gpart + tb +  600ull*9216);
    float4 g2 = *(const float4*)(Gpart + tb + 1200ull*9216);
    float4 g3 = *(const float4*)(Gpart + tb + 1800ull*9216);
    float gx = g0.x + g1.x + g2.x + g3.x;
    float gy = g0.y + g1.y + g2.y + g3.y;
    float gz = g0.z + g1.z + g2.z + g3.z;
    float gw = g0.w + g1.w + g2.w + g3.w;

    float  sqp = sq[b*480 + p];
    float4 sqq = *(const float4*)(sq + b*480 + vc*96 + ql4);
    float4 d;
    d.x = sqp + sqq.x - 2.0f * gx;
    d.y = sqp + sqq.y - 2.0f * gy;
    d.z = sqp + sqq.z - 2.0f * gz;
    d.w = sqp + sqq.w - 2.0f * gw;
    *(float4*)(dist + (size_t)b*230400 + (size_t)p*480 + vc*96 + ql4) = d;
}

// ---------------------------------------------------------------------------
// K3: per-row top-6  (passing, verbatim)
// ---------------------------------------------------------------------------
__global__ __launch_bounds__(256) void k3_topk(const float* __restrict__ dist,
                                               int* __restrict__ idx) {
    int wid  = (blockIdx.x * 256 + threadIdx.x) >> 6;  // global wave id
    int lane = threadIdx.x & 63;
    int b = wid / PP, p = wid % PP;
    const float* row = dist + (size_t)b * PP * PP + (size_t)p * PP;

    unsigned long long key[8];
#pragma unroll
    for (int j = 0; j < 8; ++j) {
        int q = j*64 + lane;
        if (q < PP) {
            unsigned int f = __float_as_uint(row[q]);
            unsigned int mono = f ^ ((f & 0x80000000u) ? 0xFFFFFFFFu : 0x80000000u);
            key[j] = ((unsigned long long)mono << 32) | (unsigned int)q;
        } else {
            key[j] = ~0ull;
        }
    }
    int* outp = idx + ((size_t)b*PP + p) * KK;
    for (int k = 0; k < KK; ++k) {
        unsigned long long m = key[0];
#pragma unroll
        for (int j = 1; j < 8; ++j) m = (key[j] < m) ? key[j] : m;
        for (int s = 1; s < 64; s <<= 1) {
            unsigned long long o = __shfl_xor(m, s, 64);
            m = (o < m) ? o : m;
        }
        if (lane == 0) outp[k] = (int)(m & 0xFFFFFFFFu);
#pragma unroll
        for (int j = 0; j < 8; ++j) if (key[j] == m) key[j] = ~0ull;
    }
}

// ---------------------------------------------------------------------------
// kw2: reorder w2 -> bf16 w2h[co][cc][tap][ci64] (placed in dist region, after k3)
// ---------------------------------------------------------------------------
__global__ __launch_bounds__(256) void kw2_conv(const float* __restrict__ w2,
                                                unsigned short* __restrict__ w2h) {
    int e = blockIdx.x * 256 + threadIdx.x;   // 73728 total
    if (e < 73728) {
        int co = e / 1152, r = e % 1152;
        int cc = r / 576, r2 = r % 576;
        int tap = r2 / 64, ci_l = r2 % 64;
        w2h[e] = f2bf(w2[co*1152 + (cc*64 + ci_l)*9 + tap]);
    }
}

// ---------------------------------------------------------------------------
// K4: gather + 1x1 conv via inline-asm MFMA  (r13 verbatim, passing)
// ---------------------------------------------------------------------------
__global__ __launch_bounds__(256) void k4_conv1(const float* __restrict__ lfV,
                                                const float* __restrict__ w1,
                                                const int* __restrict__ idxg,
                                                float* __restrict__ a1) {
    int blk = blockIdx.x;            // b*240 + ptile
    int b = blk / 240, ptile = blk % 240;
    int n = b / PNHh, pnh = b % PNHh;
    int p0 = ptile * 2;

    __shared__ unsigned short Bs[80][384];   // [col][swizzled krow] bf16
    __shared__ int idxs[12];

    int t = threadIdx.x;
    if (t < 12) idxs[t] = idxg[(b*PP + p0 + t/6)*KK + (t % 6)];
    __syncthreads();

    for (int i = 0; i < 30; ++i) {
        int e = i * 256 + t;               // 7680 = 2*6*64*5*2
        int half = e & 1;
        int u    = (e >> 1) % 5;
        int c    = ((e >> 1) / 5) % 64;
        int k    = ((e >> 1) / 320) % 6;
        int pl   = e / 3840;
        int q = idxs[pl * 6 + k];
        const float* src = lfV
            + (size_t)((n*5 + q/96)*96 + (q%96)) * LFV_IMG
            + (size_t)c*480 + u*96 + pnh*8 + half*4;
        float4 vv = *(const float4*)src;
        int colbase = pl*40 + u*8 + half*4;
        int krow = k*64 + c;
        int kc = krow >> 3, kl = krow & 7;   // chunk 0..47, low 0..7
        int c0 = colbase + 0, c1 = colbase + 1, c2 = colbase + 2, c3 = colbase + 3;
        Bs[c0][(((kc & ~7) | ((kc & 7) ^ (c0 & 7))) << 3) | kl] = f2bf(vv.x);
        Bs[c1][(((kc & ~7) | ((kc & 7) ^ (c1 & 7))) << 3) | kl] = f2bf(vv.y);
        Bs[c2][(((kc & ~7) | ((kc & 7) ^ (c2 & 7))) << 3) | kl] = f2bf(vv.z);
        Bs[c3][(((kc & ~7) | ((kc & 7) ^ (c3 & 7))) << 3) | kl] = f2bf(vv.w);
    }
    __syncthreads();

    int lane = t & 63, wv = t >> 6;
    int l15 = lane & 15, hi = lane >> 4;
    int co0 = wv * 16;
    f32x4 acc[5] = {};
#pragma unroll
    for (int f = 0; f < 5; ++f)
        asm volatile("s_nop 1" : "+v"(acc[f]));

    const float* ap = w1 + (size_t)(co0 + l15) * 384 + hi * 8;
    for (int ks = 0; ks < 12; ++ks) {
        i32x4 a = pack8(ap + ks * 32);
        asm volatile("s_nop 1" : "+v"(a));
#pragma unroll
        for (int f = 0; f < 5; ++f) {
            int col = f * 16 + l15;
            int ch = ks * 4 + hi;            // chunk 0..47
            int chs = (ch & ~7) | ((ch & 7) ^ (col & 7));
            i32x4 bv = *(const i32x4*)&Bs[col][chs << 3];
            mfma_bf16_16x16x32(acc[f], a, bv);
        }
    }
#pragma unroll
    for (int f = 0; f < 5; ++f)
        asm volatile("s_nop 7\ns_nop 7" : "+v"(acc[f]));

#pragma unroll
    for (int f = 0; f < 5; ++f) {
        int col = f * 16 + l15;
        int pg = p0 + col / 40, rr = col % 40;
        int u = rr >> 3, psh = rr & 7;
        size_t base = (size_t)((n*5 + pg/96)*96 + (pg%96)) * LFV_IMG
                    + (size_t)u * 96 + pnh*8 + psh;
#pragma unroll
        for (int rg = 0; rg < 4; ++rg) {
            float x = acc[f][rg];
            x = x > 0.f ? x : 0.1f * x;
            a1[base + (size_t)(co0 + hi*4 + rg) * 480] = x;
        }
    }
}

// ---------------------------------------------------------------------------
// K5n: 3x3 conv via inline-asm MFMA, u-fused tile.
//      block = (nv, w-tile 4, h-tile 16) -> computes ALL 5 u outputs x 64 co.
//      LDS ins[(w*5+uin)*18+hp][64ci] (46 KB -> 3 blocks/CU), XOR-swizzled,
//      scalar b16 LDS writes only. u-halo handled by SKIPPING MFMAs (exact).
//      FIXED vs r14: staging guards are exact 0 <= hp < 18 on every element
//      (r14 let hp=18,19 spill into the next subtile -> absmax 4.8 corruption).
// ---------------------------------------------------------------------------
__global__ __launch_bounds__(256) void k5n_conv3(const float* __restrict__ lfV,
                                                 const float* __restrict__ a1,
                                                 const unsigned short* __restrict__ w2h,
                                                 float* __restrict__ outp) {
    int blk = blockIdx.x;             // grid 1440 = nv*144 + wt*6 + ht
    int ht = blk % 6;  int r = blk / 6;
    int wt = r % 24;   int nv = r / 24;    // nv = n*5 + v
    int w0 = wt * 4, h0 = ht * 16;
    int imgbase = nv * 96 + w0;

    __shared__ unsigned short ins[360][64];   // 46,080 B

    int t = threadIdx.x;
    int lane = t & 63, wv = t >> 6, l15 = lane & 15, hi = lane >> 4;
    int wl = l15 & 3;                 // output w within tile
    int hl = wv * 4 + (l15 >> 2);     // output h within tile (wave-split)

    f32x4 acc[5][4] = {};
#pragma unroll
    for (int u = 0; u < 5; ++u)
#pragma unroll
        for (int j = 0; j < 4; ++j)
            asm volatile("s_nop 1" : "+v"(acc[u][j]));

    for (int cc = 0; cc < 2; ++cc) {
        const float* basep = cc ? a1 : lfV;
        if (cc) __syncthreads();
        // stage: e = (ci, uin, w, g): float4 over 4 h, cvt bf16, b16 scatter
        for (int i = 0; i < 30; ++i) {
            int e = i * 256 + t;              // 7680 = 64*5*4*6
            int g   = e % 6;
            int w   = (e / 6) & 3;
            int uin = (e / 24) % 5;
            int ci  = e / 120;
            int hbase = h0 - 4 + g * 4;       // aligned float4 chunk
            float4 vv = {0.f, 0.f, 0.f, 0.f};
            if (hbase >= 0 && hbase <= 92)
                vv = *(const float4*)(basep + (size_t)(imgbase + w) * LFV_IMG
                      + (size_t)ci * 480 + uin * 96 + hbase);
            int sbase = (w*5 + uin) * 18;
            int hp0 = g*4 - 3;                // hp of vv.x  (in [-3, 17])
            int cch = ci >> 3, clo = ci & 7;
            if (hp0 >= 0) {                               // hp0 <= 17 always
                int s = sbase + hp0;
                ins[s][((cch ^ (s & 7)) << 3) | clo] = f2bf(vv.x);
            }
            if (hp0 + 1 >= 0 && hp0 + 1 < 18) {
                int s = sbase + hp0 + 1;
                ins[s][((cch ^ (s & 7)) << 3) | clo] = f2bf(vv.y);
            }
            if (hp0 + 2 >= 0 && hp0 + 2 < 18) {
                int s = sbase + hp0 + 2;
                ins[s][((cch ^ (s & 7)) << 3) | clo] = f2bf(vv.z);
            }
            if (hp0 + 3 < 18) {                           // hp0+3 >= 0 always
                int s = sbase + hp0 + 3;
                ins[s][((cch ^ (s & 7)) << 3) | clo] = f2bf(vv.w);
            }
        }
        __syncthreads();

        // compute: K-steps (du,dh,kk); B-frag per u feeds 4 co-frag MFMAs
        for (int du = 0; du < 3; ++du) {
#pragma unroll
            for (int dh = 0; dh < 3; ++dh)
#pragma unroll
            for (int kk = 0; kk < 2; ++kk) {
                const unsigned short* wp = w2h + cc*576 + (du*3 + dh)*64
                                         + kk*32 + hi*8 + (size_t)l15*1152;
                i32x4 a0 = *(const i32x4*)(wp);
                i32x4 a1f = *(const i32x4*)(wp + 16*1152);
                i32x4 a2 = *(const i32x4*)(wp + 32*1152);
                i32x4 a3 = *(const i32x4*)(wp + 48*1152);
#pragma unroll
                for (int u = 0; u < 5; ++u) {
                    int uin = u + du - 1;
                    if (uin < 0 || uin > 4) continue;   // u-halo: exact skip
                    int s = (wl*5 + uin)*18 + hl + dh;
                    i32x4 bv = *(const i32x4*)&ins[s][((kk*4 + hi) ^ (s & 7)) << 3];
                    mfma_bf16_16x16x32(acc[u][0], a0, bv);
                    mfma_bf16_16x16x32(acc[u][1], a1f, bv);
                    mfma_bf16_16x16x32(acc[u][2], a2, bv);
                    mfma_bf16_16x16x32(acc[u][3], a3, bv);
                }
            }
        }
        if (!cc) __syncthreads();   // protect ins reuse before second stage
    }
#pragma unroll
    for (int u = 0; u < 5; ++u)
#pragma unroll
        for (int j = 0; j < 4; ++j)
            asm volatile("s_nop 7\ns_nop 7" : "+v"(acc[u][j]));

    // leaky + permuted store: out[(n*25+u*5+v)][co][h0+hl][w0+wl]
    int n = nv / 5, v = nv % 5;
#pragma unroll
    for (int u = 0; u < 5; ++u) {
        size_t ob = (size_t)((n*25 + u*5 + v) * 64) * IMG_HW
                  + (size_t)(h0 + hl) * 96 + w0 + wl;
#pragma unroll
        for (int j = 0; j < 4; ++j) {
#pragma unroll
            for (int rg = 0; rg < 4; ++rg) {
                int co = j*16 + hi*4 + rg;
                float x = acc[u][j][rg];
                x = x > 0.f ? x : 0.1f * x;
                outp[ob + (size_t)co * IMG_HW] = x;
            }
        }
    }
}

// ---------------------------------------------------------------------------
extern "C" void kernel_launch(void* const* d_in, const int* in_sizes, int n_in,
                              void* d_out, int out_size, void* d_ws, size_t ws_size,
                              hipStream_t stream) {
    const float* lf_fea = (const float*)d_in[0];
    const float* w1     = (const float*)d_in[1];
    const float* w2     = (const float*)d_in[2];
    float* outp = (float*)d_out;

    char* ws = (char*)d_ws;
    // ws layout (bytes) — r8/r11 EXACT footprint (proven in-bounds):
    //   lfV : 117,964,800  @ 0
    //   a1  : 117,964,800  @ 117,964,800   (Gpart 88,473,600 aliases its head:
    //                                       k2a/k2b finish before k4 writes a1)
    //   dist:  22,118,400  @ 235,929,600   (w2h aliases its head AFTER k3)
    //   sq  :      46,080  @ 258,048,000
    //   idx :      69,120  @ 258,094,080   (end 258,163,200)
    float* lfV   = (float*)(ws);
    float* a1    = (float*)(ws + 117964800ull);
    float* Gpart = (float*)(ws + 117964800ull);   // aliases a1 (consumed first)
    float* dist  = (float*)(ws + 235929600ull);
    float* sq    = (float*)(ws + 258048000ull);
    int*   idx   = (int*)  (ws + 258094080ull);
    unsigned short* w2h = (unsigned short*)(ws + 235929600ull);  // reuses dist

    hipLaunchKernelGGL(k0_lfv,   dim3(3200), dim3(256), 0, stream, lf_fea, lfV);
    hipLaunchKernelGGL(k1_sq,    dim3(360),  dim3(256), 0, stream, lf_fea, sq);
    hipLaunchKernelGGL(k2a_gram, dim3(1440), dim3(256), 0, stream, lf_fea, Gpart);
    hipLaunchKernelGGL(k2b_dist, dim3(5400), dim3(256), 0, stream, Gpart, sq, dist);
    hipLaunchKernelGGL(k3_topk,  dim3(2880), dim3(256), 0, stream, dist, idx);
    hipLaunchKernelGGL(kw2_conv, dim3(288),  dim3(256), 0, stream, w2, w2h);
    hipLaunchKernelGGL(k4_conv1, dim3(5760), dim3(256), 0, stream, lfV, w1, idx, a1);
    hipLaunchKernelGGL(k5n_conv3,dim3(1440), dim3(256), 0, stream, lfV, a1, w2h, outp);
}

// Round 16
// 1007.518 us; speedup vs baseline: 2.4819x; 1.0422x over previous
//
#include <hip/hip_runtime.h>
#include <stdint.h>

// Fixed problem config
#define NN   2
#define ANU  5
#define CH   64
#define HH   96
#define WW   96
#define KK   6
#define PSHh 8
#define PNHh 12
#define BB   (NN*PNHh)        // 24
#define PP   (ANU*WW)         // 480
#define CCD  (CH*ANU*PSHh)    // 2560
#define IMG_HW (HH*WW)            // 9216
#define IMG_STRIDE (CH*HH*WW)     // 589824 floats per input image
#define LFV_IMG (CH*ANU*HH)       // 30720 floats per (n,v,w) image in lfV / a1

typedef int   i32x4 __attribute__((ext_vector_type(4)));
typedef float f32x4 __attribute__((ext_vector_type(4)));

__device__ __forceinline__ unsigned short f2bf(float f) {
    unsigned int u = __float_as_uint(f);
    return (unsigned short)((u + 0x7FFFu + ((u >> 16) & 1u)) >> 16);
}

__device__ __forceinline__ void mfma_bf16_16x16x32(f32x4& d, i32x4 a, i32x4 b) {
    asm volatile("v_mfma_f32_16x16x32_bf16 %0, %1, %2, %0"
                 : "+v"(d) : "v"(a), "v"(b));
}

// pack 8 consecutive fp32 -> 8 bf16 in an i32x4 (A-fragment)
__device__ __forceinline__ i32x4 pack8(const float* p) {
    float4 lo = *(const float4*)p;
    float4 hi = *(const float4*)(p + 4);
    i32x4 r;
    r[0] = (int)((unsigned int)f2bf(lo.x) | ((unsigned int)f2bf(lo.y) << 16));
    r[1] = (int)((unsigned int)f2bf(lo.z) | ((unsigned int)f2bf(lo.w) << 16));
    r[2] = (int)((unsigned int)f2bf(hi.x) | ((unsigned int)f2bf(hi.y) << 16));
    r[3] = (int)((unsigned int)f2bf(hi.z) | ((unsigned int)f2bf(hi.w) << 16));
    return r;
}

// ---------------------------------------------------------------------------
// K0: transpose lf_fea[(n,u,v)][c][h][w] -> lfV[(n,v,w)][c][u][h]  (passing)
// ---------------------------------------------------------------------------
__global__ __launch_bounds__(256) void k0_lfv(const float* __restrict__ lf_fea,
                                              float* __restrict__ lfV) {
    int bc  = blockIdx.x;          // img*64 + c
    int img = bc >> 6;
    int c   = bc & 63;
    int n = img / 25, r = img % 25, u = r / 5, v = r % 5;
    const float* src = lf_fea + (size_t)bc * IMG_HW;
    __shared__ float tile[96][97];
    for (int e = threadIdx.x; e < 96*96; e += 256) {
        int h = e / 96, w = e % 96;
        tile[h][w] = src[e];
    }
    __syncthreads();
    size_t base = (size_t)((n*5 + v)*96) * LFV_IMG + (size_t)c*480 + u*96;
    for (int e = threadIdx.x; e < 96*96; e += 256) {
        int w = e / 96, h = e % 96;
        lfV[base + (size_t)w * LFV_IMG + h] = tile[h][w];
    }
}

// ---------------------------------------------------------------------------
// K1: sq[b][p] (fp64 accumulate), 8-way column split per row; 360 blocks
// ---------------------------------------------------------------------------
__global__ __launch_bounds__(256) void k1_sq(const float* __restrict__ lf_fea,
                                             float* __restrict__ sq) {
    int t = threadIdx.x;
    int row = blockIdx.x * 32 + (t & 31);      // 0..11519
    int cp = t >> 5;                           // 0..7
    int b = row / PP, p = row % PP;
    int n = b / PNHh, pnh = b % PNHh;
    int v = p / WW, w = p % WW;
    double acc = 0.0;
    for (int ci = 0; ci < 8; ++ci) {
        int c = cp * 8 + ci;
        for (int u = 0; u < 5; ++u) {
            const float* s = lf_fea + ((size_t)((n*25 + u*5 + v)*64 + c)) * IMG_HW
                           + pnh*8*96 + w;
#pragma unroll
            for (int psh = 0; psh < 8; ++psh) {
                float x = s[psh*96];
                acc += (double)x * (double)x;
            }
        }
    }
    __shared__ double red[256];
    red[t] = acc;
    __syncthreads();
    if (t < 32) {
        double ss = 0.0;
#pragma unroll
        for (int j = 0; j < 8; ++j) ss += red[j * 32 + t];
        sq[blockIdx.x * 32 + t] = (float)ss;
    }
}

// ---------------------------------------------------------------------------
// K2a: partial Gram, symmetric (vr<=vc), K-split 4; grid 1440.
//      RE-TILED vs r15: 32x8 threads, 12x3 per-thread tile.
//      A-reads: 3x b128 broadcast (addr depends only on ty, 48B-aligned);
//      B-reads: 3x b32, tx*3 spans all 32 banks (gcd(3,32)=1).
//      Per-output summation order BIT-IDENTICAL to r15 (20 chunks of 32,
//      sequential fma, accC sub-accumulator) -> zero top-k risk.
// ---------------------------------------------------------------------------
__global__ __launch_bounds__(256) void k2a_gram(const float* __restrict__ lf_fea,
                                                float* __restrict__ Gpart) {
    const int VRt[15] = {0,0,0,0,0,1,1,1,1,2,2,2,3,3,4};
    const int VCt[15] = {0,1,2,3,4,1,2,3,4,2,3,4,3,4,4};
    int blk = blockIdx.x;            // b*60 + pr*4 + ks
    int b  = blk / 60;
    int r0 = blk % 60;
    int pr = r0 / 4, ks = r0 % 4;
    int vr = VRt[pr], vc = VCt[pr];
    int n = b / PNHh, pnh = b % PNHh;

    __shared__ float As[32][96];
    __shared__ float Bs[32][96];

    int tx = threadIdx.x & 31, ty = threadIdx.x >> 5;   // 32 x 8
    float acc[12][3] = {};

    int kbase = ks * 640;
    for (int kc0 = kbase; kc0 < kbase + 640; kc0 += 32) {
        for (int e = threadIdx.x; e < 32*96; e += 256) {
            int kci = e / 96, w = e % 96;
            int cc = kc0 + kci;
            int c = cc / 40, r2 = cc % 40, u = r2 >> 3, psh = r2 & 7;
            size_t off = ((size_t)((n*25 + u*5)*64 + c)) * IMG_HW + (pnh*8 + psh)*96 + w;
            As[kci][w] = lf_fea[off + (size_t)vr * IMG_STRIDE];
            Bs[kci][w] = lf_fea[off + (size_t)vc * IMG_STRIDE];
        }
        __syncthreads();
        float accC[12][3] = {};
#pragma unroll
        for (int kc = 0; kc < 32; ++kc) {
            float a[12], bq[3];
            *(float4*)&a[0] = *(const float4*)&As[kc][ty*12 + 0];
            *(float4*)&a[4] = *(const float4*)&As[kc][ty*12 + 4];
            *(float4*)&a[8] = *(const float4*)&As[kc][ty*12 + 8];
#pragma unroll
            for (int j = 0; j < 3; ++j) bq[j] = Bs[kc][tx*3 + j];
#pragma unroll
            for (int i = 0; i < 12; ++i)
#pragma unroll
                for (int j = 0; j < 3; ++j)
                    accC[i][j] = fmaf(a[i], bq[j], accC[i][j]);
        }
#pragma unroll
        for (int i = 0; i < 12; ++i)
#pragma unroll
            for (int j = 0; j < 3; ++j)
                acc[i][j] += accC[i][j];
        __syncthreads();
    }

    size_t gbase = ((size_t)(ks*600 + b*25 + vr*5 + vc)) * 9216;
#pragma unroll
    for (int i = 0; i < 12; ++i)
#pragma unroll
        for (int j = 0; j < 3; ++j)
            Gpart[gbase + (ty*12 + i)*96 + tx*3 + j] = acc[i][j];

    if (vr != vc) {
        size_t gbt = ((size_t)(ks*600 + b*25 + vc*5 + vr)) * 9216;
#pragma unroll
        for (int i = 0; i < 12; ++i)
#pragma unroll
            for (int j = 0; j < 3; ++j)
                Gpart[gbt + (tx*3 + j)*96 + ty*12 + i] = acc[i][j];
    }
}

// ---------------------------------------------------------------------------
// K2b: dist[b][p][q] = sq_p + sq_q - 2 * sum_ks Gpart   (r11 verbatim)
// ---------------------------------------------------------------------------
__global__ __launch_bounds__(256) void k2b_dist(const float* __restrict__ Gpart,
                                                const float* __restrict__ sq,
                                                float* __restrict__ dist) {
    int tid = blockIdx.x * 256 + threadIdx.x;   // grid 5400: exactly 1,382,400
    int b = tid / 57600;
    int r = tid % 57600;
    int p = r / 120, qt = r % 120;
    int vr = p / 96, pl = p % 96;
    int vc = qt / 24;
    int ql4 = (qt % 24) * 4;

    size_t tb = ((size_t)(b*25 + vr*5 + vc)) * 9216 + pl*96 + ql4;
    float4 g0 = *(const float4*)(Gpart + tb);
    float4 g1 = *(const float4*)(Gpart + tb +  600ull*9216);
    float4 g2 = *(const float4*)(Gpart + tb + 1200ull*9216);
    float4 g3 = *(const float4*)(Gpart + tb + 1800ull*9216);
    float gx = g0.x + g1.x + g2.x + g3.x;
    float gy = g0.y + g1.y + g2.y + g3.y;
    float gz = g0.z + g1.z + g2.z + g3.z;
    float gw = g0.w + g1.w + g2.w + g3.w;

    float  sqp = sq[b*480 + p];
    float4 sqq = *(const float4*)(sq + b*480 + vc*96 + ql4);
    float4 d;
    d.x = sqp + sqq.x - 2.0f * gx;
    d.y = sqp + sqq.y - 2.0f * gy;
    d.z = sqp + sqq.z - 2.0f * gz;
    d.w = sqp + sqq.w - 2.0f * gw;
    *(float4*)(dist + (size_t)b*230400 + (size_t)p*480 + vc*96 + ql4) = d;
}

// ---------------------------------------------------------------------------
// K3: per-row top-6  (passing, verbatim)
// ---------------------------------------------------------------------------
__global__ __launch_bounds__(256) void k3_topk(const float* __restrict__ dist,
                                               int* __restrict__ idx) {
    int wid  = (blockIdx.x * 256 + threadIdx.x) >> 6;  // global wave id
    int lane = threadIdx.x & 63;
    int b = wid / PP, p = wid % PP;
    const float* row = dist + (size_t)b * PP * PP + (size_t)p * PP;

    unsigned long long key[8];
#pragma unroll
    for (int j = 0; j < 8; ++j) {
        int q = j*64 + lane;
        if (q < PP) {
            unsigned int f = __float_as_uint(row[q]);
            unsigned int mono = f ^ ((f & 0x80000000u) ? 0xFFFFFFFFu : 0x80000000u);
            key[j] = ((unsigned long long)mono << 32) | (unsigned int)q;
        } else {
            key[j] = ~0ull;
        }
    }
    int* outp = idx + ((size_t)b*PP + p) * KK;
    for (int k = 0; k < KK; ++k) {
        unsigned long long m = key[0];
#pragma unroll
        for (int j = 1; j < 8; ++j) m = (key[j] < m) ? key[j] : m;
        for (int s = 1; s < 64; s <<= 1) {
            unsigned long long o = __shfl_xor(m, s, 64);
            m = (o < m) ? o : m;
        }
        if (lane == 0) outp[k] = (int)(m & 0xFFFFFFFFu);
#pragma unroll
        for (int j = 0; j < 8; ++j) if (key[j] == m) key[j] = ~0ull;
    }
}

// ---------------------------------------------------------------------------
// kw2: reorder w2 -> bf16 w2h[co][cc][tap][ci64] (placed in dist region, after k3)
// ---------------------------------------------------------------------------
__global__ __launch_bounds__(256) void kw2_conv(const float* __restrict__ w2,
                                                unsigned short* __restrict__ w2h) {
    int e = blockIdx.x * 256 + threadIdx.x;   // 73728 total
    if (e < 73728) {
        int co = e / 1152, r = e % 1152;
        int cc = r / 576, r2 = r % 576;
        int tap = r2 / 64, ci_l = r2 % 64;
        w2h[e] = f2bf(w2[co*1152 + (cc*64 + ci_l)*9 + tap]);
    }
}

// ---------------------------------------------------------------------------
// K4: gather + 1x1 conv via inline-asm MFMA  (r13 verbatim, passing)
// ---------------------------------------------------------------------------
__global__ __launch_bounds__(256) void k4_conv1(const float* __restrict__ lfV,
                                                const float* __restrict__ w1,
                                                const int* __restrict__ idxg,
                                                float* __restrict__ a1) {
    int blk = blockIdx.x;            // b*240 + ptile
    int b = blk / 240, ptile = blk % 240;
    int n = b / PNHh, pnh = b % PNHh;
    int p0 = ptile * 2;

    __shared__ unsigned short Bs[80][384];   // [col][swizzled krow] bf16
    __shared__ int idxs[12];

    int t = threadIdx.x;
    if (t < 12) idxs[t] = idxg[(b*PP + p0 + t/6)*KK + (t % 6)];
    __syncthreads();

    for (int i = 0; i < 30; ++i) {
        int e = i * 256 + t;               // 7680 = 2*6*64*5*2
        int half = e & 1;
        int u    = (e >> 1) % 5;
        int c    = ((e >> 1) / 5) % 64;
        int k    = ((e >> 1) / 320) % 6;
        int pl   = e / 3840;
        int q = idxs[pl * 6 + k];
        const float* src = lfV
            + (size_t)((n*5 + q/96)*96 + (q%96)) * LFV_IMG
            + (size_t)c*480 + u*96 + pnh*8 + half*4;
        float4 vv = *(const float4*)src;
        int colbase = pl*40 + u*8 + half*4;
        int krow = k*64 + c;
        int kc = krow >> 3, kl = krow & 7;   // chunk 0..47, low 0..7
        int c0 = colbase + 0, c1 = colbase + 1, c2 = colbase + 2, c3 = colbase + 3;
        Bs[c0][(((kc & ~7) | ((kc & 7) ^ (c0 & 7))) << 3) | kl] = f2bf(vv.x);
        Bs[c1][(((kc & ~7) | ((kc & 7) ^ (c1 & 7))) << 3) | kl] = f2bf(vv.y);
        Bs[c2][(((kc & ~7) | ((kc & 7) ^ (c2 & 7))) << 3) | kl] = f2bf(vv.z);
        Bs[c3][(((kc & ~7) | ((kc & 7) ^ (c3 & 7))) << 3) | kl] = f2bf(vv.w);
    }
    __syncthreads();

    int lane = t & 63, wv = t >> 6;
    int l15 = lane & 15, hi = lane >> 4;
    int co0 = wv * 16;
    f32x4 acc[5] = {};
#pragma unroll
    for (int f = 0; f < 5; ++f)
        asm volatile("s_nop 1" : "+v"(acc[f]));

    const float* ap = w1 + (size_t)(co0 + l15) * 384 + hi * 8;
    for (int ks = 0; ks < 12; ++ks) {
        i32x4 a = pack8(ap + ks * 32);
        asm volatile("s_nop 1" : "+v"(a));
#pragma unroll
        for (int f = 0; f < 5; ++f) {
            int col = f * 16 + l15;
            int ch = ks * 4 + hi;            // chunk 0..47
            int chs = (ch & ~7) | ((ch & 7) ^ (col & 7));
            i32x4 bv = *(const i32x4*)&Bs[col][chs << 3];
            mfma_bf16_16x16x32(acc[f], a, bv);
        }
    }
#pragma unroll
    for (int f = 0; f < 5; ++f)
        asm volatile("s_nop 7\ns_nop 7" : "+v"(acc[f]));

#pragma unroll
    for (int f = 0; f < 5; ++f) {
        int col = f * 16 + l15;
        int pg = p0 + col / 40, rr = col % 40;
        int u = rr >> 3, psh = rr & 7;
        size_t base = (size_t)((n*5 + pg/96)*96 + (pg%96)) * LFV_IMG
                    + (size_t)u * 96 + pnh*8 + psh;
#pragma unroll
        for (int rg = 0; rg < 4; ++rg) {
            float x = acc[f][rg];
            x = x > 0.f ? x : 0.1f * x;
            a1[base + (size_t)(co0 + hi*4 + rg) * 480] = x;
        }
    }
}

// ---------------------------------------------------------------------------
// K5n: 3x3 conv via inline-asm MFMA, u-fused tile  (r15 verbatim, passing)
// ---------------------------------------------------------------------------
__global__ __launch_bounds__(256) void k5n_conv3(const float* __restrict__ lfV,
                                                 const float* __restrict__ a1,
                                                 const unsigned short* __restrict__ w2h,
                                                 float* __restrict__ outp) {
    int blk = blockIdx.x;             // grid 1440 = nv*144 + wt*6 + ht
    int ht = blk % 6;  int r = blk / 6;
    int wt = r % 24;   int nv = r / 24;    // nv = n*5 + v
    int w0 = wt * 4, h0 = ht * 16;
    int imgbase = nv * 96 + w0;

    __shared__ unsigned short ins[360][64];   // 46,080 B

    int t = threadIdx.x;
    int lane = t & 63, wv = t >> 6, l15 = lane & 15, hi = lane >> 4;
    int wl = l15 & 3;                 // output w within tile
    int hl = wv * 4 + (l15 >> 2);     // output h within tile (wave-split)

    f32x4 acc[5][4] = {};
#pragma unroll
    for (int u = 0; u < 5; ++u)
#pragma unroll
        for (int j = 0; j < 4; ++j)
            asm volatile("s_nop 1" : "+v"(acc[u][j]));

    for (int cc = 0; cc < 2; ++cc) {
        const float* basep = cc ? a1 : lfV;
        if (cc) __syncthreads();
        // stage: e = (ci, uin, w, g): float4 over 4 h, cvt bf16, b16 scatter
        for (int i = 0; i < 30; ++i) {
            int e = i * 256 + t;              // 7680 = 64*5*4*6
            int g   = e % 6;
            int w   = (e / 6) & 3;
            int uin = (e / 24) % 5;
            int ci  = e / 120;
            int hbase = h0 - 4 + g * 4;       // aligned float4 chunk
            float4 vv = {0.f, 0.f, 0.f, 0.f};
            if (hbase >= 0 && hbase <= 92)
                vv = *(const float4*)(basep + (size_t)(imgbase + w) * LFV_IMG
                      + (size_t)ci * 480 + uin * 96 + hbase);
            int sbase = (w*5 + uin) * 18;
            int hp0 = g*4 - 3;                // hp of vv.x  (in [-3, 17])
            int cch = ci >> 3, clo = ci & 7;
            if (hp0 >= 0) {                               // hp0 <= 17 always
                int s = sbase + hp0;
                ins[s][((cch ^ (s & 7)) << 3) | clo] = f2bf(vv.x);
            }
            if (hp0 + 1 >= 0 && hp0 + 1 < 18) {
                int s = sbase + hp0 + 1;
                ins[s][((cch ^ (s & 7)) << 3) | clo] = f2bf(vv.y);
            }
            if (hp0 + 2 >= 0 && hp0 + 2 < 18) {
                int s = sbase + hp0 + 2;
                ins[s][((cch ^ (s & 7)) << 3) | clo] = f2bf(vv.z);
            }
            if (hp0 + 3 < 18) {                           // hp0+3 >= 0 always
                int s = sbase + hp0 + 3;
                ins[s][((cch ^ (s & 7)) << 3) | clo] = f2bf(vv.w);
            }
        }
        __syncthreads();

        // compute: K-steps (du,dh,kk); B-frag per u feeds 4 co-frag MFMAs
        for (int du = 0; du < 3; ++du) {
#pragma unroll
            for (int dh = 0; dh < 3; ++dh)
#pragma unroll
            for (int kk = 0; kk < 2; ++kk) {
                const unsigned short* wp = w2h + cc*576 + (du*3 + dh)*64
                                         + kk*32 + hi*8 + (size_t)l15*1152;
                i32x4 a0 = *(const i32x4*)(wp);
                i32x4 a1f = *(const i32x4*)(wp + 16*1152);
                i32x4 a2 = *(const i32x4*)(wp + 32*1152);
                i32x4 a3 = *(const i32x4*)(wp + 48*1152);
#pragma unroll
                for (int u = 0; u < 5; ++u) {
                    int uin = u + du - 1;
                    if (uin < 0 || uin > 4) continue;   // u-halo: exact skip
                    int s = (wl*5 + uin)*18 + hl + dh;
                    i32x4 bv = *(const i32x4*)&ins[s][((kk*4 + hi) ^ (s & 7)) << 3];
                    mfma_bf16_16x16x32(acc[u][0], a0, bv);
                    mfma_bf16_16x16x32(acc[u][1], a1f, bv);
                    mfma_bf16_16x16x32(acc[u][2], a2, bv);
                    mfma_bf16_16x16x32(acc[u][3], a3, bv);
                }
            }
        }
        if (!cc) __syncthreads();   // protect ins reuse before second stage
    }
#pragma unroll
    for (int u = 0; u < 5; ++u)
#pragma unroll
        for (int j = 0; j < 4; ++j)
            asm volatile("s_nop 7\ns_nop 7" : "+v"(acc[u][j]));

    // leaky + permuted store: out[(n*25+u*5+v)][co][h0+hl][w0+wl]
    int n = nv / 5, v = nv % 5;
#pragma unroll
    for (int u = 0; u < 5; ++u) {
        size_t ob = (size_t)((n*25 + u*5 + v) * 64) * IMG_HW
                  + (size_t)(h0 + hl) * 96 + w0 + wl;
#pragma unroll
        for (int j = 0; j < 4; ++j) {
#pragma unroll
            for (int rg = 0; rg < 4; ++rg) {
                int co = j*16 + hi*4 + rg;
                float x = acc[u][j][rg];
                x = x > 0.f ? x : 0.1f * x;
                outp[ob + (size_t)co * IMG_HW] = x;
            }
        }
    }
}

// ---------------------------------------------------------------------------
extern "C" void kernel_launch(void* const* d_in, const int* in_sizes, int n_in,
                              void* d_out, int out_size, void* d_ws, size_t ws_size,
                              hipStream_t stream) {
    const float* lf_fea = (const float*)d_in[0];
    const float* w1     = (const float*)d_in[1];
    const float* w2     = (const float*)d_in[2];
    float* outp = (float*)d_out;

    char* ws = (char*)d_ws;
    // ws layout (bytes) — r8/r11 EXACT footprint (proven in-bounds):
    //   lfV : 117,964,800  @ 0
    //   a1  : 117,964,800  @ 117,964,800   (Gpart 88,473,600 aliases its head:
    //                                       k2a/k2b finish before k4 writes a1)
    //   dist:  22,118,400  @ 235,929,600   (w2h aliases its head AFTER k3)
    //   sq  :      46,080  @ 258,048,000
    //   idx :      69,120  @ 258,094,080   (end 258,163,200)
    float* lfV   = (float*)(ws);
    float* a1    = (float*)(ws + 117964800ull);
    float* Gpart = (float*)(ws + 117964800ull);   // aliases a1 (consumed first)
    float* dist  = (float*)(ws + 235929600ull);
    float* sq    = (float*)(ws + 258048000ull);
    int*   idx   = (int*)  (ws + 258094080ull);
    unsigned short* w2h = (unsigned short*)(ws + 235929600ull);  // reuses dist

    hipLaunchKernelGGL(k0_lfv,   dim3(3200), dim3(256), 0, stream, lf_fea, lfV);
    hipLaunchKernelGGL(k1_sq,    dim3(360),  dim3(256), 0, stream, lf_fea, sq);
    hipLaunchKernelGGL(k2a_gram, dim3(1440), dim3(256), 0, stream, lf_fea, Gpart);
    hipLaunchKernelGGL(k2b_dist, dim3(5400), dim3(256), 0, stream, Gpart, sq, dist);
    hipLaunchKernelGGL(k3_topk,  dim3(2880), dim3(256), 0, stream, dist, idx);
    hipLaunchKernelGGL(kw2_conv, dim3(288),  dim3(256), 0, stream, w2, w2h);
    hipLaunchKernelGGL(k4_conv1, dim3(5760), dim3(256), 0, stream, lfV, w1, idx, a1);
    hipLaunchKernelGGL(k5n_conv3,dim3(1440), dim3(256), 0, stream, lfV, a1, w2h, outp);
}

// Round 20
// 927.516 us; speedup vs baseline: 2.6960x; 1.0863x over previous
//
#include <hip/hip_runtime.h>
#include <stdint.h>

// Fixed problem config
#define NN   2
#define ANU  5
#define CH   64
#define HH   96
#define WW   96
#define KK   6
#define PSHh 8
#define PNHh 12
#define BB   (NN*PNHh)        // 24
#define PP   (ANU*WW)         // 480
#define CCD  (CH*ANU*PSHh)    // 2560
#define IMG_HW (HH*WW)            // 9216
#define IMG_STRIDE (CH*HH*WW)     // 589824 floats per input image
#define LFV_IMG (CH*ANU*HH)       // 30720 floats per (n,v,w) image in lfV / a1

typedef int   i32x4 __attribute__((ext_vector_type(4)));
typedef float f32x4 __attribute__((ext_vector_type(4)));

__device__ __forceinline__ unsigned short f2bf(float f) {
    unsigned int u = __float_as_uint(f);
    return (unsigned short)((u + 0x7FFFu + ((u >> 16) & 1u)) >> 16);
}

__device__ __forceinline__ void mfma_bf16_16x16x32(f32x4& d, i32x4 a, i32x4 b) {
    asm volatile("v_mfma_f32_16x16x32_bf16 %0, %1, %2, %0"
                 : "+v"(d) : "v"(a), "v"(b));
}

// ---------------------------------------------------------------------------
// K0: transpose lf_fea[(n,u,v)][c][h][w] -> lfV[(n,v,w)][c][u][h]  (passing)
// ---------------------------------------------------------------------------
__global__ __launch_bounds__(256) void k0_lfv(const float* __restrict__ lf_fea,
                                              float* __restrict__ lfV) {
    int bc  = blockIdx.x;          // img*64 + c
    int img = bc >> 6;
    int c   = bc & 63;
    int n = img / 25, r = img % 25, u = r / 5, v = r % 5;
    const float* src = lf_fea + (size_t)bc * IMG_HW;
    __shared__ float tile[96][97];
    for (int e = threadIdx.x; e < 96*96; e += 256) {
        int h = e / 96, w = e % 96;
        tile[h][w] = src[e];
    }
    __syncthreads();
    size_t base = (size_t)((n*5 + v)*96) * LFV_IMG + (size_t)c*480 + u*96;
    for (int e = threadIdx.x; e < 96*96; e += 256) {
        int w = e / 96, h = e % 96;
        lfV[base + (size_t)w * LFV_IMG + h] = tile[h][w];
    }
}

// ---------------------------------------------------------------------------
// K1: sq[b][p] (fp64 accumulate), 8-way column split per row; 360 blocks
// ---------------------------------------------------------------------------
__global__ __launch_bounds__(256) void k1_sq(const float* __restrict__ lf_fea,
                                             float* __restrict__ sq) {
    int t = threadIdx.x;
    int row = blockIdx.x * 32 + (t & 31);      // 0..11519
    int cp = t >> 5;                           // 0..7
    int b = row / PP, p = row % PP;
    int n = b / PNHh, pnh = b % PNHh;
    int v = p / WW, w = p % WW;
    double acc = 0.0;
    for (int ci = 0; ci < 8; ++ci) {
        int c = cp * 8 + ci;
        for (int u = 0; u < 5; ++u) {
            const float* s = lf_fea + ((size_t)((n*25 + u*5 + v)*64 + c)) * IMG_HW
                           + pnh*8*96 + w;
#pragma unroll
            for (int psh = 0; psh < 8; ++psh) {
                float x = s[psh*96];
                acc += (double)x * (double)x;
            }
        }
    }
    __shared__ double red[256];
    red[t] = acc;
    __syncthreads();
    if (t < 32) {
        double ss = 0.0;
#pragma unroll
        for (int j = 0; j < 8; ++j) ss += red[j * 32 + t];
        sq[blockIdx.x * 32 + t] = (float)ss;
    }
}

// ---------------------------------------------------------------------------
// K2a: partial Gram, symmetric (vr<=vc), K-split 4; grid 1440.
//      Staging division-hoisted vs r16: thread owns fixed row r=t>>3, cols
//      w=(t&7)+8j; /40,%40 computed once per chunk. LDS contents, compute
//      loop, and summation order BIT-IDENTICAL to r16 -> zero top-k risk.
// ---------------------------------------------------------------------------
__global__ __launch_bounds__(256) void k2a_gram(const float* __restrict__ lf_fea,
                                                float* __restrict__ Gpart) {
    const int VRt[15] = {0,0,0,0,0,1,1,1,1,2,2,2,3,3,4};
    const int VCt[15] = {0,1,2,3,4,1,2,3,4,2,3,4,3,4,4};
    int blk = blockIdx.x;            // b*60 + pr*4 + ks
    int b  = blk / 60;
    int r0 = blk % 60;
    int pr = r0 / 4, ks = r0 % 4;
    int vr = VRt[pr], vc = VCt[pr];
    int n = b / PNHh, pnh = b % PNHh;

    __shared__ float As[32][96];
    __shared__ float Bs[32][96];

    int t  = threadIdx.x;
    int tx = t & 31, ty = t >> 5;    // 32 x 8 compute tiling
    int sr = t >> 3, sw = t & 7;     // staging: row 0..31, col-base 0..7
    float acc[12][3] = {};

    int kbase = ks * 640;
    for (int kc0 = kbase; kc0 < kbase + 640; kc0 += 32) {
        {
            int cc = kc0 + sr;
            int c = cc / 40, r2 = cc % 40, u = r2 >> 3, psh = r2 & 7;
            size_t off = ((size_t)((n*25 + u*5)*64 + c)) * IMG_HW + (pnh*8 + psh)*96;
            const float* pa = lf_fea + off + (size_t)vr * IMG_STRIDE;
            const float* pb = lf_fea + off + (size_t)vc * IMG_STRIDE;
#pragma unroll
            for (int j = 0; j < 12; ++j) {
                int w = sw + 8*j;
                As[sr][w] = pa[w];
                Bs[sr][w] = pb[w];
            }
        }
        __syncthreads();
        float accC[12][3] = {};
#pragma unroll
        for (int kc = 0; kc < 32; ++kc) {
            float a[12], bq[3];
            *(float4*)&a[0] = *(const float4*)&As[kc][ty*12 + 0];
            *(float4*)&a[4] = *(const float4*)&As[kc][ty*12 + 4];
            *(float4*)&a[8] = *(const float4*)&As[kc][ty*12 + 8];
#pragma unroll
            for (int j = 0; j < 3; ++j) bq[j] = Bs[kc][tx*3 + j];
#pragma unroll
            for (int i = 0; i < 12; ++i)
#pragma unroll
                for (int j = 0; j < 3; ++j)
                    accC[i][j] = fmaf(a[i], bq[j], accC[i][j]);
        }
#pragma unroll
        for (int i = 0; i < 12; ++i)
#pragma unroll
            for (int j = 0; j < 3; ++j)
                acc[i][j] += accC[i][j];
        __syncthreads();
    }

    size_t gbase = ((size_t)(ks*600 + b*25 + vr*5 + vc)) * 9216;
#pragma unroll
    for (int i = 0; i < 12; ++i)
#pragma unroll
        for (int j = 0; j < 3; ++j)
            Gpart[gbase + (ty*12 + i)*96 + tx*3 + j] = acc[i][j];

    if (vr != vc) {
        size_t gbt = ((size_t)(ks*600 + b*25 + vc*5 + vr)) * 9216;
#pragma unroll
        for (int i = 0; i < 12; ++i)
#pragma unroll
            for (int j = 0; j < 3; ++j)
                Gpart[gbt + (tx*3 + j)*96 + ty*12 + i] = acc[i][j];
    }
}

// ---------------------------------------------------------------------------
// K2b: dist[b][p][q] = sq_p + sq_q - 2 * sum_ks Gpart   (r11 verbatim)
// ---------------------------------------------------------------------------
__global__ __launch_bounds__(256) void k2b_dist(const float* __restrict__ Gpart,
                                                const float* __restrict__ sq,
                                                float* __restrict__ dist) {
    int tid = blockIdx.x * 256 + threadIdx.x;   // grid 5400: exactly 1,382,400
    int b = tid / 57600;
    int r = tid % 57600;
    int p = r / 120, qt = r % 120;
    int vr = p / 96, pl = p % 96;
    int vc = qt / 24;
    int ql4 = (qt % 24) * 4;

    size_t tb = ((size_t)(b*25 + vr*5 + vc)) * 9216 + pl*96 + ql4;
    float4 g0 = *(const float4*)(Gpart + tb);
    float4 g1 = *(const float4*)(Gpart + tb +  600ull*9216);
    float4 g2 = *(const float4*)(Gpart + tb + 1200ull*9216);
    float4 g3 = *(const float4*)(Gpart + tb + 1800ull*9216);
    float gx = g0.x + g1.x + g2.x + g3.x;
    float gy = g0.y + g1.y + g2.y + g3.y;
    float gz = g0.z + g1.z + g2.z + g3.z;
    float gw = g0.w + g1.w + g2.w + g3.w;

    float  sqp = sq[b*480 + p];
    float4 sqq = *(const float4*)(sq + b*480 + vc*96 + ql4);
    float4 d;
    d.x = sqp + sqq.x - 2.0f * gx;
    d.y = sqp + sqq.y - 2.0f * gy;
    d.z = sqp + sqq.z - 2.0f * gz;
    d.w = sqp + sqq.w - 2.0f * gw;
    *(float4*)(dist + (size_t)b*230400 + (size_t)p*480 + vc*96 + ql4) = d;
}

// ---------------------------------------------------------------------------
// K3: per-row top-6  (passing, verbatim)
// ---------------------------------------------------------------------------
__global__ __launch_bounds__(256) void k3_topk(const float* __restrict__ dist,
                                               int* __restrict__ idx) {
    int wid  = (blockIdx.x * 256 + threadIdx.x) >> 6;  // global wave id
    int lane = threadIdx.x & 63;
    int b = wid / PP, p = wid % PP;
    const float* row = dist + (size_t)b * PP * PP + (size_t)p * PP;

    unsigned long long key[8];
#pragma unroll
    for (int j = 0; j < 8; ++j) {
        int q = j*64 + lane;
        if (q < PP) {
            unsigned int f = __float_as_uint(row[q]);
            unsigned int mono = f ^ ((f & 0x80000000u) ? 0xFFFFFFFFu : 0x80000000u);
            key[j] = ((unsigned long long)mono << 32) | (unsigned int)q;
        } else {
            key[j] = ~0ull;
        }
    }
    int* outp = idx + ((size_t)b*PP + p) * KK;
    for (int k = 0; k < KK; ++k) {
        unsigned long long m = key[0];
#pragma unroll
        for (int j = 1; j < 8; ++j) m = (key[j] < m) ? key[j] : m;
        for (int s = 1; s < 64; s <<= 1) {
            unsigned long long o = __shfl_xor(m, s, 64);
            m = (o < m) ? o : m;
        }
        if (lane == 0) outp[k] = (int)(m & 0xFFFFFFFFu);
#pragma unroll
        for (int j = 0; j < 8; ++j) if (key[j] == m) key[j] = ~0ull;
    }
}

// ---------------------------------------------------------------------------
// kw1: w1 -> bf16 flat copy w1h[co][k*64+c]  (kw2-pattern, proven class)
// ---------------------------------------------------------------------------
__global__ __launch_bounds__(256) void kw1_conv(const float* __restrict__ w1,
                                                unsigned short* __restrict__ w1h) {
    int e = blockIdx.x * 256 + threadIdx.x;   // 24576 total, grid 96
    if (e < 24576) w1h[e] = f2bf(w1[e]);
}

// ---------------------------------------------------------------------------
// kw2: reorder w2 -> bf16 w2h[co][cc][tap][ci64] (passing, verbatim)
// ---------------------------------------------------------------------------
__global__ __launch_bounds__(256) void kw2_conv(const float* __restrict__ w2,
                                                unsigned short* __restrict__ w2h) {
    int e = blockIdx.x * 256 + threadIdx.x;   // 73728 total
    if (e < 73728) {
        int co = e / 1152, r = e % 1152;
        int cc = r / 576, r2 = r % 576;
        int tap = r2 / 64, ci_l = r2 % 64;
        w2h[e] = f2bf(w2[co*1152 + (cc*64 + ci_l)*9 + tap]);
    }
}

// ---------------------------------------------------------------------------
// K4: gather + 1x1 conv via inline-asm MFMA (r13-proven core).
//     A-fragments now loaded i32x4 from pre-converted bf16 w1h (same read
//     pattern passing builds use on w2h); pack8 deleted. B staging and all
//     else byte-identical to the passing r16 build.
// ---------------------------------------------------------------------------
__global__ __launch_bounds__(256) void k4_conv1(const float* __restrict__ lfV,
                                                const unsigned short* __restrict__ w1h,
                                                const int* __restrict__ idxg,
                                                float* __restrict__ a1) {
    int blk = blockIdx.x;            // b*240 + ptile
    int b = blk / 240, ptile = blk % 240;
    int n = b / PNHh, pnh = b % PNHh;
    int p0 = ptile * 2;

    __shared__ unsigned short Bs[80][384];   // [col][swizzled krow] bf16
    __shared__ int idxs[12];

    int t = threadIdx.x;
    if (t < 12) idxs[t] = idxg[(b*PP + p0 + t/6)*KK + (t % 6)];
    __syncthreads();

    for (int i = 0; i < 30; ++i) {
        int e = i * 256 + t;               // 7680 = 2*6*64*5*2
        int half = e & 1;
        int u    = (e >> 1) % 5;
        int c    = ((e >> 1) / 5) % 64;
        int k    = ((e >> 1) / 320) % 6;
        int pl   = e / 3840;
        int q = idxs[pl * 6 + k];
        const float* src = lfV
            + (size_t)((n*5 + q/96)*96 + (q%96)) * LFV_IMG
            + (size_t)c*480 + u*96 + pnh*8 + half*4;
        float4 vv = *(const float4*)src;
        int colbase = pl*40 + u*8 + half*4;
        int krow = k*64 + c;
        int kc = krow >> 3, kl = krow & 7;   // chunk 0..47, low 0..7
        int c0 = colbase + 0, c1 = colbase + 1, c2 = colbase + 2, c3 = colbase + 3;
        Bs[c0][(((kc & ~7) | ((kc & 7) ^ (c0 & 7))) << 3) | kl] = f2bf(vv.x);
        Bs[c1][(((kc & ~7) | ((kc & 7) ^ (c1 & 7))) << 3) | kl] = f2bf(vv.y);
        Bs[c2][(((kc & ~7) | ((kc & 7) ^ (c2 & 7))) << 3) | kl] = f2bf(vv.z);
        Bs[c3][(((kc & ~7) | ((kc & 7) ^ (c3 & 7))) << 3) | kl] = f2bf(vv.w);
    }
    __syncthreads();

    int lane = t & 63, wv = t >> 6;
    int l15 = lane & 15, hi = lane >> 4;
    int co0 = wv * 16;
    f32x4 acc[5] = {};
#pragma unroll
    for (int f = 0; f < 5; ++f)
        asm volatile("s_nop 1" : "+v"(acc[f]));

    const unsigned short* ap = w1h + (size_t)(co0 + l15) * 384 + hi * 8;
    for (int ks = 0; ks < 12; ++ks) {
        i32x4 a = *(const i32x4*)(ap + ks * 32);
        asm volatile("s_nop 1" : "+v"(a));
#pragma unroll
        for (int f = 0; f < 5; ++f) {
            int col = f * 16 + l15;
            int ch = ks * 4 + hi;            // chunk 0..47
            int chs = (ch & ~7) | ((ch & 7) ^ (col & 7));
            i32x4 bv = *(const i32x4*)&Bs[col][chs << 3];
            mfma_bf16_16x16x32(acc[f], a, bv);
        }
    }
#pragma unroll
    for (int f = 0; f < 5; ++f)
        asm volatile("s_nop 7\ns_nop 7" : "+v"(acc[f]));

#pragma unroll
    for (int f = 0; f < 5; ++f) {
        int col = f * 16 + l15;
        int pg = p0 + col / 40, rr = col % 40;
        int u = rr >> 3, psh = rr & 7;
        size_t base = (size_t)((n*5 + pg/96)*96 + (pg%96)) * LFV_IMG
                    + (size_t)u * 96 + pnh*8 + psh;
#pragma unroll
        for (int rg = 0; rg < 4; ++rg) {
            float x = acc[f][rg];
            x = x > 0.f ? x : 0.1f * x;
            a1[base + (size_t)(co0 + hi*4 + rg) * 480] = x;
        }
    }
}

// ---------------------------------------------------------------------------
// K5n: 3x3 conv via inline-asm MFMA, u-fused tile  (r15/r16 verbatim, passing)
// ---------------------------------------------------------------------------
__global__ __launch_bounds__(256) void k5n_conv3(const float* __restrict__ lfV,
                                                 const float* __restrict__ a1,
                                                 const unsigned short* __restrict__ w2h,
                                                 float* __restrict__ outp) {
    int blk = blockIdx.x;             // grid 1440 = nv*144 + wt*6 + ht
    int ht = blk % 6;  int r = blk / 6;
    int wt = r % 24;   int nv = r / 24;    // nv = n*5 + v
    int w0 = wt * 4, h0 = ht * 16;
    int imgbase = nv * 96 + w0;

    __shared__ unsigned short ins[360][64];   // 46,080 B

    int t = threadIdx.x;
    int lane = t & 63, wv = t >> 6, l15 = lane & 15, hi = lane >> 4;
    int wl = l15 & 3;                 // output w within tile
    int hl = wv * 4 + (l15 >> 2);     // output h within tile (wave-split)

    f32x4 acc[5][4] = {};
#pragma unroll
    for (int u = 0; u < 5; ++u)
#pragma unroll
        for (int j = 0; j < 4; ++j)
            asm volatile("s_nop 1" : "+v"(acc[u][j]));

    for (int cc = 0; cc < 2; ++cc) {
        const float* basep = cc ? a1 : lfV;
        if (cc) __syncthreads();
        // stage: e = (ci, uin, w, g): float4 over 4 h, cvt bf16, b16 scatter
        for (int i = 0; i < 30; ++i) {
            int e = i * 256 + t;              // 7680 = 64*5*4*6
            int g   = e % 6;
            int w   = (e / 6) & 3;
            int uin = (e / 24) % 5;
            int ci  = e / 120;
            int hbase = h0 - 4 + g * 4;       // aligned float4 chunk
            float4 vv = {0.f, 0.f, 0.f, 0.f};
            if (hbase >= 0 && hbase <= 92)
                vv = *(const float4*)(basep + (size_t)(imgbase + w) * LFV_IMG
                      + (size_t)ci * 480 + uin * 96 + hbase);
            int sbase = (w*5 + uin) * 18;
            int hp0 = g*4 - 3;                // hp of vv.x  (in [-3, 17])
            int cch = ci >> 3, clo = ci & 7;
            if (hp0 >= 0) {                               // hp0 <= 17 always
                int s = sbase + hp0;
                ins[s][((cch ^ (s & 7)) << 3) | clo] = f2bf(vv.x);
            }
            if (hp0 + 1 >= 0 && hp0 + 1 < 18) {
                int s = sbase + hp0 + 1;
                ins[s][((cch ^ (s & 7)) << 3) | clo] = f2bf(vv.y);
            }
            if (hp0 + 2 >= 0 && hp0 + 2 < 18) {
                int s = sbase + hp0 + 2;
                ins[s][((cch ^ (s & 7)) << 3) | clo] = f2bf(vv.z);
            }
            if (hp0 + 3 < 18) {                           // hp0+3 >= 0 always
                int s = sbase + hp0 + 3;
                ins[s][((cch ^ (s & 7)) << 3) | clo] = f2bf(vv.w);
            }
        }
        __syncthreads();

        // compute: K-steps (du,dh,kk); B-frag per u feeds 4 co-frag MFMAs
        for (int du = 0; du < 3; ++du) {
#pragma unroll
            for (int dh = 0; dh < 3; ++dh)
#pragma unroll
            for (int kk = 0; kk < 2; ++kk) {
                const unsigned short* wp = w2h + cc*576 + (du*3 + dh)*64
                                         + kk*32 + hi*8 + (size_t)l15*1152;
                i32x4 a0 = *(const i32x4*)(wp);
                i32x4 a1f = *(const i32x4*)(wp + 16*1152);
                i32x4 a2 = *(const i32x4*)(wp + 32*1152);
                i32x4 a3 = *(const i32x4*)(wp + 48*1152);
#pragma unroll
                for (int u = 0; u < 5; ++u) {
                    int uin = u + du - 1;
                    if (uin < 0 || uin > 4) continue;   // u-halo: exact skip
                    int s = (wl*5 + uin)*18 + hl + dh;
                    i32x4 bv = *(const i32x4*)&ins[s][((kk*4 + hi) ^ (s & 7)) << 3];
                    mfma_bf16_16x16x32(acc[u][0], a0, bv);
                    mfma_bf16_16x16x32(acc[u][1], a1f, bv);
                    mfma_bf16_16x16x32(acc[u][2], a2, bv);
                    mfma_bf16_16x16x32(acc[u][3], a3, bv);
                }
            }
        }
        if (!cc) __syncthreads();   // protect ins reuse before second stage
    }
#pragma unroll
    for (int u = 0; u < 5; ++u)
#pragma unroll
        for (int j = 0; j < 4; ++j)
            asm volatile("s_nop 7\ns_nop 7" : "+v"(acc[u][j]));

    // leaky + permuted store: out[(n*25+u*5+v)][co][h0+hl][w0+wl]
    int n = nv / 5, v = nv % 5;
#pragma unroll
    for (int u = 0; u < 5; ++u) {
        size_t ob = (size_t)((n*25 + u*5 + v) * 64) * IMG_HW
                  + (size_t)(h0 + hl) * 96 + w0 + wl;
#pragma unroll
        for (int j = 0; j < 4; ++j) {
#pragma unroll
            for (int rg = 0; rg < 4; ++rg) {
                int co = j*16 + hi*4 + rg;
                float x = acc[u][j][rg];
                x = x > 0.f ? x : 0.1f * x;
                outp[ob + (size_t)co * IMG_HW] = x;
            }
        }
    }
}

// ---------------------------------------------------------------------------
extern "C" void kernel_launch(void* const* d_in, const int* in_sizes, int n_in,
                              void* d_out, int out_size, void* d_ws, size_t ws_size,
                              hipStream_t stream) {
    const float* lf_fea = (const float*)d_in[0];
    const float* w1     = (const float*)d_in[1];
    const float* w2     = (const float*)d_in[2];
    float* outp = (float*)d_out;

    char* ws = (char*)d_ws;
    // ws layout (bytes) — r8/r11 EXACT footprint (proven in-bounds):
    //   lfV : 117,964,800  @ 0
    //   a1  : 117,964,800  @ 117,964,800   (Gpart 88,473,600 aliases its head:
    //                                       k2a/k2b finish before k4 writes a1)
    //   dist:  22,118,400  @ 235,929,600   (w2h+w1h alias its head AFTER k3)
    //   sq  :      46,080  @ 258,048,000
    //   idx :      69,120  @ 258,094,080   (end 258,163,200)
    float* lfV   = (float*)(ws);
    float* a1    = (float*)(ws + 117964800ull);
    float* Gpart = (float*)(ws + 117964800ull);   // aliases a1 (consumed first)
    float* dist  = (float*)(ws + 235929600ull);
    float* sq    = (float*)(ws + 258048000ull);
    int*   idx   = (int*)  (ws + 258094080ull);
    unsigned short* w2h = (unsigned short*)(ws + 235929600ull);  // reuses dist
    unsigned short* w1h = (unsigned short*)(ws + 235929600ull + 147456ull);

    hipLaunchKernelGGL(k0_lfv,   dim3(3200), dim3(256), 0, stream, lf_fea, lfV);
    hipLaunchKernelGGL(k1_sq,    dim3(360),  dim3(256), 0, stream, lf_fea, sq);
    hipLaunchKernelGGL(k2a_gram, dim3(1440), dim3(256), 0, stream, lf_fea, Gpart);
    hipLaunchKernelGGL(k2b_dist, dim3(5400), dim3(256), 0, stream, Gpart, sq, dist);
    hipLaunchKernelGGL(k3_topk,  dim3(2880), dim3(256), 0, stream, dist, idx);
    hipLaunchKernelGGL(kw1_conv, dim3(96),   dim3(256), 0, stream, w1, w1h);
    hipLaunchKernelGGL(kw2_conv, dim3(288),  dim3(256), 0, stream, w2, w2h);
    hipLaunchKernelGGL(k4_conv1, dim3(5760), dim3(256), 0, stream, lfV, w1h, idx, a1);
    hipLaunchKernelGGL(k5n_conv3,dim3(1440), dim3(256), 0, stream, lfV, a1, w2h, outp);
}

// Round 21
// 898.425 us; speedup vs baseline: 2.7833x; 1.0324x over previous
//
#include <hip/hip_runtime.h>
#include <stdint.h>

// Fixed problem config
#define NN   2
#define ANU  5
#define CH   64
#define HH   96
#define WW   96
#define KK   6
#define PSHh 8
#define PNHh 12
#define BB   (NN*PNHh)        // 24
#define PP   (ANU*WW)         // 480
#define CCD  (CH*ANU*PSHh)    // 2560
#define IMG_HW (HH*WW)            // 9216
#define IMG_STRIDE (CH*HH*WW)     // 589824 floats per input image
#define LFV_IMG (CH*ANU*HH)       // 30720 elems per (n,v,w) image in lfVh / a1

typedef int   i32x4 __attribute__((ext_vector_type(4)));
typedef float f32x4 __attribute__((ext_vector_type(4)));

__device__ __forceinline__ unsigned short f2bf(float f) {
    unsigned int u = __float_as_uint(f);
    return (unsigned short)((u + 0x7FFFu + ((u >> 16) & 1u)) >> 16);
}

__device__ __forceinline__ void mfma_bf16_16x16x32(f32x4& d, i32x4 a, i32x4 b) {
    asm volatile("v_mfma_f32_16x16x32_bf16 %0, %1, %2, %0"
                 : "+v"(d) : "v"(a), "v"(b));
}

// ---------------------------------------------------------------------------
// K0: transpose lf_fea[(n,u,v)][c][h][w] -> lfVh[(n,v,w)][c][u][h] (bf16).
//     Same transpose as the passing k0_lfv; store dtype u16 (proven class).
// ---------------------------------------------------------------------------
__global__ __launch_bounds__(256) void k0_lfv(const float* __restrict__ lf_fea,
                                              unsigned short* __restrict__ lfVh) {
    int bc  = blockIdx.x;          // img*64 + c
    int img = bc >> 6;
    int c   = bc & 63;
    int n = img / 25, r = img % 25, u = r / 5, v = r % 5;
    const float* src = lf_fea + (size_t)bc * IMG_HW;
    __shared__ float tile[96][97];
    for (int e = threadIdx.x; e < 96*96; e += 256) {
        int h = e / 96, w = e % 96;
        tile[h][w] = src[e];
    }
    __syncthreads();
    size_t base = (size_t)((n*5 + v)*96) * LFV_IMG + (size_t)c*480 + u*96;
    for (int e = threadIdx.x; e < 96*96; e += 256) {
        int w = e / 96, h = e % 96;
        lfVh[base + (size_t)w * LFV_IMG + h] = f2bf(tile[h][w]);
    }
}

// ---------------------------------------------------------------------------
// K1: sq[b][p] (fp64 accumulate), 8-way column split per row; 360 blocks
// ---------------------------------------------------------------------------
__global__ __launch_bounds__(256) void k1_sq(const float* __restrict__ lf_fea,
                                             float* __restrict__ sq) {
    int t = threadIdx.x;
    int row = blockIdx.x * 32 + (t & 31);      // 0..11519
    int cp = t >> 5;                           // 0..7
    int b = row / PP, p = row % PP;
    int n = b / PNHh, pnh = b % PNHh;
    int v = p / WW, w = p % WW;
    double acc = 0.0;
    for (int ci = 0; ci < 8; ++ci) {
        int c = cp * 8 + ci;
        for (int u = 0; u < 5; ++u) {
            const float* s = lf_fea + ((size_t)((n*25 + u*5 + v)*64 + c)) * IMG_HW
                           + pnh*8*96 + w;
#pragma unroll
            for (int psh = 0; psh < 8; ++psh) {
                float x = s[psh*96];
                acc += (double)x * (double)x;
            }
        }
    }
    __shared__ double red[256];
    red[t] = acc;
    __syncthreads();
    if (t < 32) {
        double ss = 0.0;
#pragma unroll
        for (int j = 0; j < 8; ++j) ss += red[j * 32 + t];
        sq[blockIdx.x * 32 + t] = (float)ss;
    }
}

// ---------------------------------------------------------------------------
// K2a: partial Gram, symmetric (vr<=vc), K-split 4; grid 1440  (r20 verbatim)
// ---------------------------------------------------------------------------
__global__ __launch_bounds__(256) void k2a_gram(const float* __restrict__ lf_fea,
                                                float* __restrict__ Gpart) {
    const int VRt[15] = {0,0,0,0,0,1,1,1,1,2,2,2,3,3,4};
    const int VCt[15] = {0,1,2,3,4,1,2,3,4,2,3,4,3,4,4};
    int blk = blockIdx.x;            // b*60 + pr*4 + ks
    int b  = blk / 60;
    int r0 = blk % 60;
    int pr = r0 / 4, ks = r0 % 4;
    int vr = VRt[pr], vc = VCt[pr];
    int n = b / PNHh, pnh = b % PNHh;

    __shared__ float As[32][96];
    __shared__ float Bs[32][96];

    int t  = threadIdx.x;
    int tx = t & 31, ty = t >> 5;    // 32 x 8 compute tiling
    int sr = t >> 3, sw = t & 7;     // staging: row 0..31, col-base 0..7
    float acc[12][3] = {};

    int kbase = ks * 640;
    for (int kc0 = kbase; kc0 < kbase + 640; kc0 += 32) {
        {
            int cc = kc0 + sr;
            int c = cc / 40, r2 = cc % 40, u = r2 >> 3, psh = r2 & 7;
            size_t off = ((size_t)((n*25 + u*5)*64 + c)) * IMG_HW + (pnh*8 + psh)*96;
            const float* pa = lf_fea + off + (size_t)vr * IMG_STRIDE;
            const float* pb = lf_fea + off + (size_t)vc * IMG_STRIDE;
#pragma unroll
            for (int j = 0; j < 12; ++j) {
                int w = sw + 8*j;
                As[sr][w] = pa[w];
                Bs[sr][w] = pb[w];
            }
        }
        __syncthreads();
        float accC[12][3] = {};
#pragma unroll
        for (int kc = 0; kc < 32; ++kc) {
            float a[12], bq[3];
            *(float4*)&a[0] = *(const float4*)&As[kc][ty*12 + 0];
            *(float4*)&a[4] = *(const float4*)&As[kc][ty*12 + 4];
            *(float4*)&a[8] = *(const float4*)&As[kc][ty*12 + 8];
#pragma unroll
            for (int j = 0; j < 3; ++j) bq[j] = Bs[kc][tx*3 + j];
#pragma unroll
            for (int i = 0; i < 12; ++i)
#pragma unroll
                for (int j = 0; j < 3; ++j)
                    accC[i][j] = fmaf(a[i], bq[j], accC[i][j]);
        }
#pragma unroll
        for (int i = 0; i < 12; ++i)
#pragma unroll
            for (int j = 0; j < 3; ++j)
                acc[i][j] += accC[i][j];
        __syncthreads();
    }

    size_t gbase = ((size_t)(ks*600 + b*25 + vr*5 + vc)) * 9216;
#pragma unroll
    for (int i = 0; i < 12; ++i)
#pragma unroll
        for (int j = 0; j < 3; ++j)
            Gpart[gbase + (ty*12 + i)*96 + tx*3 + j] = acc[i][j];

    if (vr != vc) {
        size_t gbt = ((size_t)(ks*600 + b*25 + vc*5 + vr)) * 9216;
#pragma unroll
        for (int i = 0; i < 12; ++i)
#pragma unroll
            for (int j = 0; j < 3; ++j)
                Gpart[gbt + (tx*3 + j)*96 + ty*12 + i] = acc[i][j];
    }
}

// ---------------------------------------------------------------------------
// K2b: dist[b][p][q] = sq_p + sq_q - 2 * sum_ks Gpart   (r11 verbatim)
// ---------------------------------------------------------------------------
__global__ __launch_bounds__(256) void k2b_dist(const float* __restrict__ Gpart,
                                                const float* __restrict__ sq,
                                                float* __restrict__ dist) {
    int tid = blockIdx.x * 256 + threadIdx.x;   // grid 5400: exactly 1,382,400
    int b = tid / 57600;
    int r = tid % 57600;
    int p = r / 120, qt = r % 120;
    int vr = p / 96, pl = p % 96;
    int vc = qt / 24;
    int ql4 = (qt % 24) * 4;

    size_t tb = ((size_t)(b*25 + vr*5 + vc)) * 9216 + pl*96 + ql4;
    float4 g0 = *(const float4*)(Gpart + tb);
    float4 g1 = *(const float4*)(Gpart + tb +  600ull*9216);
    float4 g2 = *(const float4*)(Gpart + tb + 1200ull*9216);
    float4 g3 = *(const float4*)(Gpart + tb + 1800ull*9216);
    float gx = g0.x + g1.x + g2.x + g3.x;
    float gy = g0.y + g1.y + g2.y + g3.y;
    float gz = g0.z + g1.z + g2.z + g3.z;
    float gw = g0.w + g1.w + g2.w + g3.w;

    float  sqp = sq[b*480 + p];
    float4 sqq = *(const float4*)(sq + b*480 + vc*96 + ql4);
    float4 d;
    d.x = sqp + sqq.x - 2.0f * gx;
    d.y = sqp + sqq.y - 2.0f * gy;
    d.z = sqp + sqq.z - 2.0f * gz;
    d.w = sqp + sqq.w - 2.0f * gw;
    *(float4*)(dist + (size_t)b*230400 + (size_t)p*480 + vc*96 + ql4) = d;
}

// ---------------------------------------------------------------------------
// K3: per-row top-6  (passing, verbatim)
// ---------------------------------------------------------------------------
__global__ __launch_bounds__(256) void k3_topk(const float* __restrict__ dist,
                                               int* __restrict__ idx) {
    int wid  = (blockIdx.x * 256 + threadIdx.x) >> 6;  // global wave id
    int lane = threadIdx.x & 63;
    int b = wid / PP, p = wid % PP;
    const float* row = dist + (size_t)b * PP * PP + (size_t)p * PP;

    unsigned long long key[8];
#pragma unroll
    for (int j = 0; j < 8; ++j) {
        int q = j*64 + lane;
        if (q < PP) {
            unsigned int f = __float_as_uint(row[q]);
            unsigned int mono = f ^ ((f & 0x80000000u) ? 0xFFFFFFFFu : 0x80000000u);
            key[j] = ((unsigned long long)mono << 32) | (unsigned int)q;
        } else {
            key[j] = ~0ull;
        }
    }
    int* outp = idx + ((size_t)b*PP + p) * KK;
    for (int k = 0; k < KK; ++k) {
        unsigned long long m = key[0];
#pragma unroll
        for (int j = 1; j < 8; ++j) m = (key[j] < m) ? key[j] : m;
        for (int s = 1; s < 64; s <<= 1) {
            unsigned long long o = __shfl_xor(m, s, 64);
            m = (o < m) ? o : m;
        }
        if (lane == 0) outp[k] = (int)(m & 0xFFFFFFFFu);
#pragma unroll
        for (int j = 0; j < 8; ++j) if (key[j] == m) key[j] = ~0ull;
    }
}

// ---------------------------------------------------------------------------
// kw1: w1 -> bf16 flat copy w1h[co][k*64+c]  (passing, verbatim)
// ---------------------------------------------------------------------------
__global__ __launch_bounds__(256) void kw1_conv(const float* __restrict__ w1,
                                                unsigned short* __restrict__ w1h) {
    int e = blockIdx.x * 256 + threadIdx.x;   // 24576 total, grid 96
    if (e < 24576) w1h[e] = f2bf(w1[e]);
}

// ---------------------------------------------------------------------------
// kw2: reorder w2 -> bf16 w2h[co][cc][tap][ci64] (passing, verbatim)
// ---------------------------------------------------------------------------
__global__ __launch_bounds__(256) void kw2_conv(const float* __restrict__ w2,
                                                unsigned short* __restrict__ w2h) {
    int e = blockIdx.x * 256 + threadIdx.x;   // 73728 total
    if (e < 73728) {
        int co = e / 1152, r = e % 1152;
        int cc = r / 576, r2 = r % 576;
        int tap = r2 / 64, ci_l = r2 % 64;
        w2h[e] = f2bf(w2[co*1152 + (cc*64 + ci_l)*9 + tap]);
    }
}

// ---------------------------------------------------------------------------
// K4: gather + 1x1 conv via inline-asm MFMA (r20 core).
//     Gather now reads bf16 lfVh (ushort4 = 8B loads, traffic halved, no
//     f2bf); LDS stores stay scalar u16 with identical swizzled indices.
//     Values bit-identical to r20 (same f2bf rounding point).
// ---------------------------------------------------------------------------
__global__ __launch_bounds__(256) void k4_conv1(const unsigned short* __restrict__ lfVh,
                                                const unsigned short* __restrict__ w1h,
                                                const int* __restrict__ idxg,
                                                float* __restrict__ a1) {
    int blk = blockIdx.x;            // b*240 + ptile
    int b = blk / 240, ptile = blk % 240;
    int n = b / PNHh, pnh = b % PNHh;
    int p0 = ptile * 2;

    __shared__ unsigned short Bs[80][384];   // [col][swizzled krow] bf16
    __shared__ int idxs[12];

    int t = threadIdx.x;
    if (t < 12) idxs[t] = idxg[(b*PP + p0 + t/6)*KK + (t % 6)];
    __syncthreads();

    for (int i = 0; i < 30; ++i) {
        int e = i * 256 + t;               // 7680 = 2*6*64*5*2
        int half = e & 1;
        int u    = (e >> 1) % 5;
        int c    = ((e >> 1) / 5) % 64;
        int k    = ((e >> 1) / 320) % 6;
        int pl   = e / 3840;
        int q = idxs[pl * 6 + k];
        const unsigned short* src = lfVh
            + (size_t)((n*5 + q/96)*96 + (q%96)) * LFV_IMG
            + (size_t)c*480 + u*96 + pnh*8 + half*4;
        ushort4 vv = *(const ushort4*)src;
        int colbase = pl*40 + u*8 + half*4;
        int krow = k*64 + c;
        int kc = krow >> 3, kl = krow & 7;   // chunk 0..47, low 0..7
        int c0 = colbase + 0, c1 = colbase + 1, c2 = colbase + 2, c3 = colbase + 3;
        Bs[c0][(((kc & ~7) | ((kc & 7) ^ (c0 & 7))) << 3) | kl] = vv.x;
        Bs[c1][(((kc & ~7) | ((kc & 7) ^ (c1 & 7))) << 3) | kl] = vv.y;
        Bs[c2][(((kc & ~7) | ((kc & 7) ^ (c2 & 7))) << 3) | kl] = vv.z;
        Bs[c3][(((kc & ~7) | ((kc & 7) ^ (c3 & 7))) << 3) | kl] = vv.w;
    }
    __syncthreads();

    int lane = t & 63, wv = t >> 6;
    int l15 = lane & 15, hi = lane >> 4;
    int co0 = wv * 16;
    f32x4 acc[5] = {};
#pragma unroll
    for (int f = 0; f < 5; ++f)
        asm volatile("s_nop 1" : "+v"(acc[f]));

    const unsigned short* ap = w1h + (size_t)(co0 + l15) * 384 + hi * 8;
    for (int ks = 0; ks < 12; ++ks) {
        i32x4 a = *(const i32x4*)(ap + ks * 32);
        asm volatile("s_nop 1" : "+v"(a));
#pragma unroll
        for (int f = 0; f < 5; ++f) {
            int col = f * 16 + l15;
            int ch = ks * 4 + hi;            // chunk 0..47
            int chs = (ch & ~7) | ((ch & 7) ^ (col & 7));
            i32x4 bv = *(const i32x4*)&Bs[col][chs << 3];
            mfma_bf16_16x16x32(acc[f], a, bv);
        }
    }
#pragma unroll
    for (int f = 0; f < 5; ++f)
        asm volatile("s_nop 7\ns_nop 7" : "+v"(acc[f]));

#pragma unroll
    for (int f = 0; f < 5; ++f) {
        int col = f * 16 + l15;
        int pg = p0 + col / 40, rr = col % 40;
        int u = rr >> 3, psh = rr & 7;
        size_t base = (size_t)((n*5 + pg/96)*96 + (pg%96)) * LFV_IMG
                    + (size_t)u * 96 + pnh*8 + psh;
#pragma unroll
        for (int rg = 0; rg < 4; ++rg) {
            float x = acc[f][rg];
            x = x > 0.f ? x : 0.1f * x;
            a1[base + (size_t)(co0 + hi*4 + rg) * 480] = x;
        }
    }
}

// ---------------------------------------------------------------------------
// K5n: 3x3 conv via inline-asm MFMA, u-fused tile (r20 core).
//      cc=0 stages from bf16 lfVh (ushort4 loads, no f2bf); cc=1 stages
//      from fp32 a1 (float4 + f2bf, unchanged). Same guards & LDS indices.
// ---------------------------------------------------------------------------
__global__ __launch_bounds__(256) void k5n_conv3(const unsigned short* __restrict__ lfVh,
                                                 const float* __restrict__ a1,
                                                 const unsigned short* __restrict__ w2h,
                                                 float* __restrict__ outp) {
    int blk = blockIdx.x;             // grid 1440 = nv*144 + wt*6 + ht
    int ht = blk % 6;  int r = blk / 6;
    int wt = r % 24;   int nv = r / 24;    // nv = n*5 + v
    int w0 = wt * 4, h0 = ht * 16;
    int imgbase = nv * 96 + w0;

    __shared__ unsigned short ins[360][64];   // 46,080 B

    int t = threadIdx.x;
    int lane = t & 63, wv = t >> 6, l15 = lane & 15, hi = lane >> 4;
    int wl = l15 & 3;                 // output w within tile
    int hl = wv * 4 + (l15 >> 2);     // output h within tile (wave-split)

    f32x4 acc[5][4] = {};
#pragma unroll
    for (int u = 0; u < 5; ++u)
#pragma unroll
        for (int j = 0; j < 4; ++j)
            asm volatile("s_nop 1" : "+v"(acc[u][j]));

    for (int cc = 0; cc < 2; ++cc) {
        if (cc) __syncthreads();
        // stage: e = (ci, uin, w, g): 4 h-values, b16 scatter with guards
        for (int i = 0; i < 30; ++i) {
            int e = i * 256 + t;              // 7680 = 64*5*4*6
            int g   = e % 6;
            int w   = (e / 6) & 3;
            int uin = (e / 24) % 5;
            int ci  = e / 120;
            int hbase = h0 - 4 + g * 4;       // aligned chunk of 4 h-values
            unsigned short b0 = 0, b1 = 0, b2 = 0, b3 = 0;
            if (hbase >= 0 && hbase <= 92) {
                size_t off = (size_t)(imgbase + w) * LFV_IMG
                           + (size_t)ci * 480 + uin * 96 + hbase;
                if (cc == 0) {
                    ushort4 vv = *(const ushort4*)(lfVh + off);
                    b0 = vv.x; b1 = vv.y; b2 = vv.z; b3 = vv.w;
                } else {
                    float4 vv = *(const float4*)(a1 + off);
                    b0 = f2bf(vv.x); b1 = f2bf(vv.y);
                    b2 = f2bf(vv.z); b3 = f2bf(vv.w);
                }
            }
            int sbase = (w*5 + uin) * 18;
            int hp0 = g*4 - 3;                // hp of element 0 (in [-3, 17])
            int cch = ci >> 3, clo = ci & 7;
            if (hp0 >= 0) {                               // hp0 <= 17 always
                int s = sbase + hp0;
                ins[s][((cch ^ (s & 7)) << 3) | clo] = b0;
            }
            if (hp0 + 1 >= 0 && hp0 + 1 < 18) {
                int s = sbase + hp0 + 1;
                ins[s][((cch ^ (s & 7)) << 3) | clo] = b1;
            }
            if (hp0 + 2 >= 0 && hp0 + 2 < 18) {
                int s = sbase + hp0 + 2;
                ins[s][((cch ^ (s & 7)) << 3) | clo] = b2;
            }
            if (hp0 + 3 < 18) {                           // hp0+3 >= 0 always
                int s = sbase + hp0 + 3;
                ins[s][((cch ^ (s & 7)) << 3) | clo] = b3;
            }
        }
        __syncthreads();

        // compute: K-steps (du,dh,kk); B-frag per u feeds 4 co-frag MFMAs
        for (int du = 0; du < 3; ++du) {
#pragma unroll
            for (int dh = 0; dh < 3; ++dh)
#pragma unroll
            for (int kk = 0; kk < 2; ++kk) {
                const unsigned short* wp = w2h + cc*576 + (du*3 + dh)*64
                                         + kk*32 + hi*8 + (size_t)l15*1152;
                i32x4 a0 = *(const i32x4*)(wp);
                i32x4 a1f = *(const i32x4*)(wp + 16*1152);
                i32x4 a2 = *(const i32x4*)(wp + 32*1152);
                i32x4 a3 = *(const i32x4*)(wp + 48*1152);
#pragma unroll
                for (int u = 0; u < 5; ++u) {
                    int uin = u + du - 1;
                    if (uin < 0 || uin > 4) continue;   // u-halo: exact skip
                    int s = (wl*5 + uin)*18 + hl + dh;
                    i32x4 bv = *(const i32x4*)&ins[s][((kk*4 + hi) ^ (s & 7)) << 3];
                    mfma_bf16_16x16x32(acc[u][0], a0, bv);
                    mfma_bf16_16x16x32(acc[u][1], a1f, bv);
                    mfma_bf16_16x16x32(acc[u][2], a2, bv);
                    mfma_bf16_16x16x32(acc[u][3], a3, bv);
                }
            }
        }
        if (!cc) __syncthreads();   // protect ins reuse before second stage
    }
#pragma unroll
    for (int u = 0; u < 5; ++u)
#pragma unroll
        for (int j = 0; j < 4; ++j)
            asm volatile("s_nop 7\ns_nop 7" : "+v"(acc[u][j]));

    // leaky + permuted store: out[(n*25+u*5+v)][co][h0+hl][w0+wl]
    int n = nv / 5, v = nv % 5;
#pragma unroll
    for (int u = 0; u < 5; ++u) {
        size_t ob = (size_t)((n*25 + u*5 + v) * 64) * IMG_HW
                  + (size_t)(h0 + hl) * 96 + w0 + wl;
#pragma unroll
        for (int j = 0; j < 4; ++j) {
#pragma unroll
            for (int rg = 0; rg < 4; ++rg) {
                int co = j*16 + hi*4 + rg;
                float x = acc[u][j][rg];
                x = x > 0.f ? x : 0.1f * x;
                outp[ob + (size_t)co * IMG_HW] = x;
            }
        }
    }
}

// ---------------------------------------------------------------------------
extern "C" void kernel_launch(void* const* d_in, const int* in_sizes, int n_in,
                              void* d_out, int out_size, void* d_ws, size_t ws_size,
                              hipStream_t stream) {
    const float* lf_fea = (const float*)d_in[0];
    const float* w1     = (const float*)d_in[1];
    const float* w2     = (const float*)d_in[2];
    float* outp = (float*)d_out;

    char* ws = (char*)d_ws;
    // ws layout (bytes), end ~199.3 MB (< proven 258 MB footprint):
    //   lfVh :  58,982,400 @ 0                       (bf16)
    //   a1   : 117,964,800 @  58,982,400             (fp32; Gpart aliases its
    //                                                 head, consumed before k4)
    //   dist :  22,118,400 @ 176,947,200             (w2h/w1h alias after k3)
    //   sq   :      46,080 @ 199,065,600
    //   idx  :      69,120 @ 199,111,680   (end 199,180,800)
    unsigned short* lfVh = (unsigned short*)(ws);
    float* a1    = (float*)(ws + 58982400ull);
    float* Gpart = (float*)(ws + 58982400ull);    // aliases a1 (consumed first)
    float* dist  = (float*)(ws + 176947200ull);
    float* sq    = (float*)(ws + 199065600ull);
    int*   idx   = (int*)  (ws + 199111680ull);
    unsigned short* w2h = (unsigned short*)(ws + 176947200ull);  // reuses dist
    unsigned short* w1h = (unsigned short*)(ws + 176947200ull + 147456ull);

    hipLaunchKernelGGL(k0_lfv,   dim3(3200), dim3(256), 0, stream, lf_fea, lfVh);
    hipLaunchKernelGGL(k1_sq,    dim3(360),  dim3(256), 0, stream, lf_fea, sq);
    hipLaunchKernelGGL(k2a_gram, dim3(1440), dim3(256), 0, stream, lf_fea, Gpart);
    hipLaunchKernelGGL(k2b_dist, dim3(5400), dim3(256), 0, stream, Gpart, sq, dist);
    hipLaunchKernelGGL(k3_topk,  dim3(2880), dim3(256), 0, stream, dist, idx);
    hipLaunchKernelGGL(kw1_conv, dim3(96),   dim3(256), 0, stream, w1, w1h);
    hipLaunchKernelGGL(kw2_conv, dim3(288),  dim3(256), 0, stream, w2, w2h);
    hipLaunchKernelGGL(k4_conv1, dim3(5760), dim3(256), 0, stream, lfVh, w1h, idx, a1);
    hipLaunchKernelGGL(k5n_conv3,dim3(1440), dim3(256), 0, stream, lfVh, a1, w2h, outp);
}

// Round 22
// 841.791 us; speedup vs baseline: 2.9706x; 1.0673x over previous
//
#include <hip/hip_runtime.h>
#include <stdint.h>

// Fixed problem config
#define NN   2
#define ANU  5
#define CH   64
#define HH   96
#define WW   96
#define KK   6
#define PSHh 8
#define PNHh 12
#define BB   (NN*PNHh)        // 24
#define PP   (ANU*WW)         // 480
#define CCD  (CH*ANU*PSHh)    // 2560
#define IMG_HW (HH*WW)            // 9216
#define IMG_STRIDE (CH*HH*WW)     // 589824 floats per input image
#define LFV_IMG (CH*ANU*HH)       // 30720 elems per (n,v,w) image in lfVh / a1

typedef int   i32x4 __attribute__((ext_vector_type(4)));
typedef float f32x4 __attribute__((ext_vector_type(4)));

__device__ __forceinline__ unsigned short f2bf(float f) {
    unsigned int u = __float_as_uint(f);
    return (unsigned short)((u + 0x7FFFu + ((u >> 16) & 1u)) >> 16);
}

__device__ __forceinline__ void mfma_bf16_16x16x32(f32x4& d, i32x4 a, i32x4 b) {
    asm volatile("v_mfma_f32_16x16x32_bf16 %0, %1, %2, %0"
                 : "+v"(d) : "v"(a), "v"(b));
}

// ---------------------------------------------------------------------------
// K0: transpose lf_fea[(n,u,v)][c][h][w] -> lfVh[(n,v,w)][c][u][h] (bf16)
//     (r21 verbatim, passing)
// ---------------------------------------------------------------------------
__global__ __launch_bounds__(256) void k0_lfv(const float* __restrict__ lf_fea,
                                              unsigned short* __restrict__ lfVh) {
    int bc  = blockIdx.x;          // img*64 + c
    int img = bc >> 6;
    int c   = bc & 63;
    int n = img / 25, r = img % 25, u = r / 5, v = r % 5;
    const float* src = lf_fea + (size_t)bc * IMG_HW;
    __shared__ float tile[96][97];
    for (int e = threadIdx.x; e < 96*96; e += 256) {
        int h = e / 96, w = e % 96;
        tile[h][w] = src[e];
    }
    __syncthreads();
    size_t base = (size_t)((n*5 + v)*96) * LFV_IMG + (size_t)c*480 + u*96;
    for (int e = threadIdx.x; e < 96*96; e += 256) {
        int w = e / 96, h = e % 96;
        lfVh[base + (size_t)w * LFV_IMG + h] = f2bf(tile[h][w]);
    }
}

// ---------------------------------------------------------------------------
// K0g: pack lf_fea -> lfG[(n,pnh)][p=(v,w)][c][u][psh] (bf16, gather-optimal:
//      each (b,p) feature column = contiguous 5120B). LDS float b32 writes,
//      u16 global stores (proven classes). grid = 50 img x 12 pnh x 4 ctile.
// ---------------------------------------------------------------------------
__global__ __launch_bounds__(256) void k0g_pack(const float* __restrict__ lf,
                                                unsigned short* __restrict__ lfG) {
    int blk = blockIdx.x;            // ((img*12 + pnh)*4 + ct), grid 2400
    int ct = blk & 3; int r = blk >> 2;
    int pnh = r % 12, img = r / 12;
    int n = img / 25, rr = img % 25, u = rr / 5, v = rr % 5;
    int c0 = ct * 16;
    __shared__ float tile[16][8][97];
    int t = threadIdx.x;
    const float* src = lf + (size_t)img * IMG_STRIDE + (size_t)c0 * IMG_HW + pnh*768;
#pragma unroll
    for (int i = 0; i < 12; ++i) {
        int e = i*256 + t;           // 3072 float4
        int ci = e / 192, r2 = e % 192, psh = r2 / 24, q2 = r2 % 24;
        float4 vv = *(const float4*)(src + (size_t)ci*IMG_HW + psh*96 + q2*4);
        tile[ci][psh][q2*4+0]=vv.x; tile[ci][psh][q2*4+1]=vv.y;
        tile[ci][psh][q2*4+2]=vv.z; tile[ci][psh][q2*4+3]=vv.w;
    }
    __syncthreads();
    size_t ob = ((size_t)((n*12+pnh)*480 + v*96)) * 2560 + c0*40 + u*8;
#pragma unroll
    for (int i = 0; i < 24; ++i) {
        int e = i*256 + t;           // 6144 units = (w, ci, psh-pair)
        int w = e >> 6, r2 = e & 63, ci = r2 >> 2, pp = r2 & 3;
        size_t off = ob + (size_t)w*2560 + ci*40 + pp*2;
        lfG[off]     = f2bf(tile[ci][pp*2][w]);
        lfG[off + 1] = f2bf(tile[ci][pp*2+1][w]);
    }
}

// ---------------------------------------------------------------------------
// K1: sq[b][p] (fp64 accumulate), 8-way column split per row; 360 blocks
// ---------------------------------------------------------------------------
__global__ __launch_bounds__(256) void k1_sq(const float* __restrict__ lf_fea,
                                             float* __restrict__ sq) {
    int t = threadIdx.x;
    int row = blockIdx.x * 32 + (t & 31);      // 0..11519
    int cp = t >> 5;                           // 0..7
    int b = row / PP, p = row % PP;
    int n = b / PNHh, pnh = b % PNHh;
    int v = p / WW, w = p % WW;
    double acc = 0.0;
    for (int ci = 0; ci < 8; ++ci) {
        int c = cp * 8 + ci;
        for (int u = 0; u < 5; ++u) {
            const float* s = lf_fea + ((size_t)((n*25 + u*5 + v)*64 + c)) * IMG_HW
                           + pnh*8*96 + w;
#pragma unroll
            for (int psh = 0; psh < 8; ++psh) {
                float x = s[psh*96];
                acc += (double)x * (double)x;
            }
        }
    }
    __shared__ double red[256];
    red[t] = acc;
    __syncthreads();
    if (t < 32) {
        double ss = 0.0;
#pragma unroll
        for (int j = 0; j < 8; ++j) ss += red[j * 32 + t];
        sq[blockIdx.x * 32 + t] = (float)ss;
    }
}

// ---------------------------------------------------------------------------
// K2a: partial Gram, symmetric (vr<=vc), K-split 4; grid 1440  (r21 verbatim)
// ---------------------------------------------------------------------------
__global__ __launch_bounds__(256) void k2a_gram(const float* __restrict__ lf_fea,
                                                float* __restrict__ Gpart) {
    const int VRt[15] = {0,0,0,0,0,1,1,1,1,2,2,2,3,3,4};
    const int VCt[15] = {0,1,2,3,4,1,2,3,4,2,3,4,3,4,4};
    int blk = blockIdx.x;            // b*60 + pr*4 + ks
    int b  = blk / 60;
    int r0 = blk % 60;
    int pr = r0 / 4, ks = r0 % 4;
    int vr = VRt[pr], vc = VCt[pr];
    int n = b / PNHh, pnh = b % PNHh;

    __shared__ float As[32][96];
    __shared__ float Bs[32][96];

    int t  = threadIdx.x;
    int tx = t & 31, ty = t >> 5;    // 32 x 8 compute tiling
    int sr = t >> 3, sw = t & 7;     // staging: row 0..31, col-base 0..7
    float acc[12][3] = {};

    int kbase = ks * 640;
    for (int kc0 = kbase; kc0 < kbase + 640; kc0 += 32) {
        {
            int cc = kc0 + sr;
            int c = cc / 40, r2 = cc % 40, u = r2 >> 3, psh = r2 & 7;
            size_t off = ((size_t)((n*25 + u*5)*64 + c)) * IMG_HW + (pnh*8 + psh)*96;
            const float* pa = lf_fea + off + (size_t)vr * IMG_STRIDE;
            const float* pb = lf_fea + off + (size_t)vc * IMG_STRIDE;
#pragma unroll
            for (int j = 0; j < 12; ++j) {
                int w = sw + 8*j;
                As[sr][w] = pa[w];
                Bs[sr][w] = pb[w];
            }
        }
        __syncthreads();
        float accC[12][3] = {};
#pragma unroll
        for (int kc = 0; kc < 32; ++kc) {
            float a[12], bq[3];
            *(float4*)&a[0] = *(const float4*)&As[kc][ty*12 + 0];
            *(float4*)&a[4] = *(const float4*)&As[kc][ty*12 + 4];
            *(float4*)&a[8] = *(const float4*)&As[kc][ty*12 + 8];
#pragma unroll
            for (int j = 0; j < 3; ++j) bq[j] = Bs[kc][tx*3 + j];
#pragma unroll
            for (int i = 0; i < 12; ++i)
#pragma unroll
                for (int j = 0; j < 3; ++j)
                    accC[i][j] = fmaf(a[i], bq[j], accC[i][j]);
        }
#pragma unroll
        for (int i = 0; i < 12; ++i)
#pragma unroll
            for (int j = 0; j < 3; ++j)
                acc[i][j] += accC[i][j];
        __syncthreads();
    }

    size_t gbase = ((size_t)(ks*600 + b*25 + vr*5 + vc)) * 9216;
#pragma unroll
    for (int i = 0; i < 12; ++i)
#pragma unroll
        for (int j = 0; j < 3; ++j)
            Gpart[gbase + (ty*12 + i)*96 + tx*3 + j] = acc[i][j];

    if (vr != vc) {
        size_t gbt = ((size_t)(ks*600 + b*25 + vc*5 + vr)) * 9216;
#pragma unroll
        for (int i = 0; i < 12; ++i)
#pragma unroll
            for (int j = 0; j < 3; ++j)
                Gpart[gbt + (tx*3 + j)*96 + ty*12 + i] = acc[i][j];
    }
}

// ---------------------------------------------------------------------------
// K2b: dist[b][p][q] = sq_p + sq_q - 2 * sum_ks Gpart   (r11 verbatim)
// ---------------------------------------------------------------------------
__global__ __launch_bounds__(256) void k2b_dist(const float* __restrict__ Gpart,
                                                const float* __restrict__ sq,
                                                float* __restrict__ dist) {
    int tid = blockIdx.x * 256 + threadIdx.x;   // grid 5400: exactly 1,382,400
    int b = tid / 57600;
    int r = tid % 57600;
    int p = r / 120, qt = r % 120;
    int vr = p / 96, pl = p % 96;
    int vc = qt / 24;
    int ql4 = (qt % 24) * 4;

    size_t tb = ((size_t)(b*25 + vr*5 + vc)) * 9216 + pl*96 + ql4;
    float4 g0 = *(const float4*)(Gpart + tb);
    float4 g1 = *(const float4*)(Gpart + tb +  600ull*9216);
    float4 g2 = *(const float4*)(Gpart + tb + 1200ull*9216);
    float4 g3 = *(const float4*)(Gpart + tb + 1800ull*9216);
    float gx = g0.x + g1.x + g2.x + g3.x;
    float gy = g0.y + g1.y + g2.y + g3.y;
    float gz = g0.z + g1.z + g2.z + g3.z;
    float gw = g0.w + g1.w + g2.w + g3.w;

    float  sqp = sq[b*480 + p];
    float4 sqq = *(const float4*)(sq + b*480 + vc*96 + ql4);
    float4 d;
    d.x = sqp + sqq.x - 2.0f * gx;
    d.y = sqp + sqq.y - 2.0f * gy;
    d.z = sqp + sqq.z - 2.0f * gz;
    d.w = sqp + sqq.w - 2.0f * gw;
    *(float4*)(dist + (size_t)b*230400 + (size_t)p*480 + vc*96 + ql4) = d;
}

// ---------------------------------------------------------------------------
// K3: per-row top-6  (passing, verbatim)
// ---------------------------------------------------------------------------
__global__ __launch_bounds__(256) void k3_topk(const float* __restrict__ dist,
                                               int* __restrict__ idx) {
    int wid  = (blockIdx.x * 256 + threadIdx.x) >> 6;  // global wave id
    int lane = threadIdx.x & 63;
    int b = wid / PP, p = wid % PP;
    const float* row = dist + (size_t)b * PP * PP + (size_t)p * PP;

    unsigned long long key[8];
#pragma unroll
    for (int j = 0; j < 8; ++j) {
        int q = j*64 + lane;
        if (q < PP) {
            unsigned int f = __float_as_uint(row[q]);
            unsigned int mono = f ^ ((f & 0x80000000u) ? 0xFFFFFFFFu : 0x80000000u);
            key[j] = ((unsigned long long)mono << 32) | (unsigned int)q;
        } else {
            key[j] = ~0ull;
        }
    }
    int* outp = idx + ((size_t)b*PP + p) * KK;
    for (int k = 0; k < KK; ++k) {
        unsigned long long m = key[0];
#pragma unroll
        for (int j = 1; j < 8; ++j) m = (key[j] < m) ? key[j] : m;
        for (int s = 1; s < 64; s <<= 1) {
            unsigned long long o = __shfl_xor(m, s, 64);
            m = (o < m) ? o : m;
        }
        if (lane == 0) outp[k] = (int)(m & 0xFFFFFFFFu);
#pragma unroll
        for (int j = 0; j < 8; ++j) if (key[j] == m) key[j] = ~0ull;
    }
}

// ---------------------------------------------------------------------------
// kw1: w1 -> bf16 flat copy w1h[co][k*64+c]  (passing, verbatim)
// ---------------------------------------------------------------------------
__global__ __launch_bounds__(256) void kw1_conv(const float* __restrict__ w1,
                                                unsigned short* __restrict__ w1h) {
    int e = blockIdx.x * 256 + threadIdx.x;   // 24576 total, grid 96
    if (e < 24576) w1h[e] = f2bf(w1[e]);
}

// ---------------------------------------------------------------------------
// kw2: reorder w2 -> bf16 w2h[co][cc][tap][ci64] (passing, verbatim)
// ---------------------------------------------------------------------------
__global__ __launch_bounds__(256) void kw2_conv(const float* __restrict__ w2,
                                                unsigned short* __restrict__ w2h) {
    int e = blockIdx.x * 256 + threadIdx.x;   // 73728 total
    if (e < 73728) {
        int co = e / 1152, r = e % 1152;
        int cc = r / 576, r2 = r % 576;
        int tap = r2 / 64, ci_l = r2 % 64;
        w2h[e] = f2bf(w2[co*1152 + (cc*64 + ci_l)*9 + tap]);
    }
}

// ---------------------------------------------------------------------------
// K4: gather + 1x1 conv via inline-asm MFMA (r21 compute core verbatim).
//     Gather now from lfG: per (pl,k) the whole 5120B feature column is
//     walked with consecutive 16B loads (fully-used cache lines).
//     Each 16B unit = one (c,u), psh 0..7 -> 8 consecutive LDS columns;
//     colbase % 8 == 0 so col&7 == psh and the r21 swizzle is unchanged.
//     Output bit-identical to r21.
// ---------------------------------------------------------------------------
__global__ __launch_bounds__(256) void k4_conv1(const unsigned short* __restrict__ lfG,
                                                const unsigned short* __restrict__ w1h,
                                                const int* __restrict__ idxg,
                                                float* __restrict__ a1) {
    int blk = blockIdx.x;            // b*240 + ptile
    int b = blk / 240, ptile = blk % 240;
    int n = b / PNHh, pnh = b % PNHh;
    int p0 = ptile * 2;

    __shared__ unsigned short Bs[80][384];   // [col][swizzled krow] bf16
    __shared__ int idxs[12];

    int t = threadIdx.x;
    if (t < 12) idxs[t] = idxg[(b*PP + p0 + t/6)*KK + (t % 6)];
    __syncthreads();

    // stage: 3840 units of 16B; unit = (pl, k, m); m -> (c = m/5, u = m%5)
    for (int i = 0; i < 15; ++i) {
        int e = i * 256 + t;         // 3840 exactly
        int pl = e / 1920, r = e % 1920;
        int k = r / 320, m = r % 320;
        int c = m / 5, u = m % 5;
        int q = idxs[pl*6 + k];
        i32x4 vv = *(const i32x4*)(lfG + ((size_t)(b*480 + q))*2560 + m*8);
        int colbase = pl*40 + u*8;   // multiple of 8
        int krow = k*64 + c;
        int kc = krow >> 3, kl = krow & 7;
        int kbase = kc & ~7, klo = kc & 7;
#pragma unroll
        for (int j = 0; j < 4; ++j) {
            unsigned int d = (unsigned int)vv[j];
            int j0 = 2*j, j1 = 2*j + 1;
            Bs[colbase + j0][((kbase | (klo ^ j0)) << 3) | kl] =
                (unsigned short)(d & 0xFFFFu);
            Bs[colbase + j1][((kbase | (klo ^ j1)) << 3) | kl] =
                (unsigned short)(d >> 16);
        }
    }
    __syncthreads();

    int lane = t & 63, wv = t >> 6;
    int l15 = lane & 15, hi = lane >> 4;
    int co0 = wv * 16;
    f32x4 acc[5] = {};
#pragma unroll
    for (int f = 0; f < 5; ++f)
        asm volatile("s_nop 1" : "+v"(acc[f]));

    const unsigned short* ap = w1h + (size_t)(co0 + l15) * 384 + hi * 8;
    for (int ks = 0; ks < 12; ++ks) {
        i32x4 a = *(const i32x4*)(ap + ks * 32);
        asm volatile("s_nop 1" : "+v"(a));
#pragma unroll
        for (int f = 0; f < 5; ++f) {
            int col = f * 16 + l15;
            int ch = ks * 4 + hi;            // chunk 0..47
            int chs = (ch & ~7) | ((ch & 7) ^ (col & 7));
            i32x4 bv = *(const i32x4*)&Bs[col][chs << 3];
            mfma_bf16_16x16x32(acc[f], a, bv);
        }
    }
#pragma unroll
    for (int f = 0; f < 5; ++f)
        asm volatile("s_nop 7\ns_nop 7" : "+v"(acc[f]));

#pragma unroll
    for (int f = 0; f < 5; ++f) {
        int col = f * 16 + l15;
        int pg = p0 + col / 40, rr = col % 40;
        int u = rr >> 3, psh = rr & 7;
        size_t base = (size_t)((n*5 + pg/96)*96 + (pg%96)) * LFV_IMG
                    + (size_t)u * 96 + pnh*8 + psh;
#pragma unroll
        for (int rg = 0; rg < 4; ++rg) {
            float x = acc[f][rg];
            x = x > 0.f ? x : 0.1f * x;
            a1[base + (size_t)(co0 + hi*4 + rg) * 480] = x;
        }
    }
}

// ---------------------------------------------------------------------------
// K5n: 3x3 conv via inline-asm MFMA, u-fused tile  (r21 verbatim, passing)
// ---------------------------------------------------------------------------
__global__ __launch_bounds__(256) void k5n_conv3(const unsigned short* __restrict__ lfVh,
                                                 const float* __restrict__ a1,
                                                 const unsigned short* __restrict__ w2h,
                                                 float* __restrict__ outp) {
    int blk = blockIdx.x;             // grid 1440 = nv*144 + wt*6 + ht
    int ht = blk % 6;  int r = blk / 6;
    int wt = r % 24;   int nv = r / 24;    // nv = n*5 + v
    int w0 = wt * 4, h0 = ht * 16;
    int imgbase = nv * 96 + w0;

    __shared__ unsigned short ins[360][64];   // 46,080 B

    int t = threadIdx.x;
    int lane = t & 63, wv = t >> 6, l15 = lane & 15, hi = lane >> 4;
    int wl = l15 & 3;                 // output w within tile
    int hl = wv * 4 + (l15 >> 2);     // output h within tile (wave-split)

    f32x4 acc[5][4] = {};
#pragma unroll
    for (int u = 0; u < 5; ++u)
#pragma unroll
        for (int j = 0; j < 4; ++j)
            asm volatile("s_nop 1" : "+v"(acc[u][j]));

    for (int cc = 0; cc < 2; ++cc) {
        if (cc) __syncthreads();
        // stage: e = (ci, uin, w, g): 4 h-values, b16 scatter with guards
        for (int i = 0; i < 30; ++i) {
            int e = i * 256 + t;              // 7680 = 64*5*4*6
            int g   = e % 6;
            int w   = (e / 6) & 3;
            int uin = (e / 24) % 5;
            int ci  = e / 120;
            int hbase = h0 - 4 + g * 4;       // aligned chunk of 4 h-values
            unsigned short b0 = 0, b1 = 0, b2 = 0, b3 = 0;
            if (hbase >= 0 && hbase <= 92) {
                size_t off = (size_t)(imgbase + w) * LFV_IMG
                           + (size_t)ci * 480 + uin * 96 + hbase;
                if (cc == 0) {
                    ushort4 vv = *(const ushort4*)(lfVh + off);
                    b0 = vv.x; b1 = vv.y; b2 = vv.z; b3 = vv.w;
                } else {
                    float4 vv = *(const float4*)(a1 + off);
                    b0 = f2bf(vv.x); b1 = f2bf(vv.y);
                    b2 = f2bf(vv.z); b3 = f2bf(vv.w);
                }
            }
            int sbase = (w*5 + uin) * 18;
            int hp0 = g*4 - 3;                // hp of element 0 (in [-3, 17])
            int cch = ci >> 3, clo = ci & 7;
            if (hp0 >= 0) {                               // hp0 <= 17 always
                int s = sbase + hp0;
                ins[s][((cch ^ (s & 7)) << 3) | clo] = b0;
            }
            if (hp0 + 1 >= 0 && hp0 + 1 < 18) {
                int s = sbase + hp0 + 1;
                ins[s][((cch ^ (s & 7)) << 3) | clo] = b1;
            }
            if (hp0 + 2 >= 0 && hp0 + 2 < 18) {
                int s = sbase + hp0 + 2;
                ins[s][((cch ^ (s & 7)) << 3) | clo] = b2;
            }
            if (hp0 + 3 < 18) {                           // hp0+3 >= 0 always
                int s = sbase + hp0 + 3;
                ins[s][((cch ^ (s & 7)) << 3) | clo] = b3;
            }
        }
        __syncthreads();

        // compute: K-steps (du,dh,kk); B-frag per u feeds 4 co-frag MFMAs
        for (int du = 0; du < 3; ++du) {
#pragma unroll
            for (int dh = 0; dh < 3; ++dh)
#pragma unroll
            for (int kk = 0; kk < 2; ++kk) {
                const unsigned short* wp = w2h + cc*576 + (du*3 + dh)*64
                                         + kk*32 + hi*8 + (size_t)l15*1152;
                i32x4 a0 = *(const i32x4*)(wp);
                i32x4 a1f = *(const i32x4*)(wp + 16*1152);
                i32x4 a2 = *(const i32x4*)(wp + 32*1152);
                i32x4 a3 = *(const i32x4*)(wp + 48*1152);
#pragma unroll
                for (int u = 0; u < 5; ++u) {
                    int uin = u + du - 1;
                    if (uin < 0 || uin > 4) continue;   // u-halo: exact skip
                    int s = (wl*5 + uin)*18 + hl + dh;
                    i32x4 bv = *(const i32x4*)&ins[s][((kk*4 + hi) ^ (s & 7)) << 3];
                    mfma_bf16_16x16x32(acc[u][0], a0, bv);
                    mfma_bf16_16x16x32(acc[u][1], a1f, bv);
                    mfma_bf16_16x16x32(acc[u][2], a2, bv);
                    mfma_bf16_16x16x32(acc[u][3], a3, bv);
                }
            }
        }
        if (!cc) __syncthreads();   // protect ins reuse before second stage
    }
#pragma unroll
    for (int u = 0; u < 5; ++u)
#pragma unroll
        for (int j = 0; j < 4; ++j)
            asm volatile("s_nop 7\ns_nop 7" : "+v"(acc[u][j]));

    // leaky + permuted store: out[(n*25+u*5+v)][co][h0+hl][w0+wl]
    int n = nv / 5, v = nv % 5;
#pragma unroll
    for (int u = 0; u < 5; ++u) {
        size_t ob = (size_t)((n*25 + u*5 + v) * 64) * IMG_HW
                  + (size_t)(h0 + hl) * 96 + w0 + wl;
#pragma unroll
        for (int j = 0; j < 4; ++j) {
#pragma unroll
            for (int rg = 0; rg < 4; ++rg) {
                int co = j*16 + hi*4 + rg;
                float x = acc[u][j][rg];
                x = x > 0.f ? x : 0.1f * x;
                outp[ob + (size_t)co * IMG_HW] = x;
            }
        }
    }
}

// ---------------------------------------------------------------------------
extern "C" void kernel_launch(void* const* d_in, const int* in_sizes, int n_in,
                              void* d_out, int out_size, void* d_ws, size_t ws_size,
                              hipStream_t stream) {
    const float* lf_fea = (const float*)d_in[0];
    const float* w1     = (const float*)d_in[1];
    const float* w2     = (const float*)d_in[2];
    float* outp = (float*)d_out;

    char* ws = (char*)d_ws;
    // ws layout (bytes) — EXACTLY the proven 258,163,200 footprint:
    //   lfVh :  58,982,400 @ 0                       (bf16)
    //   lfG  :  58,982,400 @  58,982,400             (bf16, gather-optimal)
    //   a1   : 117,964,800 @ 117,964,800             (fp32; Gpart aliases its
    //                                                 head, consumed before k4)
    //   dist :  22,118,400 @ 235,929,600             (w2h/w1h alias after k3)
    //   sq   :      46,080 @ 258,048,000
    //   idx  :      69,120 @ 258,094,080   (end 258,163,200)
    unsigned short* lfVh = (unsigned short*)(ws);
    unsigned short* lfG  = (unsigned short*)(ws + 58982400ull);
    float* a1    = (float*)(ws + 117964800ull);
    float* Gpart = (float*)(ws + 117964800ull);   // aliases a1 (consumed first)
    float* dist  = (float*)(ws + 235929600ull);
    float* sq    = (float*)(ws + 258048000ull);
    int*   idx   = (int*)  (ws + 258094080ull);
    unsigned short* w2h = (unsigned short*)(ws + 235929600ull);  // reuses dist
    unsigned short* w1h = (unsigned short*)(ws + 235929600ull + 147456ull);

    hipLaunchKernelGGL(k0_lfv,   dim3(3200), dim3(256), 0, stream, lf_fea, lfVh);
    hipLaunchKernelGGL(k0g_pack, dim3(2400), dim3(256), 0, stream, lf_fea, lfG);
    hipLaunchKernelGGL(k1_sq,    dim3(360),  dim3(256), 0, stream, lf_fea, sq);
    hipLaunchKernelGGL(k2a_gram, dim3(1440), dim3(256), 0, stream, lf_fea, Gpart);
    hipLaunchKernelGGL(k2b_dist, dim3(5400), dim3(256), 0, stream, Gpart, sq, dist);
    hipLaunchKernelGGL(k3_topk,  dim3(2880), dim3(256), 0, stream, dist, idx);
    hipLaunchKernelGGL(kw1_conv, dim3(96),   dim3(256), 0, stream, w1, w1h);
    hipLaunchKernelGGL(kw2_conv, dim3(288),  dim3(256), 0, stream, w2, w2h);
    hipLaunchKernelGGL(k4_conv1, dim3(5760), dim3(256), 0, stream, lfG, w1h, idx, a1);
    hipLaunchKernelGGL(k5n_conv3,dim3(1440), dim3(256), 0, stream, lfVh, a1, w2h, outp);
}

// Round 23
// 832.295 us; speedup vs baseline: 3.0044x; 1.0114x over previous
//
#include <hip/hip_runtime.h>
#include <stdint.h>

// Fixed problem config
#define NN   2
#define ANU  5
#define CH   64
#define HH   96
#define WW   96
#define KK   6
#define PSHh 8
#define PNHh 12
#define BB   (NN*PNHh)        // 24
#define PP   (ANU*WW)         // 480
#define CCD  (CH*ANU*PSHh)    // 2560
#define IMG_HW (HH*WW)            // 9216
#define IMG_STRIDE (CH*HH*WW)     // 589824 floats per input image
#define LFV_IMG (CH*ANU*HH)       // 30720 elems per (n,v,w) image in lfVh / a1h

typedef int   i32x4 __attribute__((ext_vector_type(4)));
typedef float f32x4 __attribute__((ext_vector_type(4)));

__device__ __forceinline__ unsigned short f2bf(float f) {
    unsigned int u = __float_as_uint(f);
    return (unsigned short)((u + 0x7FFFu + ((u >> 16) & 1u)) >> 16);
}

__device__ __forceinline__ void mfma_bf16_16x16x32(f32x4& d, i32x4 a, i32x4 b) {
    asm volatile("v_mfma_f32_16x16x32_bf16 %0, %1, %2, %0"
                 : "+v"(d) : "v"(a), "v"(b));
}

// ---------------------------------------------------------------------------
// K0: transpose lf_fea[(n,u,v)][c][h][w] -> lfVh[(n,v,w)][c][u][h] (bf16)
//     (r22 verbatim, passing)
// ---------------------------------------------------------------------------
__global__ __launch_bounds__(256) void k0_lfv(const float* __restrict__ lf_fea,
                                              unsigned short* __restrict__ lfVh) {
    int bc  = blockIdx.x;          // img*64 + c
    int img = bc >> 6;
    int c   = bc & 63;
    int n = img / 25, r = img % 25, u = r / 5, v = r % 5;
    const float* src = lf_fea + (size_t)bc * IMG_HW;
    __shared__ float tile[96][97];
    for (int e = threadIdx.x; e < 96*96; e += 256) {
        int h = e / 96, w = e % 96;
        tile[h][w] = src[e];
    }
    __syncthreads();
    size_t base = (size_t)((n*5 + v)*96) * LFV_IMG + (size_t)c*480 + u*96;
    for (int e = threadIdx.x; e < 96*96; e += 256) {
        int w = e / 96, h = e % 96;
        lfVh[base + (size_t)w * LFV_IMG + h] = f2bf(tile[h][w]);
    }
}

// ---------------------------------------------------------------------------
// K0g: pack lf_fea -> lfG[(n,pnh)][p=(v,w)][c][u][psh] (bf16, gather-optimal)
//      (r22 verbatim, passing)
// ---------------------------------------------------------------------------
__global__ __launch_bounds__(256) void k0g_pack(const float* __restrict__ lf,
                                                unsigned short* __restrict__ lfG) {
    int blk = blockIdx.x;            // ((img*12 + pnh)*4 + ct), grid 2400
    int ct = blk & 3; int r = blk >> 2;
    int pnh = r % 12, img = r / 12;
    int n = img / 25, rr = img % 25, u = rr / 5, v = rr % 5;
    int c0 = ct * 16;
    __shared__ float tile[16][8][97];
    int t = threadIdx.x;
    const float* src = lf + (size_t)img * IMG_STRIDE + (size_t)c0 * IMG_HW + pnh*768;
#pragma unroll
    for (int i = 0; i < 12; ++i) {
        int e = i*256 + t;           // 3072 float4
        int ci = e / 192, r2 = e % 192, psh = r2 / 24, q2 = r2 % 24;
        float4 vv = *(const float4*)(src + (size_t)ci*IMG_HW + psh*96 + q2*4);
        tile[ci][psh][q2*4+0]=vv.x; tile[ci][psh][q2*4+1]=vv.y;
        tile[ci][psh][q2*4+2]=vv.z; tile[ci][psh][q2*4+3]=vv.w;
    }
    __syncthreads();
    size_t ob = ((size_t)((n*12+pnh)*480 + v*96)) * 2560 + c0*40 + u*8;
#pragma unroll
    for (int i = 0; i < 24; ++i) {
        int e = i*256 + t;           // 6144 units = (w, ci, psh-pair)
        int w = e >> 6, r2 = e & 63, ci = r2 >> 2, pp = r2 & 3;
        size_t off = ob + (size_t)w*2560 + ci*40 + pp*2;
        lfG[off]     = f2bf(tile[ci][pp*2][w]);
        lfG[off + 1] = f2bf(tile[ci][pp*2+1][w]);
    }
}

// ---------------------------------------------------------------------------
// K1: sq[b][p] (fp64 accumulate), 8-way column split per row; 360 blocks
// ---------------------------------------------------------------------------
__global__ __launch_bounds__(256) void k1_sq(const float* __restrict__ lf_fea,
                                             float* __restrict__ sq) {
    int t = threadIdx.x;
    int row = blockIdx.x * 32 + (t & 31);      // 0..11519
    int cp = t >> 5;                           // 0..7
    int b = row / PP, p = row % PP;
    int n = b / PNHh, pnh = b % PNHh;
    int v = p / WW, w = p % WW;
    double acc = 0.0;
    for (int ci = 0; ci < 8; ++ci) {
        int c = cp * 8 + ci;
        for (int u = 0; u < 5; ++u) {
            const float* s = lf_fea + ((size_t)((n*25 + u*5 + v)*64 + c)) * IMG_HW
                           + pnh*8*96 + w;
#pragma unroll
            for (int psh = 0; psh < 8; ++psh) {
                float x = s[psh*96];
                acc += (double)x * (double)x;
            }
        }
    }
    __shared__ double red[256];
    red[t] = acc;
    __syncthreads();
    if (t < 32) {
        double ss = 0.0;
#pragma unroll
        for (int j = 0; j < 8; ++j) ss += red[j * 32 + t];
        sq[blockIdx.x * 32 + t] = (float)ss;
    }
}

// ---------------------------------------------------------------------------
// K2a: partial Gram, symmetric (vr<=vc), K-split 4; grid 1440  (r22 verbatim)
// ---------------------------------------------------------------------------
__global__ __launch_bounds__(256) void k2a_gram(const float* __restrict__ lf_fea,
                                                float* __restrict__ Gpart) {
    const int VRt[15] = {0,0,0,0,0,1,1,1,1,2,2,2,3,3,4};
    const int VCt[15] = {0,1,2,3,4,1,2,3,4,2,3,4,3,4,4};
    int blk = blockIdx.x;            // b*60 + pr*4 + ks
    int b  = blk / 60;
    int r0 = blk % 60;
    int pr = r0 / 4, ks = r0 % 4;
    int vr = VRt[pr], vc = VCt[pr];
    int n = b / PNHh, pnh = b % PNHh;

    __shared__ float As[32][96];
    __shared__ float Bs[32][96];

    int t  = threadIdx.x;
    int tx = t & 31, ty = t >> 5;    // 32 x 8 compute tiling
    int sr = t >> 3, sw = t & 7;     // staging: row 0..31, col-base 0..7
    float acc[12][3] = {};

    int kbase = ks * 640;
    for (int kc0 = kbase; kc0 < kbase + 640; kc0 += 32) {
        {
            int cc = kc0 + sr;
            int c = cc / 40, r2 = cc % 40, u = r2 >> 3, psh = r2 & 7;
            size_t off = ((size_t)((n*25 + u*5)*64 + c)) * IMG_HW + (pnh*8 + psh)*96;
            const float* pa = lf_fea + off + (size_t)vr * IMG_STRIDE;
            const float* pb = lf_fea + off + (size_t)vc * IMG_STRIDE;
#pragma unroll
            for (int j = 0; j < 12; ++j) {
                int w = sw + 8*j;
                As[sr][w] = pa[w];
                Bs[sr][w] = pb[w];
            }
        }
        __syncthreads();
        float accC[12][3] = {};
#pragma unroll
        for (int kc = 0; kc < 32; ++kc) {
            float a[12], bq[3];
            *(float4*)&a[0] = *(const float4*)&As[kc][ty*12 + 0];
            *(float4*)&a[4] = *(const float4*)&As[kc][ty*12 + 4];
            *(float4*)&a[8] = *(const float4*)&As[kc][ty*12 + 8];
#pragma unroll
            for (int j = 0; j < 3; ++j) bq[j] = Bs[kc][tx*3 + j];
#pragma unroll
            for (int i = 0; i < 12; ++i)
#pragma unroll
                for (int j = 0; j < 3; ++j)
                    accC[i][j] = fmaf(a[i], bq[j], accC[i][j]);
        }
#pragma unroll
        for (int i = 0; i < 12; ++i)
#pragma unroll
            for (int j = 0; j < 3; ++j)
                acc[i][j] += accC[i][j];
        __syncthreads();
    }

    size_t gbase = ((size_t)(ks*600 + b*25 + vr*5 + vc)) * 9216;
#pragma unroll
    for (int i = 0; i < 12; ++i)
#pragma unroll
        for (int j = 0; j < 3; ++j)
            Gpart[gbase + (ty*12 + i)*96 + tx*3 + j] = acc[i][j];

    if (vr != vc) {
        size_t gbt = ((size_t)(ks*600 + b*25 + vc*5 + vr)) * 9216;
#pragma unroll
        for (int i = 0; i < 12; ++i)
#pragma unroll
            for (int j = 0; j < 3; ++j)
                Gpart[gbt + (tx*3 + j)*96 + ty*12 + i] = acc[i][j];
    }
}

// ---------------------------------------------------------------------------
// K2b: dist[b][p][q] = sq_p + sq_q - 2 * sum_ks Gpart   (r11 verbatim)
// ---------------------------------------------------------------------------
__global__ __launch_bounds__(256) void k2b_dist(const float* __restrict__ Gpart,
                                                const float* __restrict__ sq,
                                                float* __restrict__ dist) {
    int tid = blockIdx.x * 256 + threadIdx.x;   // grid 5400: exactly 1,382,400
    int b = tid / 57600;
    int r = tid % 57600;
    int p = r / 120, qt = r % 120;
    int vr = p / 96, pl = p % 96;
    int vc = qt / 24;
    int ql4 = (qt % 24) * 4;

    size_t tb = ((size_t)(b*25 + vr*5 + vc)) * 9216 + pl*96 + ql4;
    float4 g0 = *(const float4*)(Gpart + tb);
    float4 g1 = *(const float4*)(Gpart + tb +  600ull*9216);
    float4 g2 = *(const float4*)(Gpart + tb + 1200ull*9216);
    float4 g3 = *(const float4*)(Gpart + tb + 1800ull*9216);
    float gx = g0.x + g1.x + g2.x + g3.x;
    float gy = g0.y + g1.y + g2.y + g3.y;
    float gz = g0.z + g1.z + g2.z + g3.z;
    float gw = g0.w + g1.w + g2.w + g3.w;

    float  sqp = sq[b*480 + p];
    float4 sqq = *(const float4*)(sq + b*480 + vc*96 + ql4);
    float4 d;
    d.x = sqp + sqq.x - 2.0f * gx;
    d.y = sqp + sqq.y - 2.0f * gy;
    d.z = sqp + sqq.z - 2.0f * gz;
    d.w = sqp + sqq.w - 2.0f * gw;
    *(float4*)(dist + (size_t)b*230400 + (size_t)p*480 + vc*96 + ql4) = d;
}

// ---------------------------------------------------------------------------
// K3: per-row top-6  (passing, verbatim)
// ---------------------------------------------------------------------------
__global__ __launch_bounds__(256) void k3_topk(const float* __restrict__ dist,
                                               int* __restrict__ idx) {
    int wid  = (blockIdx.x * 256 + threadIdx.x) >> 6;  // global wave id
    int lane = threadIdx.x & 63;
    int b = wid / PP, p = wid % PP;
    const float* row = dist + (size_t)b * PP * PP + (size_t)p * PP;

    unsigned long long key[8];
#pragma unroll
    for (int j = 0; j < 8; ++j) {
        int q = j*64 + lane;
        if (q < PP) {
            unsigned int f = __float_as_uint(row[q]);
            unsigned int mono = f ^ ((f & 0x80000000u) ? 0xFFFFFFFFu : 0x80000000u);
            key[j] = ((unsigned long long)mono << 32) | (unsigned int)q;
        } else {
            key[j] = ~0ull;
        }
    }
    int* outp = idx + ((size_t)b*PP + p) * KK;
    for (int k = 0; k < KK; ++k) {
        unsigned long long m = key[0];
#pragma unroll
        for (int j = 1; j < 8; ++j) m = (key[j] < m) ? key[j] : m;
        for (int s = 1; s < 64; s <<= 1) {
            unsigned long long o = __shfl_xor(m, s, 64);
            m = (o < m) ? o : m;
        }
        if (lane == 0) outp[k] = (int)(m & 0xFFFFFFFFu);
#pragma unroll
        for (int j = 0; j < 8; ++j) if (key[j] == m) key[j] = ~0ull;
    }
}

// ---------------------------------------------------------------------------
// kw1: w1 -> bf16 flat copy w1h[co][k*64+c]  (passing, verbatim)
// ---------------------------------------------------------------------------
__global__ __launch_bounds__(256) void kw1_conv(const float* __restrict__ w1,
                                                unsigned short* __restrict__ w1h) {
    int e = blockIdx.x * 256 + threadIdx.x;   // 24576 total, grid 96
    if (e < 24576) w1h[e] = f2bf(w1[e]);
}

// ---------------------------------------------------------------------------
// kw2: reorder w2 -> bf16 w2h[co][cc][tap][ci64] (passing, verbatim)
// ---------------------------------------------------------------------------
__global__ __launch_bounds__(256) void kw2_conv(const float* __restrict__ w2,
                                                unsigned short* __restrict__ w2h) {
    int e = blockIdx.x * 256 + threadIdx.x;   // 73728 total
    if (e < 73728) {
        int co = e / 1152, r = e % 1152;
        int cc = r / 576, r2 = r % 576;
        int tap = r2 / 64, ci_l = r2 % 64;
        w2h[e] = f2bf(w2[co*1152 + (cc*64 + ci_l)*9 + tap]);
    }
}

// ---------------------------------------------------------------------------
// K4: gather + 1x1 conv via inline-asm MFMA (r22 core verbatim).
//     Epilogue now stores bf16 a1h (u16 scatter, execution-proven class);
//     same f2bf rounding point k5n used at stage time -> output bit-identical.
// ---------------------------------------------------------------------------
__global__ __launch_bounds__(256) void k4_conv1(const unsigned short* __restrict__ lfG,
                                                const unsigned short* __restrict__ w1h,
                                                const int* __restrict__ idxg,
                                                unsigned short* __restrict__ a1h) {
    int blk = blockIdx.x;            // b*240 + ptile
    int b = blk / 240, ptile = blk % 240;
    int n = b / PNHh, pnh = b % PNHh;
    int p0 = ptile * 2;

    __shared__ unsigned short Bs[80][384];   // [col][swizzled krow] bf16
    __shared__ int idxs[12];

    int t = threadIdx.x;
    if (t < 12) idxs[t] = idxg[(b*PP + p0 + t/6)*KK + (t % 6)];
    __syncthreads();

    // stage: 3840 units of 16B; unit = (pl, k, m); m -> (c = m/5, u = m%5)
    for (int i = 0; i < 15; ++i) {
        int e = i * 256 + t;         // 3840 exactly
        int pl = e / 1920, r = e % 1920;
        int k = r / 320, m = r % 320;
        int c = m / 5, u = m % 5;
        int q = idxs[pl*6 + k];
        i32x4 vv = *(const i32x4*)(lfG + ((size_t)(b*480 + q))*2560 + m*8);
        int colbase = pl*40 + u*8;   // multiple of 8
        int krow = k*64 + c;
        int kc = krow >> 3, kl = krow & 7;
        int kbase = kc & ~7, klo = kc & 7;
#pragma unroll
        for (int j = 0; j < 4; ++j) {
            unsigned int d = (unsigned int)vv[j];
            int j0 = 2*j, j1 = 2*j + 1;
            Bs[colbase + j0][((kbase | (klo ^ j0)) << 3) | kl] =
                (unsigned short)(d & 0xFFFFu);
            Bs[colbase + j1][((kbase | (klo ^ j1)) << 3) | kl] =
                (unsigned short)(d >> 16);
        }
    }
    __syncthreads();

    int lane = t & 63, wv = t >> 6;
    int l15 = lane & 15, hi = lane >> 4;
    int co0 = wv * 16;
    f32x4 acc[5] = {};
#pragma unroll
    for (int f = 0; f < 5; ++f)
        asm volatile("s_nop 1" : "+v"(acc[f]));

    const unsigned short* ap = w1h + (size_t)(co0 + l15) * 384 + hi * 8;
    for (int ks = 0; ks < 12; ++ks) {
        i32x4 a = *(const i32x4*)(ap + ks * 32);
        asm volatile("s_nop 1" : "+v"(a));
#pragma unroll
        for (int f = 0; f < 5; ++f) {
            int col = f * 16 + l15;
            int ch = ks * 4 + hi;            // chunk 0..47
            int chs = (ch & ~7) | ((ch & 7) ^ (col & 7));
            i32x4 bv = *(const i32x4*)&Bs[col][chs << 3];
            mfma_bf16_16x16x32(acc[f], a, bv);
        }
    }
#pragma unroll
    for (int f = 0; f < 5; ++f)
        asm volatile("s_nop 7\ns_nop 7" : "+v"(acc[f]));

    // epilogue: leaky + bf16 u16 stores; D map: col=lane&15, row=hi*4+reg
#pragma unroll
    for (int f = 0; f < 5; ++f) {
        int col = f * 16 + l15;
        int pg = p0 + col / 40, rr = col % 40;
        int u = rr >> 3, psh = rr & 7;
        size_t base = (size_t)((n*5 + pg/96)*96 + (pg%96)) * LFV_IMG
                    + (size_t)u * 96 + pnh*8 + psh;
#pragma unroll
        for (int rg = 0; rg < 4; ++rg) {
            float x = acc[f][rg];
            x = x > 0.f ? x : 0.1f * x;
            a1h[base + (size_t)(co0 + hi*4 + rg) * 480] = f2bf(x);
        }
    }
}

// ---------------------------------------------------------------------------
// K5n: 3x3 conv via inline-asm MFMA, u-fused tile (r22 core).
//      Both cc passes now read bf16 (lfVh / a1h) via the proven ushort4
//      path — branch eliminated, a1 read traffic halved.
// ---------------------------------------------------------------------------
__global__ __launch_bounds__(256) void k5n_conv3(const unsigned short* __restrict__ lfVh,
                                                 const unsigned short* __restrict__ a1h,
                                                 const unsigned short* __restrict__ w2h,
                                                 float* __restrict__ outp) {
    int blk = blockIdx.x;             // grid 1440 = nv*144 + wt*6 + ht
    int ht = blk % 6;  int r = blk / 6;
    int wt = r % 24;   int nv = r / 24;    // nv = n*5 + v
    int w0 = wt * 4, h0 = ht * 16;
    int imgbase = nv * 96 + w0;

    __shared__ unsigned short ins[360][64];   // 46,080 B

    int t = threadIdx.x;
    int lane = t & 63, wv = t >> 6, l15 = lane & 15, hi = lane >> 4;
    int wl = l15 & 3;                 // output w within tile
    int hl = wv * 4 + (l15 >> 2);     // output h within tile (wave-split)

    f32x4 acc[5][4] = {};
#pragma unroll
    for (int u = 0; u < 5; ++u)
#pragma unroll
        for (int j = 0; j < 4; ++j)
            asm volatile("s_nop 1" : "+v"(acc[u][j]));

    for (int cc = 0; cc < 2; ++cc) {
        const unsigned short* basep = cc ? a1h : lfVh;
        if (cc) __syncthreads();
        // stage: e = (ci, uin, w, g): 4 h-values, b16 scatter with guards
        for (int i = 0; i < 30; ++i) {
            int e = i * 256 + t;              // 7680 = 64*5*4*6
            int g   = e % 6;
            int w   = (e / 6) & 3;
            int uin = (e / 24) % 5;
            int ci  = e / 120;
            int hbase = h0 - 4 + g * 4;       // aligned chunk of 4 h-values
            unsigned short b0 = 0, b1 = 0, b2 = 0, b3 = 0;
            if (hbase >= 0 && hbase <= 92) {
                ushort4 vv = *(const ushort4*)(basep
                    + (size_t)(imgbase + w) * LFV_IMG
                    + (size_t)ci * 480 + uin * 96 + hbase);
                b0 = vv.x; b1 = vv.y; b2 = vv.z; b3 = vv.w;
            }
            int sbase = (w*5 + uin) * 18;
            int hp0 = g*4 - 3;                // hp of element 0 (in [-3, 17])
            int cch = ci >> 3, clo = ci & 7;
            if (hp0 >= 0) {                               // hp0 <= 17 always
                int s = sbase + hp0;
                ins[s][((cch ^ (s & 7)) << 3) | clo] = b0;
            }
            if (hp0 + 1 >= 0 && hp0 + 1 < 18) {
                int s = sbase + hp0 + 1;
                ins[s][((cch ^ (s & 7)) << 3) | clo] = b1;
            }
            if (hp0 + 2 >= 0 && hp0 + 2 < 18) {
                int s = sbase + hp0 + 2;
                ins[s][((cch ^ (s & 7)) << 3) | clo] = b2;
            }
            if (hp0 + 3 < 18) {                           // hp0+3 >= 0 always
                int s = sbase + hp0 + 3;
                ins[s][((cch ^ (s & 7)) << 3) | clo] = b3;
            }
        }
        __syncthreads();

        // compute: K-steps (du,dh,kk); B-frag per u feeds 4 co-frag MFMAs
        for (int du = 0; du < 3; ++du) {
#pragma unroll
            for (int dh = 0; dh < 3; ++dh)
#pragma unroll
            for (int kk = 0; kk < 2; ++kk) {
                const unsigned short* wp = w2h + cc*576 + (du*3 + dh)*64
                                         + kk*32 + hi*8 + (size_t)l15*1152;
                i32x4 a0 = *(const i32x4*)(wp);
                i32x4 a1f = *(const i32x4*)(wp + 16*1152);
                i32x4 a2 = *(const i32x4*)(wp + 32*1152);
                i32x4 a3 = *(const i32x4*)(wp + 48*1152);
#pragma unroll
                for (int u = 0; u < 5; ++u) {
                    int uin = u + du - 1;
                    if (uin < 0 || uin > 4) continue;   // u-halo: exact skip
                    int s = (wl*5 + uin)*18 + hl + dh;
                    i32x4 bv = *(const i32x4*)&ins[s][((kk*4 + hi) ^ (s & 7)) << 3];
                    mfma_bf16_16x16x32(acc[u][0], a0, bv);
                    mfma_bf16_16x16x32(acc[u][1], a1f, bv);
                    mfma_bf16_16x16x32(acc[u][2], a2, bv);
                    mfma_bf16_16x16x32(acc[u][3], a3, bv);
                }
            }
        }
        if (!cc) __syncthreads();   // protect ins reuse before second stage
    }
#pragma unroll
    for (int u = 0; u < 5; ++u)
#pragma unroll
        for (int j = 0; j < 4; ++j)
            asm volatile("s_nop 7\ns_nop 7" : "+v"(acc[u][j]));

    // leaky + permuted store: out[(n*25+u*5+v)][co][h0+hl][w0+wl]
    int n = nv / 5, v = nv % 5;
#pragma unroll
    for (int u = 0; u < 5; ++u) {
        size_t ob = (size_t)((n*25 + u*5 + v) * 64) * IMG_HW
                  + (size_t)(h0 + hl) * 96 + w0 + wl;
#pragma unroll
        for (int j = 0; j < 4; ++j) {
#pragma unroll
            for (int rg = 0; rg < 4; ++rg) {
                int co = j*16 + hi*4 + rg;
                float x = acc[u][j][rg];
                x = x > 0.f ? x : 0.1f * x;
                outp[ob + (size_t)co * IMG_HW] = x;
            }
        }
    }
}

// ---------------------------------------------------------------------------
extern "C" void kernel_launch(void* const* d_in, const int* in_sizes, int n_in,
                              void* d_out, int out_size, void* d_ws, size_t ws_size,
                              hipStream_t stream) {
    const float* lf_fea = (const float*)d_in[0];
    const float* w1     = (const float*)d_in[1];
    const float* w2     = (const float*)d_in[2];
    float* outp = (float*)d_out;

    char* ws = (char*)d_ws;
    // ws layout (bytes), end 228,672,000 (< proven 258 MB footprint):
    //   lfVh :  58,982,400 @ 0                       (bf16)
    //   lfG  :  58,982,400 @  58,982,400             (bf16, gather-optimal)
    //   a1h/Gpart union     @ 117,964,800, size 88,473,600
    //     (Gpart written k2a, read k2b, dead before k4 writes a1h)
    //   dist :  22,118,400 @ 206,438,400             (w2h/w1h alias after k3)
    //   sq   :      46,080 @ 228,556,800
    //   idx  :      69,120 @ 228,602,880   (end 228,672,000)
    unsigned short* lfVh = (unsigned short*)(ws);
    unsigned short* lfG  = (unsigned short*)(ws + 58982400ull);
    unsigned short* a1h  = (unsigned short*)(ws + 117964800ull);
    float* Gpart = (float*)(ws + 117964800ull);   // aliases a1h (dead first)
    float* dist  = (float*)(ws + 206438400ull);
    float* sq    = (float*)(ws + 228556800ull);
    int*   idx   = (int*)  (ws + 228602880ull);
    unsigned short* w2h = (unsigned short*)(ws + 206438400ull);  // reuses dist
    unsigned short* w1h = (unsigned short*)(ws + 206438400ull + 147456ull);

    hipLaunchKernelGGL(k0_lfv,   dim3(3200), dim3(256), 0, stream, lf_fea, lfVh);
    hipLaunchKernelGGL(k0g_pack, dim3(2400), dim3(256), 0, stream, lf_fea, lfG);
    hipLaunchKernelGGL(k1_sq,    dim3(360),  dim3(256), 0, stream, lf_fea, sq);
    hipLaunchKernelGGL(k2a_gram, dim3(1440), dim3(256), 0, stream, lf_fea, Gpart);
    hipLaunchKernelGGL(k2b_dist, dim3(5400), dim3(256), 0, stream, Gpart, sq, dist);
    hipLaunchKernelGGL(k3_topk,  dim3(2880), dim3(256), 0, stream, dist, idx);
    hipLaunchKernelGGL(kw1_conv, dim3(96),   dim3(256), 0, stream, w1, w1h);
    hipLaunchKernelGGL(kw2_conv, dim3(288),  dim3(256), 0, stream, w2, w2h);
    hipLaunchKernelGGL(k4_conv1, dim3(5760), dim3(256), 0, stream, lfG, w1h, idx, a1h);
    hipLaunchKernelGGL(k5n_conv3,dim3(1440), dim3(256), 0, stream, lfVh, a1h, w2h, outp);
}